// Round 14
// baseline (400.492 us; speedup 1.0000x reference)
//
#include <hip/hip_runtime.h>

#define EPS 1e-3f

// Tensor geometry (fixed for this problem):
// y1 (L1 pre-act): bf16 channel-last (2, 21,256,256, 16)  -- 32 B per cell
// m1: (2,21,256,256) fp32
// h2q: quad-interleaved fp32 (2, 8, 11,128,128, 4)   m2: (2,11,128,128)
// h3:  (2,64,5,64,64)  m3: (2,5,64,64)
// out: (2,64,2,64,64) -> d_out (2,128,64,64) same layout
//
// Lessons encoded:
//  - Block-uniform weight pointers only (scalar s_load path). (r2)
//  - Direct conv beats phase-barrier LDS staging here. (r10)
//  - conv_l2 is effectively dense (m1 ~13.7%, E[taps/px]=3.7, 93% of taps issue
//    per wave); sparse wave-per-px machinery loses to per-wave overhead (r12).
//    Thread-per-(px,16oc) direct conv is the knee (~126us, VALUBusy 77%). (r13)
//  - Scatter: bf16 channel-last y1 + packed bf16 atomics (request-bound). (r13)
//  - oc-split factor trades duplicated input reads (L2) vs wave count:
//    conv_l3 8-way was L2-bound (~2.3GB dup reads) -> 4-way is FMA-bound. (r14)
//  - conv_l4 at 8 waves/CU was latency-exposed -> 16-way split. (r14)

// f32 -> bf16 (RNE)
static __device__ __forceinline__ unsigned f2bf(float f) {
    unsigned u = __float_as_uint(f);
    return (u + 0x7FFFu + ((u >> 16) & 1u)) >> 16;
}

// ---------------- Weight repack + BN fold ----------------
// wT2: [tap][cin][oc] 27x16x32; wT3: [tap][cin][oc] 27x32x64; wT4: [(c*3+kz)*64+oc]
// shb: [0..31]=sh2, [32..95]=sh3, [96..159]=sh4, [160..175]=sc1, [176..191]=sh1
__global__ __launch_bounds__(256) void repack(
    const float* __restrict__ g1, const float* __restrict__ b1,
    const float* __restrict__ rm1, const float* __restrict__ rv1,
    const float* __restrict__ w2, const float* __restrict__ g2, const float* __restrict__ b2,
    const float* __restrict__ rm2, const float* __restrict__ rv2,
    const float* __restrict__ w3, const float* __restrict__ g3, const float* __restrict__ b3,
    const float* __restrict__ rm3, const float* __restrict__ rv3,
    const float* __restrict__ w4, const float* __restrict__ g4, const float* __restrict__ b4,
    const float* __restrict__ rm4, const float* __restrict__ rv4,
    float* __restrict__ wT2, float* __restrict__ wT3, float* __restrict__ wT4,
    float* __restrict__ shb)
{
    const int i = blockIdx.x * 256 + threadIdx.x;
    if (i < 13824) {                       // wT2[tap*512 + cin*32 + oc]
        const int tap = i / 512, cin = (i / 32) % 16, oc = i & 31;
        const float inv = g2[oc] * rsqrtf(rv2[oc] + EPS);
        wT2[i] = w2[(oc * 16 + cin) * 27 + tap] * inv;
    } else if (i < 69120) {                // wT3[tap*2048 + cin*64 + oc]
        const int j = i - 13824;
        const int tap = j / 2048, cin = (j / 64) % 32, oc = j & 63;
        const float inv = g3[oc] * rsqrtf(rv3[oc] + EPS);
        wT3[j] = w3[(oc * 32 + cin) * 27 + tap] * inv;
    } else if (i < 81408) {                // wT4[(c*3+kz)*64+oc], 64x3x64
        const int j = i - 69120;
        const int c = j / 192, kz = (j / 64) % 3, oc = j & 63;
        const float inv = g4[oc] * rsqrtf(rv4[oc] + EPS);
        wT4[j] = w4[(oc * 64 + c) * 3 + kz] * inv;
    } else if (i < 81600) {                // shifts + L1 BN scale/shift
        const int j = i - 81408;
        if (j < 32) {
            const float inv = g2[j] * rsqrtf(rv2[j] + EPS);
            shb[j] = b2[j] - rm2[j] * inv;
        } else if (j < 96) {
            const int o = j - 32;
            const float inv = g3[o] * rsqrtf(rv3[o] + EPS);
            shb[j] = b3[o] - rm3[o] * inv;
        } else if (j < 160) {
            const int o = j - 96;
            const float inv = g4[o] * rsqrtf(rv4[o] + EPS);
            shb[j] = b4[o] - rm4[o] * inv;
        } else if (j < 176) {
            const int o = j - 160;
            shb[j] = g1[o] * rsqrtf(rv1[o] + EPS);           // sc1
        } else if (j < 192) {
            const int o = j - 176;
            const float inv = g1[o] * rsqrtf(rv1[o] + EPS);
            shb[j] = b1[o] - rm1[o] * inv;                   // sh1
        }
    }
}

// ---------------- Layer 1: voxel scatter, one thread per (voxel, oc-pair) ----------------
// y1 bf16 channel-last: cell = 32 B contiguous; one packed-bf16 atomic adds 2 ch.
__global__ __launch_bounds__(256) void scatter_l1(
    const float* __restrict__ vf, const int* __restrict__ coors, int NV,
    const float* __restrict__ w1, unsigned short* __restrict__ y1,
    float* __restrict__ m1)
{
    __shared__ float ws[16 * 3 * 27];  // (oc, c, tap)
    for (int e = threadIdx.x; e < 16 * 3 * 27; e += 256) ws[e] = w1[e];
    __syncthreads();

    const int gid = blockIdx.x * 256 + threadIdx.x;
    const int i = gid >> 3;        // voxel
    const int oc2 = gid & 7;       // channel pair
    if (i >= NV) return;
    const int oc = oc2 * 2;

    const int b = coors[4 * i + 0];
    const int z = coors[4 * i + 1];
    const int y = coors[4 * i + 2];
    const int x = coors[4 * i + 3];
    const float f0 = vf[3 * i + 0];
    const float f1 = vf[3 * i + 1];
    const float f2 = vf[3 * i + 2];

    int ozv[2], kzv[2], nz = 0;
    int oyv[2], kyv[2], ny = 0;
    int oxv[2], kxv[2], nx = 0;
#pragma unroll
    for (int k = 0; k < 3; ++k) {
        int t = z + 1 - k;
        if (t >= 0 && !(t & 1)) { int o = t >> 1; if (o < 21) { ozv[nz] = o; kzv[nz] = k; ++nz; } }
    }
#pragma unroll
    for (int k = 0; k < 3; ++k) {
        int t = y + 1 - k;
        if (t >= 0 && !(t & 1)) { int o = t >> 1; if (o < 256) { oyv[ny] = o; kyv[ny] = k; ++ny; } }
    }
#pragma unroll
    for (int k = 0; k < 3; ++k) {
        int t = x + 1 - k;
        if (t >= 0 && !(t & 1)) { int o = t >> 1; if (o < 256) { oxv[nx] = o; kxv[nx] = k; ++nx; } }
    }

    for (int a = 0; a < nz; ++a)
        for (int bb = 0; bb < ny; ++bb)
            for (int c = 0; c < nx; ++c) {
                const int oz = ozv[a], oy = oyv[bb], ox = oxv[c];
                const int tap = (kzv[a] * 3 + kyv[bb]) * 3 + kxv[c];
                const int sp = oz * 65536 + oy * 256 + ox;
                if (oc2 == 0) m1[b * 1376256 + sp] = 1.0f;
                const float s0 = ws[oc * 81 + tap] * f0 + ws[oc * 81 + 27 + tap] * f1 +
                                 ws[oc * 81 + 54 + tap] * f2;
                const float s1 = ws[(oc + 1) * 81 + tap] * f0 +
                                 ws[(oc + 1) * 81 + 27 + tap] * f1 +
                                 ws[(oc + 1) * 81 + 54 + tap] * f2;
                const unsigned pk = f2bf(s0) | (f2bf(s1) << 16);
                unsigned* addr = (unsigned*)(y1 + (size_t)(b * 1376256 + sp) * 16 +
                                             oc2 * 2);
                asm volatile("global_atomic_pk_add_bf16 %0, %1, off"
                             : : "v"(addr), "v"(pk) : "memory");
            }
}

// ---------------- Layer 2: DIRECT conv 16->32, k3, s2, pad(1,1,1) ----------------
// One thread per (output px, 16-oc group). No LDS/barriers. 27 mask values
// preloaded; active taps read the cell's 16 bf16 cin (2x16B loads) + 256 FMA.
// Writes h2 quad-interleaved (fp32) for conv_l3's vector loads.
__global__ __launch_bounds__(128) __attribute__((amdgpu_waves_per_eu(4, 8)))
void conv_l2(
    const uint4* __restrict__ y1b, const float* __restrict__ m1,
    const float* __restrict__ wT2, const float* __restrict__ shb,
    float4* __restrict__ h2q, float* __restrict__ m2)
{
    const int tid = threadIdx.x;
    const int tx = tid & 15, ty = tid >> 4;            // 16 x 8 px tile
    const int ocg = blockIdx.x >> 3;                   // 0..1 (16 oc each)
    const int ox = (blockIdx.x & 7) * 16 + tx, oy = blockIdx.y * 8 + ty;
    const int bz = blockIdx.z;
    const int b = bz / 11, oz = bz % 11;
    const int iz0 = 2 * oz - 1, iyb = 2 * oy - 1, ixb = 2 * ox - 1;

    // L1 BN params as uniforms -> SGPRs
    float sc1[16], sh1[16];
#pragma unroll
    for (int c = 0; c < 16; ++c) { sc1[c] = shb[160 + c]; sh1[c] = shb[176 + c]; }

    // preload 27 mask values (independent loads pipeline)
    float mv[27];
    float msum = 0.f;
#pragma unroll
    for (int kz = 0; kz < 3; ++kz) {
        const int iz = iz0 + kz;
#pragma unroll
        for (int ky = 0; ky < 3; ++ky) {
            const int iy = iyb + ky;
#pragma unroll
            for (int kx = 0; kx < 3; ++kx) {
                const int ix = ixb + kx;
                float m = 0.f;
                if ((unsigned)iz < 21u && (unsigned)iy < 256u && (unsigned)ix < 256u)
                    m = m1[b * 1376256 + iz * 65536 + iy * 256 + ix];
                mv[(kz * 3 + ky) * 3 + kx] = m;
                msum += m;
            }
        }
    }

    const int spo = oz * 16384 + oy * 128 + ox;

    // early-out for fully-inactive px (~2%): zero outputs, skip tap loop
    if (msum == 0.f) {
        if (ocg == 0) m2[b * 180224 + spo] = 0.f;
        const float4 zero = {0.f, 0.f, 0.f, 0.f};
#pragma unroll
        for (int lq = 0; lq < 4; ++lq)
            h2q[(b * 8 + ocg * 4 + lq) * 180224 + spo] = zero;
        return;
    }

    float acc[16];
#pragma unroll
    for (int oc = 0; oc < 16; ++oc) acc[oc] = 0.f;

#pragma unroll 1
    for (int kz = 0; kz < 3; ++kz) {
        const int iz = iz0 + kz;
#pragma unroll 1
        for (int ky = 0; ky < 3; ++ky) {
            const int iy = iyb + ky;
#pragma unroll 1
            for (int kx = 0; kx < 3; ++kx) {
                const int tap = (kz * 3 + ky) * 3 + kx;
                if (mv[tap] > 0.f) {
                    const int ix = ixb + kx;
                    const int cb = (b * 1376256 + iz * 65536 + iy * 256 + ix) * 2;
                    const uint4 u0 = y1b[cb];
                    const uint4 u1 = y1b[cb + 1];
                    const float* __restrict__ wq = wT2 + tap * 512 + ocg * 16; // uniform
                    const unsigned d[8] = {u0.x, u0.y, u0.z, u0.w,
                                           u1.x, u1.y, u1.z, u1.w};
#pragma unroll
                    for (int j = 0; j < 8; ++j) {
                        const int c0 = 2 * j;
                        const float vlo = __uint_as_float(d[j] << 16);
                        const float vhi = __uint_as_float(d[j] & 0xFFFF0000u);
                        const float v0 = fmaxf(vlo * sc1[c0] + sh1[c0], 0.f);
                        const float v1 = fmaxf(vhi * sc1[c0 + 1] + sh1[c0 + 1], 0.f);
#pragma unroll
                        for (int oc = 0; oc < 16; ++oc) {
                            acc[oc] = fmaf(wq[c0 * 32 + oc], v0,
                                      fmaf(wq[(c0 + 1) * 32 + oc], v1, acc[oc]));
                        }
                    }
                }
            }
        }
    }

    if (ocg == 0) m2[b * 180224 + spo] = 1.f;
#pragma unroll
    for (int lq = 0; lq < 4; ++lq) {
        const int q = ocg * 4 + lq;
        float4 o;
        o.x = fmaxf(acc[lq * 4 + 0] + shb[ocg * 16 + lq * 4 + 0], 0.f);
        o.y = fmaxf(acc[lq * 4 + 1] + shb[ocg * 16 + lq * 4 + 1], 0.f);
        o.z = fmaxf(acc[lq * 4 + 2] + shb[ocg * 16 + lq * 4 + 2], 0.f);
        o.w = fmaxf(acc[lq * 4 + 3] + shb[ocg * 16 + lq * 4 + 3], 0.f);
        h2q[(b * 8 + q) * 180224 + spo] = o;
    }
}

// ---------------- Layer 3: DIRECT conv 32->64, k3, s2, pad(0,1,1) ----------------
// One thread per (output px, 16-oc group): 4-way oc split -- FMA-bound
// (8-way duplicated h2q L2 reads ~2.3GB; 4-way halves to ~1.1GB). Full 32-cin
// accumulation per thread; fused BN/ReLU/mask epilogue.
__global__ __launch_bounds__(128) __attribute__((amdgpu_waves_per_eu(4, 8)))
void conv_l3(
    const float4* __restrict__ h2q, const float* __restrict__ m2,
    const float* __restrict__ wT3, const float* __restrict__ shb,
    float* __restrict__ h3, float* __restrict__ m3)
{
    const int tid = threadIdx.x;
    const int tx = tid & 15, ty = tid >> 4;            // 16 x 8 px tile
    const int ocg = blockIdx.x >> 2;                   // 0..3 (16 oc each)
    const int ox = (blockIdx.x & 3) * 16 + tx, oy = blockIdx.y * 8 + ty;
    const int bz = blockIdx.z;
    const int b = bz / 5, oz = bz % 5;
    const int iz0 = 2 * oz, iyb = 2 * oy - 1, ixb = 2 * ox - 1;   // z pad 0

    float acc[16];
#pragma unroll
    for (int oc = 0; oc < 16; ++oc) acc[oc] = 0.f;
    float msum = 0.f;

#pragma unroll 1
    for (int kz = 0; kz < 3; ++kz) {
        const int iz = iz0 + kz;                       // always in [0,10]
#pragma unroll 1
        for (int ky = 0; ky < 3; ++ky) {
            const int iy = iyb + ky;
#pragma unroll 1
            for (int kx = 0; kx < 3; ++kx) {
                const int ix = ixb + kx;
                const bool ok = (unsigned)iy < 128u && (unsigned)ix < 128u;
                if (ok) {
                    const int sp = iz * 16384 + iy * 128 + ix;
                    msum += m2[b * 180224 + sp];
                    const int tap = (kz * 3 + ky) * 3 + kx;
                    const float* __restrict__ wq = wT3 + tap * 2048 + ocg * 16; // uniform
#pragma unroll
                    for (int q = 0; q < 8; ++q) {
                        const float4 a = h2q[(b * 8 + q) * 180224 + sp];
                        const int c0 = q * 4;
#pragma unroll
                        for (int oc = 0; oc < 16; ++oc) {
                            acc[oc] = fmaf(wq[(c0 + 0) * 64 + oc], a.x,
                                      fmaf(wq[(c0 + 1) * 64 + oc], a.y,
                                      fmaf(wq[(c0 + 2) * 64 + oc], a.z,
                                      fmaf(wq[(c0 + 3) * 64 + oc], a.w, acc[oc]))));
                        }
                    }
                }
            }
        }
    }

    const float mout = msum > 0.f ? 1.f : 0.f;
    const int spo = oz * 4096 + oy * 64 + ox;
    if (ocg == 0) m3[b * 20480 + spo] = mout;
#pragma unroll
    for (int oc = 0; oc < 16; ++oc) {
        const int ocg16 = ocg * 16 + oc;
        h3[(b * 64 + ocg16) * 20480 + spo] =
            fmaxf(acc[oc] + shb[32 + ocg16], 0.f) * mout;
    }
}

// ---------------- Layer 4: conv 64->64, k(3,1,1), s(2,1,1), pad 0 ----------------
// 16 oc-groups of 4: 4096 waves = 16/CU (8-way was latency-exposed at 8/CU).
__global__ __launch_bounds__(256) __attribute__((amdgpu_waves_per_eu(4, 8)))
void conv_l4(
    const float* __restrict__ h3, const float* __restrict__ m3,
    const float* __restrict__ wT4, const float* __restrict__ shb,
    float* __restrict__ out)
{
    const int p = blockIdx.x * 256 + threadIdx.x;  // 0..4095 spatial
    const int bo = blockIdx.y;                     // b(2) x od(2) x ocg(16)
    const int b = bo >> 5, od = (bo >> 4) & 1, ocg = bo & 15;

    const float msum = m3[(b * 5 + 2 * od + 0) * 4096 + p] +
                       m3[(b * 5 + 2 * od + 1) * 4096 + p] +
                       m3[(b * 5 + 2 * od + 2) * 4096 + p];
    const float mout = msum > 0.f ? 1.f : 0.f;

    float acc[4];
#pragma unroll
    for (int oc = 0; oc < 4; ++oc) acc[oc] = 0.f;

#pragma unroll 1
    for (int c = 0; c < 64; ++c) {
        const float v0 = h3[((b * 64 + c) * 5 + 2 * od + 0) * 4096 + p];
        const float v1 = h3[((b * 64 + c) * 5 + 2 * od + 1) * 4096 + p];
        const float v2 = h3[((b * 64 + c) * 5 + 2 * od + 2) * 4096 + p];
        const float* __restrict__ wq = wT4 + c * 192 + ocg * 4;  // block-uniform
#pragma unroll
        for (int oc = 0; oc < 4; ++oc) {
            acc[oc] = fmaf(wq[oc], v0,
                      fmaf(wq[64 + oc], v1,
                      fmaf(wq[128 + oc], v2, acc[oc])));
        }
    }

#pragma unroll
    for (int oc = 0; oc < 4; ++oc) {
        const int ocgl = ocg * 4 + oc;
        out[((b * 64 + ocgl) * 2 + od) * 4096 + p] =
            fmaxf(acc[oc] + shb[96 + ocgl], 0.f) * mout;
    }
}

extern "C" void kernel_launch(void* const* d_in, const int* in_sizes, int n_in,
                              void* d_out, int out_size, void* d_ws, size_t ws_size,
                              hipStream_t stream)
{
    const float* vf    = (const float*)d_in[0];
    const int*   coors = (const int*)d_in[1];
    // d_in[2] = batch_size (==2, hardcoded in geometry)
    const float* w1 = (const float*)d_in[3];
    const float* g1 = (const float*)d_in[4];
    const float* b1 = (const float*)d_in[5];
    const float* rm1 = (const float*)d_in[6];
    const float* rv1 = (const float*)d_in[7];
    const float* w2 = (const float*)d_in[8];
    const float* g2 = (const float*)d_in[9];
    const float* b2 = (const float*)d_in[10];
    const float* rm2 = (const float*)d_in[11];
    const float* rv2 = (const float*)d_in[12];
    const float* w3 = (const float*)d_in[13];
    const float* g3 = (const float*)d_in[14];
    const float* b3 = (const float*)d_in[15];
    const float* rm3 = (const float*)d_in[16];
    const float* rv3 = (const float*)d_in[17];
    const float* w4 = (const float*)d_in[18];
    const float* g4 = (const float*)d_in[19];
    const float* b4 = (const float*)d_in[20];
    const float* rm4 = (const float*)d_in[21];
    const float* rv4 = (const float*)d_in[22];

    const int NV = in_sizes[0] / 3;

    float* ws = (float*)d_ws;
    float* y1  = ws;                   // 22,020,096 f-slots = bf16 (2,21,256,256,16)
    float* m1  = y1 + 22020096;        //  2,752,512 f  (2,21,256,256)
    float* h2q = m1 + 2752512;         // 11,534,336 f  (2,8,11,128,128,4) interleaved
    float* m2  = h2q + 11534336;       //    360,448 f  (2,11,128,128)
    float* h3  = m2 + 360448;          //  2,621,440 f  (2,64,5,64,64)
    float* m3  = h3 + 2621440;         //     40,960 f  (2,5,64,64)
    float* wT2 = m3 + 40960;           //     13,824 f
    float* wT3 = wT2 + 13824;          //     55,296 f
    float* wT4 = wT3 + 55296;          //     12,288 f
    float* shb = wT4 + 12288;          //        192 f

    // zero the scatter accumulator (bf16) + mask (contiguous)
    hipMemsetAsync(y1, 0, (size_t)(22020096 + 2752512) * sizeof(float), stream);

    repack<<<319, 256, 0, stream>>>(g1, b1, rm1, rv1,
                                    w2, g2, b2, rm2, rv2, w3, g3, b3, rm3, rv3,
                                    w4, g4, b4, rm4, rv4, wT2, wT3, wT4, shb);
    scatter_l1<<<(NV * 8 + 255) / 256, 256, 0, stream>>>(vf, coors, NV, w1,
                                                         (unsigned short*)y1, m1);
    conv_l2<<<dim3(16, 16, 22), 128, 0, stream>>>((const uint4*)y1, m1, wT2, shb,
                                                  (float4*)h2q, m2);
    conv_l3<<<dim3(16, 8, 10), 128, 0, stream>>>((const float4*)h2q, m2, wT3, shb,
                                                 h3, m3);
    conv_l4<<<dim3(16, 64), 256, 0, stream>>>(h3, m3, wT4, shb, (float*)d_out);
}

// Round 16
// 385.483 us; speedup vs baseline: 1.0389x; 1.0389x over previous
//
#include <hip/hip_runtime.h>

#define EPS 1e-3f

// Tensor geometry (fixed for this problem):
// y1 (L1 pre-act): bf16 channel-last (2, 21,256,256, 16)  -- 32 B per cell
// m1: (2,21,256,256) fp32
// h2q: quad-interleaved fp32 (2, 8, 11,128,128, 4)   m2: (2,11,128,128)
// h3:  (2,64,5,64,64)  m3: (2,5,64,64)
// out: (2,64,2,64,64) -> d_out (2,128,64,64) same layout
//
// Lessons encoded:
//  - Block-uniform weight pointers only (scalar s_load path). (r2)
//  - Direct conv beats phase-barrier LDS staging here. (r10)
//  - conv_l2 is effectively dense (m1 ~13.7%, E[taps/px]=3.7): sparse wave-per-px
//    lost to per-wave overhead (r12); early-out lost to branch cost (r14);
//    4-way conv_l3 split lost waves (r14). r13's configuration is the knee.
//  - Scatter: bf16 channel-last y1 + packed bf16 atomics (request-bound). (r13)
//  - conv_l2 is VALU-ISSUE bound (77% busy, ~58us FMA floor of 127us): cut
//    issue count with v_dot2_f32_f16 packed pairs (304->184 instr/tap). (r15)

// f32 -> bf16 (RNE)
static __device__ __forceinline__ unsigned f2bf(float f) {
    unsigned u = __float_as_uint(f);
    return (u + 0x7FFFu + ((u >> 16) & 1u)) >> 16;
}

typedef _Float16 half2v __attribute__((ext_vector_type(2)));

// ---------------- Weight repack + BN fold ----------------
// wT2h: half2 [tap][cp][oc] 27x8x32 (cin-pairs, BN-folded, f16)
// wT3: [tap][cin][oc] 27x32x64; wT4: [(c*3+kz)*64+oc]
// shb: [0..31]=sh2, [32..95]=sh3, [96..159]=sh4, [160..175]=sc1, [176..191]=sh1
__global__ __launch_bounds__(256) void repack(
    const float* __restrict__ g1, const float* __restrict__ b1,
    const float* __restrict__ rm1, const float* __restrict__ rv1,
    const float* __restrict__ w2, const float* __restrict__ g2, const float* __restrict__ b2,
    const float* __restrict__ rm2, const float* __restrict__ rv2,
    const float* __restrict__ w3, const float* __restrict__ g3, const float* __restrict__ b3,
    const float* __restrict__ rm3, const float* __restrict__ rv3,
    const float* __restrict__ w4, const float* __restrict__ g4, const float* __restrict__ b4,
    const float* __restrict__ rm4, const float* __restrict__ rv4,
    half2v* __restrict__ wT2h, float* __restrict__ wT3, float* __restrict__ wT4,
    float* __restrict__ shb)
{
    const int i = blockIdx.x * 256 + threadIdx.x;
    if (i < 6912) {                        // wT2h[tap*256 + cp*32 + oc]
        const int tap = i / 256, cp = (i / 32) % 8, oc = i & 31;
        const float inv = g2[oc] * rsqrtf(rv2[oc] + EPS);
        const float wa = w2[(oc * 16 + 2 * cp) * 27 + tap] * inv;
        const float wb = w2[(oc * 16 + 2 * cp + 1) * 27 + tap] * inv;
        half2v h;
        h.x = (_Float16)wa;
        h.y = (_Float16)wb;
        wT2h[i] = h;
    } else if (i < 62208) {                // wT3[tap*2048 + cin*64 + oc]
        const int j = i - 6912;
        const int tap = j / 2048, cin = (j / 64) % 32, oc = j & 63;
        const float inv = g3[oc] * rsqrtf(rv3[oc] + EPS);
        wT3[j] = w3[(oc * 32 + cin) * 27 + tap] * inv;
    } else if (i < 74496) {                // wT4[(c*3+kz)*64+oc], 64x3x64
        const int j = i - 62208;
        const int c = j / 192, kz = (j / 64) % 3, oc = j & 63;
        const float inv = g4[oc] * rsqrtf(rv4[oc] + EPS);
        wT4[j] = w4[(oc * 64 + c) * 3 + kz] * inv;
    } else if (i < 74688) {                // shifts + L1 BN scale/shift
        const int j = i - 74496;
        if (j < 32) {
            const float inv = g2[j] * rsqrtf(rv2[j] + EPS);
            shb[j] = b2[j] - rm2[j] * inv;
        } else if (j < 96) {
            const int o = j - 32;
            const float inv = g3[o] * rsqrtf(rv3[o] + EPS);
            shb[j] = b3[o] - rm3[o] * inv;
        } else if (j < 160) {
            const int o = j - 96;
            const float inv = g4[o] * rsqrtf(rv4[o] + EPS);
            shb[j] = b4[o] - rm4[o] * inv;
        } else if (j < 176) {
            const int o = j - 160;
            shb[j] = g1[o] * rsqrtf(rv1[o] + EPS);           // sc1
        } else if (j < 192) {
            const int o = j - 176;
            const float inv = g1[o] * rsqrtf(rv1[o] + EPS);
            shb[j] = b1[o] - rm1[o] * inv;                   // sh1
        }
    }
}

// ---------------- Layer 1: voxel scatter, one thread per (voxel, oc-pair) ----------------
// y1 bf16 channel-last: cell = 32 B contiguous; one packed-bf16 atomic adds 2 ch.
__global__ __launch_bounds__(256) void scatter_l1(
    const float* __restrict__ vf, const int* __restrict__ coors, int NV,
    const float* __restrict__ w1, unsigned short* __restrict__ y1,
    float* __restrict__ m1)
{
    __shared__ float ws[16 * 3 * 27];  // (oc, c, tap)
    for (int e = threadIdx.x; e < 16 * 3 * 27; e += 256) ws[e] = w1[e];
    __syncthreads();

    const int gid = blockIdx.x * 256 + threadIdx.x;
    const int i = gid >> 3;        // voxel
    const int oc2 = gid & 7;       // channel pair
    if (i >= NV) return;
    const int oc = oc2 * 2;

    const int b = coors[4 * i + 0];
    const int z = coors[4 * i + 1];
    const int y = coors[4 * i + 2];
    const int x = coors[4 * i + 3];
    const float f0 = vf[3 * i + 0];
    const float f1 = vf[3 * i + 1];
    const float f2 = vf[3 * i + 2];

    int ozv[2], kzv[2], nz = 0;
    int oyv[2], kyv[2], ny = 0;
    int oxv[2], kxv[2], nx = 0;
#pragma unroll
    for (int k = 0; k < 3; ++k) {
        int t = z + 1 - k;
        if (t >= 0 && !(t & 1)) { int o = t >> 1; if (o < 21) { ozv[nz] = o; kzv[nz] = k; ++nz; } }
    }
#pragma unroll
    for (int k = 0; k < 3; ++k) {
        int t = y + 1 - k;
        if (t >= 0 && !(t & 1)) { int o = t >> 1; if (o < 256) { oyv[ny] = o; kyv[ny] = k; ++ny; } }
    }
#pragma unroll
    for (int k = 0; k < 3; ++k) {
        int t = x + 1 - k;
        if (t >= 0 && !(t & 1)) { int o = t >> 1; if (o < 256) { oxv[nx] = o; kxv[nx] = k; ++nx; } }
    }

    for (int a = 0; a < nz; ++a)
        for (int bb = 0; bb < ny; ++bb)
            for (int c = 0; c < nx; ++c) {
                const int oz = ozv[a], oy = oyv[bb], ox = oxv[c];
                const int tap = (kzv[a] * 3 + kyv[bb]) * 3 + kxv[c];
                const int sp = oz * 65536 + oy * 256 + ox;
                if (oc2 == 0) m1[b * 1376256 + sp] = 1.0f;
                const float s0 = ws[oc * 81 + tap] * f0 + ws[oc * 81 + 27 + tap] * f1 +
                                 ws[oc * 81 + 54 + tap] * f2;
                const float s1 = ws[(oc + 1) * 81 + tap] * f0 +
                                 ws[(oc + 1) * 81 + 27 + tap] * f1 +
                                 ws[(oc + 1) * 81 + 54 + tap] * f2;
                const unsigned pk = f2bf(s0) | (f2bf(s1) << 16);
                unsigned* addr = (unsigned*)(y1 + (size_t)(b * 1376256 + sp) * 16 +
                                             oc2 * 2);
                asm volatile("global_atomic_pk_add_bf16 %0, %1, off"
                             : : "v"(addr), "v"(pk) : "memory");
            }
}

// ---------------- Layer 2: DIRECT conv 16->32 via v_dot2_f32_f16 ----------------
// One thread per (output px, 16-oc group). No LDS/barriers. 27 mask values
// preloaded; active taps: decode 16 bf16 cin -> BN/ReLU fp32 -> pack 8 half2 ->
// 128 fdot2 (2 MAC/instr) instead of 256 FMA. fp32 accumulation.
__global__ __launch_bounds__(128) __attribute__((amdgpu_waves_per_eu(4, 8)))
void conv_l2(
    const uint4* __restrict__ y1b, const float* __restrict__ m1,
    const half2v* __restrict__ wT2h, const float* __restrict__ shb,
    float4* __restrict__ h2q, float* __restrict__ m2)
{
    const int tid = threadIdx.x;
    const int tx = tid & 15, ty = tid >> 4;            // 16 x 8 px tile
    const int ocg = blockIdx.x >> 3;                   // 0..1 (16 oc each)
    const int ox = (blockIdx.x & 7) * 16 + tx, oy = blockIdx.y * 8 + ty;
    const int bz = blockIdx.z;
    const int b = bz / 11, oz = bz % 11;
    const int iz0 = 2 * oz - 1, iyb = 2 * oy - 1, ixb = 2 * ox - 1;

    // L1 BN params as uniforms -> SGPRs
    float sc1[16], sh1[16];
#pragma unroll
    for (int c = 0; c < 16; ++c) { sc1[c] = shb[160 + c]; sh1[c] = shb[176 + c]; }

    // preload 27 mask values (independent loads pipeline)
    float mv[27];
    float msum = 0.f;
#pragma unroll
    for (int kz = 0; kz < 3; ++kz) {
        const int iz = iz0 + kz;
#pragma unroll
        for (int ky = 0; ky < 3; ++ky) {
            const int iy = iyb + ky;
#pragma unroll
            for (int kx = 0; kx < 3; ++kx) {
                const int ix = ixb + kx;
                float m = 0.f;
                if ((unsigned)iz < 21u && (unsigned)iy < 256u && (unsigned)ix < 256u)
                    m = m1[b * 1376256 + iz * 65536 + iy * 256 + ix];
                mv[(kz * 3 + ky) * 3 + kx] = m;
                msum += m;
            }
        }
    }

    float acc[16];
#pragma unroll
    for (int oc = 0; oc < 16; ++oc) acc[oc] = 0.f;

#pragma unroll 1
    for (int kz = 0; kz < 3; ++kz) {
        const int iz = iz0 + kz;
#pragma unroll 1
        for (int ky = 0; ky < 3; ++ky) {
            const int iy = iyb + ky;
#pragma unroll 1
            for (int kx = 0; kx < 3; ++kx) {
                const int tap = (kz * 3 + ky) * 3 + kx;
                if (mv[tap] > 0.f) {
                    const int ix = ixb + kx;
                    const int cb = (b * 1376256 + iz * 65536 + iy * 256 + ix) * 2;
                    const uint4 u0 = y1b[cb];
                    const uint4 u1 = y1b[cb + 1];
                    const unsigned d[8] = {u0.x, u0.y, u0.z, u0.w,
                                           u1.x, u1.y, u1.z, u1.w};
                    // decode + BN/ReLU + pack to 8 half2
                    half2v hin[8];
#pragma unroll
                    for (int j = 0; j < 8; ++j) {
                        const int c0 = 2 * j;
                        const float vlo = __uint_as_float(d[j] << 16);
                        const float vhi = __uint_as_float(d[j] & 0xFFFF0000u);
                        const float v0 = fmaxf(vlo * sc1[c0] + sh1[c0], 0.f);
                        const float v1 = fmaxf(vhi * sc1[c0 + 1] + sh1[c0 + 1], 0.f);
                        hin[j] = __builtin_bit_cast(
                            half2v, __builtin_amdgcn_cvt_pkrtz(v0, v1));
                    }
                    const half2v* __restrict__ wq = wT2h + tap * 256 + ocg * 16;
#pragma unroll
                    for (int oc = 0; oc < 16; ++oc) {
                        float a = acc[oc];
#pragma unroll
                        for (int cp = 0; cp < 8; ++cp)
                            a = __builtin_amdgcn_fdot2(hin[cp], wq[cp * 32 + oc],
                                                       a, false);
                        acc[oc] = a;
                    }
                }
            }
        }
    }

    const float mout = msum > 0.f ? 1.f : 0.f;
    const int spo = oz * 16384 + oy * 128 + ox;
    if (ocg == 0) m2[b * 180224 + spo] = mout;
#pragma unroll
    for (int lq = 0; lq < 4; ++lq) {
        const int q = ocg * 4 + lq;
        float4 o;
        o.x = fmaxf(acc[lq * 4 + 0] + shb[ocg * 16 + lq * 4 + 0], 0.f) * mout;
        o.y = fmaxf(acc[lq * 4 + 1] + shb[ocg * 16 + lq * 4 + 1], 0.f) * mout;
        o.z = fmaxf(acc[lq * 4 + 2] + shb[ocg * 16 + lq * 4 + 2], 0.f) * mout;
        o.w = fmaxf(acc[lq * 4 + 3] + shb[ocg * 16 + lq * 4 + 3], 0.f) * mout;
        h2q[(b * 8 + q) * 180224 + spo] = o;
    }
}

// ---------------- Layer 3: DIRECT conv 32->64, k3, s2, pad(0,1,1) ----------------
// One thread per (output px, 8-oc group) -- r13 configuration (8-way split;
// 4-way halved waves and regressed, r14). Full 32-cin accumulation; fused epilogue.
__global__ __launch_bounds__(128) __attribute__((amdgpu_waves_per_eu(4, 8)))
void conv_l3(
    const float4* __restrict__ h2q, const float* __restrict__ m2,
    const float* __restrict__ wT3, const float* __restrict__ shb,
    float* __restrict__ h3, float* __restrict__ m3)
{
    const int tid = threadIdx.x;
    const int tx = tid & 15, ty = tid >> 4;            // 16 x 8 px tile
    const int ocg = blockIdx.x >> 2;                   // 0..7 (8 oc each)
    const int ox = (blockIdx.x & 3) * 16 + tx, oy = blockIdx.y * 8 + ty;
    const int bz = blockIdx.z;
    const int b = bz / 5, oz = bz % 5;
    const int iz0 = 2 * oz, iyb = 2 * oy - 1, ixb = 2 * ox - 1;   // z pad 0

    float acc[8];
#pragma unroll
    for (int oc = 0; oc < 8; ++oc) acc[oc] = 0.f;
    float msum = 0.f;

#pragma unroll 1
    for (int kz = 0; kz < 3; ++kz) {
        const int iz = iz0 + kz;                       // always in [0,10]
#pragma unroll 1
        for (int ky = 0; ky < 3; ++ky) {
            const int iy = iyb + ky;
#pragma unroll 1
            for (int kx = 0; kx < 3; ++kx) {
                const int ix = ixb + kx;
                const bool ok = (unsigned)iy < 128u && (unsigned)ix < 128u;
                if (ok) {
                    const int sp = iz * 16384 + iy * 128 + ix;
                    msum += m2[b * 180224 + sp];
                    const int tap = (kz * 3 + ky) * 3 + kx;
                    const float* __restrict__ wq = wT3 + tap * 2048 + ocg * 8; // uniform
#pragma unroll
                    for (int q = 0; q < 8; ++q) {
                        const float4 a = h2q[(b * 8 + q) * 180224 + sp];
                        const int c0 = q * 4;
#pragma unroll
                        for (int oc = 0; oc < 8; ++oc) {
                            acc[oc] = fmaf(wq[(c0 + 0) * 64 + oc], a.x,
                                      fmaf(wq[(c0 + 1) * 64 + oc], a.y,
                                      fmaf(wq[(c0 + 2) * 64 + oc], a.z,
                                      fmaf(wq[(c0 + 3) * 64 + oc], a.w, acc[oc]))));
                        }
                    }
                }
            }
        }
    }

    const float mout = msum > 0.f ? 1.f : 0.f;
    const int spo = oz * 4096 + oy * 64 + ox;
    if (ocg == 0) m3[b * 20480 + spo] = mout;
#pragma unroll
    for (int oc = 0; oc < 8; ++oc) {
        const int ocg8 = ocg * 8 + oc;
        h3[(b * 64 + ocg8) * 20480 + spo] =
            fmaxf(acc[oc] + shb[32 + ocg8], 0.f) * mout;
    }
}

// ---------------- Layer 4: conv 64->64, k(3,1,1), s(2,1,1), pad 0 ----------------
// r13 configuration (8 oc-groups of 8; 16-way regressed, r14).
__global__ __launch_bounds__(256) __attribute__((amdgpu_waves_per_eu(4, 8)))
void conv_l4(
    const float* __restrict__ h3, const float* __restrict__ m3,
    const float* __restrict__ wT4, const float* __restrict__ shb,
    float* __restrict__ out)
{
    const int p = blockIdx.x * 256 + threadIdx.x;  // 0..4095 spatial
    const int bo = blockIdx.y;
    const int b = bo >> 4, od = (bo >> 3) & 1, ocg = bo & 7;

    const float msum = m3[(b * 5 + 2 * od + 0) * 4096 + p] +
                       m3[(b * 5 + 2 * od + 1) * 4096 + p] +
                       m3[(b * 5 + 2 * od + 2) * 4096 + p];
    const float mout = msum > 0.f ? 1.f : 0.f;

    float acc[8];
#pragma unroll
    for (int oc = 0; oc < 8; ++oc) acc[oc] = 0.f;

#pragma unroll 1
    for (int c = 0; c < 64; ++c) {
        const float v0 = h3[((b * 64 + c) * 5 + 2 * od + 0) * 4096 + p];
        const float v1 = h3[((b * 64 + c) * 5 + 2 * od + 1) * 4096 + p];
        const float v2 = h3[((b * 64 + c) * 5 + 2 * od + 2) * 4096 + p];
        const float* __restrict__ wq = wT4 + c * 192 + ocg * 8;  // block-uniform
#pragma unroll
        for (int oc = 0; oc < 8; ++oc) {
            acc[oc] = fmaf(wq[oc], v0,
                      fmaf(wq[64 + oc], v1,
                      fmaf(wq[128 + oc], v2, acc[oc])));
        }
    }

#pragma unroll
    for (int oc = 0; oc < 8; ++oc) {
        const int ocgl = ocg * 8 + oc;
        out[((b * 64 + ocgl) * 2 + od) * 4096 + p] =
            fmaxf(acc[oc] + shb[96 + ocgl], 0.f) * mout;
    }
}

extern "C" void kernel_launch(void* const* d_in, const int* in_sizes, int n_in,
                              void* d_out, int out_size, void* d_ws, size_t ws_size,
                              hipStream_t stream)
{
    const float* vf    = (const float*)d_in[0];
    const int*   coors = (const int*)d_in[1];
    // d_in[2] = batch_size (==2, hardcoded in geometry)
    const float* w1 = (const float*)d_in[3];
    const float* g1 = (const float*)d_in[4];
    const float* b1 = (const float*)d_in[5];
    const float* rm1 = (const float*)d_in[6];
    const float* rv1 = (const float*)d_in[7];
    const float* w2 = (const float*)d_in[8];
    const float* g2 = (const float*)d_in[9];
    const float* b2 = (const float*)d_in[10];
    const float* rm2 = (const float*)d_in[11];
    const float* rv2 = (const float*)d_in[12];
    const float* w3 = (const float*)d_in[13];
    const float* g3 = (const float*)d_in[14];
    const float* b3 = (const float*)d_in[15];
    const float* rm3 = (const float*)d_in[16];
    const float* rv3 = (const float*)d_in[17];
    const float* w4 = (const float*)d_in[18];
    const float* g4 = (const float*)d_in[19];
    const float* b4 = (const float*)d_in[20];
    const float* rm4 = (const float*)d_in[21];
    const float* rv4 = (const float*)d_in[22];

    const int NV = in_sizes[0] / 3;

    float* ws = (float*)d_ws;
    float* y1  = ws;                   // 22,020,096 f-slots = bf16 (2,21,256,256,16)
    float* m1  = y1 + 22020096;        //  2,752,512 f  (2,21,256,256)
    float* h2q = m1 + 2752512;         // 11,534,336 f  (2,8,11,128,128,4) interleaved
    float* m2  = h2q + 11534336;       //    360,448 f  (2,11,128,128)
    float* h3  = m2 + 360448;          //  2,621,440 f  (2,64,5,64,64)
    float* m3  = h3 + 2621440;         //     40,960 f  (2,5,64,64)
    float* wT2h = m3 + 40960;          //      6,912 f-slots (half2 27x8x32)
    float* wT3 = wT2h + 6912;          //     55,296 f
    float* wT4 = wT3 + 55296;          //     12,288 f
    float* shb = wT4 + 12288;          //        192 f

    // zero the scatter accumulator (bf16) + mask (contiguous)
    (void)hipMemsetAsync(y1, 0, (size_t)(22020096 + 2752512) * sizeof(float), stream);

    repack<<<292, 256, 0, stream>>>(g1, b1, rm1, rv1,
                                    w2, g2, b2, rm2, rv2, w3, g3, b3, rm3, rv3,
                                    w4, g4, b4, rm4, rv4,
                                    (half2v*)wT2h, wT3, wT4, shb);
    scatter_l1<<<(NV * 8 + 255) / 256, 256, 0, stream>>>(vf, coors, NV, w1,
                                                         (unsigned short*)y1, m1);
    conv_l2<<<dim3(16, 16, 22), 128, 0, stream>>>((const uint4*)y1, m1,
                                                  (const half2v*)wT2h, shb,
                                                  (float4*)h2q, m2);
    conv_l3<<<dim3(32, 8, 10), 128, 0, stream>>>((const float4*)h2q, m2, wT3, shb,
                                                 h3, m3);
    conv_l4<<<dim3(16, 32), 256, 0, stream>>>(h3, m3, wT4, shb, (float*)d_out);
}

// Round 17
// 354.050 us; speedup vs baseline: 1.1312x; 1.0888x over previous
//
#include <hip/hip_runtime.h>

#define EPS 1e-3f

// Tensor geometry (fixed for this problem):
// y1/h1: f16-convertible channel-last (2, 21,256,256, 16) -- 32 B per cell.
//   Scatter accumulates bf16; h1_pass converts IN PLACE to f16 relu(bn(y1))*m1.
// m1: (2,21,256,256) fp32;  m2: (2,11,128,128) fp32 (built by build_m2)
// h2q: quad-interleaved fp32 (2, 8, 11,128,128, 4)
// h3: (2,64,5,64,64)  m3: (2,5,64,64);  out: (2,128,64,64)
//
// Lessons encoded:
//  - Block-uniform weight pointers (scalar path) for VALU convs. (r2)
//  - Direct conv beats phase-barrier LDS staging for VALU convs. (r10)
//  - conv_l2 is effectively dense; its VALU formulation plateaued at ~126us
//    (VALUBusy ~80%, fdot2 neutral r16). Only lever left: matrix pipe. (r17)
//  - MFMA implicit GEMM: A[m=lane&15][k=quad*8+j] (guide-verified layout),
//    C/D col=lane&15,row=quad*4+reg. K=27x16=432 -> 14 chunks of 32. (r17)
//  - Scatter: bf16 channel-last y1 + packed bf16 atomics. (r13)

// f32 -> bf16 (RNE)
static __device__ __forceinline__ unsigned f2bf(float f) {
    unsigned u = __float_as_uint(f);
    return (u + 0x7FFFu + ((u >> 16) & 1u)) >> 16;
}

typedef _Float16 f16x8 __attribute__((ext_vector_type(8)));
typedef float f32x4 __attribute__((ext_vector_type(4)));

// ---------------- Weight repack + BN fold ----------------
// wB2: f16 MFMA B-fragments [chunk(14)][tile(2)][lane(64)][8]
//      lane: q=lane>>4, n=lane&15; oc=tile*16+n; tap=2c+(q>>1); cin=(q&1)*8+j
// wT3: [tap][cin][oc] 27x32x64; wT4: [(c*3+kz)*64+oc]
// shb: [0..31]=sh2, [32..95]=sh3, [96..159]=sh4, [160..175]=sc1, [176..191]=sh1
__global__ __launch_bounds__(256) void repack(
    const float* __restrict__ g1, const float* __restrict__ b1,
    const float* __restrict__ rm1, const float* __restrict__ rv1,
    const float* __restrict__ w2, const float* __restrict__ g2, const float* __restrict__ b2,
    const float* __restrict__ rm2, const float* __restrict__ rv2,
    const float* __restrict__ w3, const float* __restrict__ g3, const float* __restrict__ b3,
    const float* __restrict__ rm3, const float* __restrict__ rv3,
    const float* __restrict__ w4, const float* __restrict__ g4, const float* __restrict__ b4,
    const float* __restrict__ rm4, const float* __restrict__ rv4,
    _Float16* __restrict__ wB2, float* __restrict__ wT3, float* __restrict__ wT4,
    float* __restrict__ shb)
{
    const int i = blockIdx.x * 256 + threadIdx.x;
    if (i < 14336) {                       // wB2 value v
        const int j = i & 7, lane = (i >> 3) & 63, t = (i >> 9) & 1, c = i >> 10;
        const int q = lane >> 4, n = lane & 15;
        const int oc = t * 16 + n;
        const int tap = 2 * c + (q >> 1);
        const int cin = (q & 1) * 8 + j;
        float val = 0.f;
        if (tap < 27) {
            const float inv = g2[oc] * rsqrtf(rv2[oc] + EPS);
            val = w2[(oc * 16 + cin) * 27 + tap] * inv;
        }
        wB2[i] = (_Float16)val;
    } else if (i < 69632) {                // wT3[tap*2048 + cin*64 + oc]
        const int j = i - 14336;
        const int tap = j / 2048, cin = (j / 64) % 32, oc = j & 63;
        const float inv = g3[oc] * rsqrtf(rv3[oc] + EPS);
        wT3[j] = w3[(oc * 32 + cin) * 27 + tap] * inv;
    } else if (i < 81920) {                // wT4[(c*3+kz)*64+oc], 64x3x64
        const int j = i - 69632;
        const int c = j / 192, kz = (j / 64) % 3, oc = j & 63;
        const float inv = g4[oc] * rsqrtf(rv4[oc] + EPS);
        wT4[j] = w4[(oc * 64 + c) * 3 + kz] * inv;
    } else if (i < 82112) {                // shifts + L1 BN scale/shift
        const int j = i - 81920;
        if (j < 32) {
            const float inv = g2[j] * rsqrtf(rv2[j] + EPS);
            shb[j] = b2[j] - rm2[j] * inv;
        } else if (j < 96) {
            const int o = j - 32;
            const float inv = g3[o] * rsqrtf(rv3[o] + EPS);
            shb[j] = b3[o] - rm3[o] * inv;
        } else if (j < 160) {
            const int o = j - 96;
            const float inv = g4[o] * rsqrtf(rv4[o] + EPS);
            shb[j] = b4[o] - rm4[o] * inv;
        } else if (j < 176) {
            const int o = j - 160;
            shb[j] = g1[o] * rsqrtf(rv1[o] + EPS);           // sc1
        } else if (j < 192) {
            const int o = j - 176;
            const float inv = g1[o] * rsqrtf(rv1[o] + EPS);
            shb[j] = b1[o] - rm1[o] * inv;                   // sh1
        }
    }
}

// ---------------- Layer 1: voxel scatter, one thread per (voxel, oc-pair) ----------------
__global__ __launch_bounds__(256) void scatter_l1(
    const float* __restrict__ vf, const int* __restrict__ coors, int NV,
    const float* __restrict__ w1, unsigned short* __restrict__ y1,
    float* __restrict__ m1)
{
    __shared__ float ws[16 * 3 * 27];  // (oc, c, tap)
    for (int e = threadIdx.x; e < 16 * 3 * 27; e += 256) ws[e] = w1[e];
    __syncthreads();

    const int gid = blockIdx.x * 256 + threadIdx.x;
    const int i = gid >> 3;        // voxel
    const int oc2 = gid & 7;       // channel pair
    if (i >= NV) return;
    const int oc = oc2 * 2;

    const int b = coors[4 * i + 0];
    const int z = coors[4 * i + 1];
    const int y = coors[4 * i + 2];
    const int x = coors[4 * i + 3];
    const float f0 = vf[3 * i + 0];
    const float f1 = vf[3 * i + 1];
    const float f2 = vf[3 * i + 2];

    int ozv[2], kzv[2], nz = 0;
    int oyv[2], kyv[2], ny = 0;
    int oxv[2], kxv[2], nx = 0;
#pragma unroll
    for (int k = 0; k < 3; ++k) {
        int t = z + 1 - k;
        if (t >= 0 && !(t & 1)) { int o = t >> 1; if (o < 21) { ozv[nz] = o; kzv[nz] = k; ++nz; } }
    }
#pragma unroll
    for (int k = 0; k < 3; ++k) {
        int t = y + 1 - k;
        if (t >= 0 && !(t & 1)) { int o = t >> 1; if (o < 256) { oyv[ny] = o; kyv[ny] = k; ++ny; } }
    }
#pragma unroll
    for (int k = 0; k < 3; ++k) {
        int t = x + 1 - k;
        if (t >= 0 && !(t & 1)) { int o = t >> 1; if (o < 256) { oxv[nx] = o; kxv[nx] = k; ++nx; } }
    }

    for (int a = 0; a < nz; ++a)
        for (int bb = 0; bb < ny; ++bb)
            for (int c = 0; c < nx; ++c) {
                const int oz = ozv[a], oy = oyv[bb], ox = oxv[c];
                const int tap = (kzv[a] * 3 + kyv[bb]) * 3 + kxv[c];
                const int sp = oz * 65536 + oy * 256 + ox;
                if (oc2 == 0) m1[b * 1376256 + sp] = 1.0f;
                const float s0 = ws[oc * 81 + tap] * f0 + ws[oc * 81 + 27 + tap] * f1 +
                                 ws[oc * 81 + 54 + tap] * f2;
                const float s1 = ws[(oc + 1) * 81 + tap] * f0 +
                                 ws[(oc + 1) * 81 + 27 + tap] * f1 +
                                 ws[(oc + 1) * 81 + 54 + tap] * f2;
                const unsigned pk = f2bf(s0) | (f2bf(s1) << 16);
                unsigned* addr = (unsigned*)(y1 + (size_t)(b * 1376256 + sp) * 16 +
                                             oc2 * 2);
                asm volatile("global_atomic_pk_add_bf16 %0, %1, off"
                             : : "v"(addr), "v"(pk) : "memory");
            }
}

// ---------------- h1 pass: y1(bf16) -> h1(f16) = relu(bn(y1))*m1, IN PLACE ----------------
__global__ __launch_bounds__(256) void h1_pass(
    uint4* __restrict__ y1b, const float* __restrict__ m1,
    const float* __restrict__ shb)
{
    const int idx = blockIdx.x * 256 + threadIdx.x;   // < 2,752,512 cells
    const float mv = m1[idx];
    uint4 u0 = y1b[idx * 2], u1 = y1b[idx * 2 + 1];
    const unsigned d[8] = {u0.x, u0.y, u0.z, u0.w, u1.x, u1.y, u1.z, u1.w};
    unsigned o[8];
#pragma unroll
    for (int j = 0; j < 8; ++j) {
        const int c0 = 2 * j;
        const float vlo = __uint_as_float(d[j] << 16);
        const float vhi = __uint_as_float(d[j] & 0xFFFF0000u);
        const float v0 = fmaxf(vlo * shb[160 + c0] + shb[176 + c0], 0.f) * mv;
        const float v1 = fmaxf(vhi * shb[160 + c0 + 1] + shb[176 + c0 + 1], 0.f) * mv;
        o[j] = __builtin_bit_cast(unsigned, __builtin_amdgcn_cvt_pkrtz(v0, v1));
    }
    uint4 w0, w1;
    w0.x = o[0]; w0.y = o[1]; w0.z = o[2]; w0.w = o[3];
    w1.x = o[4]; w1.y = o[5]; w1.z = o[6]; w1.w = o[7];
    y1b[idx * 2] = w0;
    y1b[idx * 2 + 1] = w1;
}

// ---------------- build m2: per-l2-px "any of 27 taps active" ----------------
__global__ __launch_bounds__(256) void build_m2(
    const float* __restrict__ m1, float* __restrict__ m2)
{
    const int idx = blockIdx.x * 256 + threadIdx.x;       // < 360448
    if (idx >= 360448) return;
    const int b = idx / 180224;
    const int r = idx - b * 180224;
    const int oz = r >> 14, r2 = r & 16383, oy = r2 >> 7, ox = r2 & 127;
    const int iz0 = 2 * oz - 1, iyb = 2 * oy - 1, ixb = 2 * ox - 1;

    float msum = 0.f;
#pragma unroll
    for (int kz = 0; kz < 3; ++kz) {
        const int iz = iz0 + kz;
#pragma unroll
        for (int ky = 0; ky < 3; ++ky) {
            const int iy = iyb + ky;
#pragma unroll
            for (int kx = 0; kx < 3; ++kx) {
                const int ix = ixb + kx;
                if ((unsigned)iz < 21u && (unsigned)iy < 256u && (unsigned)ix < 256u)
                    msum += m1[b * 1376256 + iz * 65536 + iy * 256 + ix];
            }
        }
    }
    m2[idx] = msum > 0.f ? 1.f : 0.f;
}

// ---------------- Layer 2: implicit-GEMM MFMA conv 16->32 ----------------
// One wave per 16-px x-strip; 2 N-tiles of 16 oc. K = 28 taps x 16 cin (tap 27
// zero-weighted) = 14 chunks of K=32. A from h1 (f16 cells); B from wB2.
__global__ __launch_bounds__(256) void conv_l2(
    const unsigned char* __restrict__ h1,   // f16 cells, byte-addressed
    const uint4* __restrict__ wB2,
    const float* __restrict__ m2, const float* __restrict__ shb,
    float* __restrict__ h2q_f)
{
    const int tid = threadIdx.x;
    const int gw = blockIdx.x * 4 + (tid >> 6);     // 0..22527
    const int lane = tid & 63;
    const int m = lane & 15, q = lane >> 4;

    const int plane = gw >> 10;                     // b*11+oz
    const int rem = gw & 1023;
    const int oy = rem >> 3;
    const int ox0 = (rem & 7) * 16;
    const int b = plane / 11, oz = plane % 11;
    const int iz0 = 2 * oz - 1, iyb = 2 * oy - 1;
    const int ixm = 2 * (ox0 + m) - 1;              // per-lane input x base
    const int bbase = b * 1376256;

    f32x4 acc0 = {0.f, 0.f, 0.f, 0.f}, acc1 = {0.f, 0.f, 0.f, 0.f};
    const int qsel = q >> 1;          // 0: even tap of chunk, 1: odd tap
    const int qoff = (q & 1) * 16;    // byte offset within cell (cin half)

#pragma unroll
    for (int c = 0; c < 14; ++c) {
        const int t0 = 2 * c;
        const int t1 = (2 * c + 1 < 27) ? 2 * c + 1 : 26;   // clamp pad tap addr
        const int kz0 = t0 / 9, ky0 = (t0 / 3) % 3, kx0 = t0 % 3;
        const int kz1 = t1 / 9, ky1 = (t1 / 3) % 3, kx1 = t1 % 3;
        const int izA = iz0 + kz0, iyA = iyb + ky0, ixA = ixm + kx0;
        const int izB = iz0 + kz1, iyB = iyb + ky1, ixB = ixm + kx1;
        const bool vA = (unsigned)izA < 21u && (unsigned)iyA < 256u &&
                        (unsigned)ixA < 256u;
        const bool vB = (unsigned)izB < 21u && (unsigned)iyB < 256u &&
                        (unsigned)ixB < 256u;
        const int cellA = bbase + izA * 65536 + iyA * 256 + ixA;
        const int cellB = bbase + izB * 65536 + iyB * 256 + ixB;
        const bool v = qsel ? vB : vA;
        const int cell = qsel ? cellB : cellA;
        const int addr = v ? (cell * 32 + qoff) : 0;
        uint4 ua = *(const uint4*)(h1 + addr);
        if (!v) { ua.x = 0; ua.y = 0; ua.z = 0; ua.w = 0; }
        const f16x8 af = __builtin_bit_cast(f16x8, ua);
        const f16x8 bf0 = __builtin_bit_cast(f16x8, wB2[(c * 2 + 0) * 64 + lane]);
        const f16x8 bf1 = __builtin_bit_cast(f16x8, wB2[(c * 2 + 1) * 64 + lane]);
        acc0 = __builtin_amdgcn_mfma_f32_16x16x32_f16(af, bf0, acc0, 0, 0, 0);
        acc1 = __builtin_amdgcn_mfma_f32_16x16x32_f16(af, bf1, acc1, 0, 0, 0);
    }

    // epilogue: C/D layout col=lane&15 (oc within tile), row=q*4+r (px)
    const int n = lane & 15;
#pragma unroll
    for (int r = 0; r < 4; ++r) {
        const int px = ox0 + q * 4 + r;
        const int spo = oz * 16384 + oy * 128 + px;
        const float mv = m2[b * 180224 + spo];
        {
            const int oc = n;
            const float val = fmaxf(acc0[r] + shb[oc], 0.f) * mv;
            h2q_f[((b * 8 + (oc >> 2)) * 180224 + spo) * 4 + (oc & 3)] = val;
        }
        {
            const int oc = 16 + n;
            const float val = fmaxf(acc1[r] + shb[oc], 0.f) * mv;
            h2q_f[((b * 8 + (oc >> 2)) * 180224 + spo) * 4 + (oc & 3)] = val;
        }
    }
}

// ---------------- Layer 3: DIRECT conv 32->64, k3, s2, pad(0,1,1) ----------------
__global__ __launch_bounds__(128) __attribute__((amdgpu_waves_per_eu(4, 8)))
void conv_l3(
    const float4* __restrict__ h2q, const float* __restrict__ m2,
    const float* __restrict__ wT3, const float* __restrict__ shb,
    float* __restrict__ h3, float* __restrict__ m3)
{
    const int tid = threadIdx.x;
    const int tx = tid & 15, ty = tid >> 4;            // 16 x 8 px tile
    const int ocg = blockIdx.x >> 2;                   // 0..7 (8 oc each)
    const int ox = (blockIdx.x & 3) * 16 + tx, oy = blockIdx.y * 8 + ty;
    const int bz = blockIdx.z;
    const int b = bz / 5, oz = bz % 5;
    const int iz0 = 2 * oz, iyb = 2 * oy - 1, ixb = 2 * ox - 1;   // z pad 0

    float acc[8];
#pragma unroll
    for (int oc = 0; oc < 8; ++oc) acc[oc] = 0.f;
    float msum = 0.f;

#pragma unroll 1
    for (int kz = 0; kz < 3; ++kz) {
        const int iz = iz0 + kz;                       // always in [0,10]
#pragma unroll 1
        for (int ky = 0; ky < 3; ++ky) {
            const int iy = iyb + ky;
#pragma unroll 1
            for (int kx = 0; kx < 3; ++kx) {
                const int ix = ixb + kx;
                const bool ok = (unsigned)iy < 128u && (unsigned)ix < 128u;
                if (ok) {
                    const int sp = iz * 16384 + iy * 128 + ix;
                    msum += m2[b * 180224 + sp];
                    const int tap = (kz * 3 + ky) * 3 + kx;
                    const float* __restrict__ wq = wT3 + tap * 2048 + ocg * 8; // uniform
#pragma unroll
                    for (int qq = 0; qq < 8; ++qq) {
                        const float4 a = h2q[(b * 8 + qq) * 180224 + sp];
                        const int c0 = qq * 4;
#pragma unroll
                        for (int oc = 0; oc < 8; ++oc) {
                            acc[oc] = fmaf(wq[(c0 + 0) * 64 + oc], a.x,
                                      fmaf(wq[(c0 + 1) * 64 + oc], a.y,
                                      fmaf(wq[(c0 + 2) * 64 + oc], a.z,
                                      fmaf(wq[(c0 + 3) * 64 + oc], a.w, acc[oc]))));
                        }
                    }
                }
            }
        }
    }

    const float mout = msum > 0.f ? 1.f : 0.f;
    const int spo = oz * 4096 + oy * 64 + ox;
    if (ocg == 0) m3[b * 20480 + spo] = mout;
#pragma unroll
    for (int oc = 0; oc < 8; ++oc) {
        const int ocg8 = ocg * 8 + oc;
        h3[(b * 64 + ocg8) * 20480 + spo] =
            fmaxf(acc[oc] + shb[32 + ocg8], 0.f) * mout;
    }
}

// ---------------- Layer 4: conv 64->64, k(3,1,1), s(2,1,1), pad 0 ----------------
__global__ __launch_bounds__(256) __attribute__((amdgpu_waves_per_eu(4, 8)))
void conv_l4(
    const float* __restrict__ h3, const float* __restrict__ m3,
    const float* __restrict__ wT4, const float* __restrict__ shb,
    float* __restrict__ out)
{
    const int p = blockIdx.x * 256 + threadIdx.x;  // 0..4095 spatial
    const int bo = blockIdx.y;
    const int b = bo >> 4, od = (bo >> 3) & 1, ocg = bo & 7;

    const float msum = m3[(b * 5 + 2 * od + 0) * 4096 + p] +
                       m3[(b * 5 + 2 * od + 1) * 4096 + p] +
                       m3[(b * 5 + 2 * od + 2) * 4096 + p];
    const float mout = msum > 0.f ? 1.f : 0.f;

    float acc[8];
#pragma unroll
    for (int oc = 0; oc < 8; ++oc) acc[oc] = 0.f;

#pragma unroll 1
    for (int c = 0; c < 64; ++c) {
        const float v0 = h3[((b * 64 + c) * 5 + 2 * od + 0) * 4096 + p];
        const float v1 = h3[((b * 64 + c) * 5 + 2 * od + 1) * 4096 + p];
        const float v2 = h3[((b * 64 + c) * 5 + 2 * od + 2) * 4096 + p];
        const float* __restrict__ wq = wT4 + c * 192 + ocg * 8;  // block-uniform
#pragma unroll
        for (int oc = 0; oc < 8; ++oc) {
            acc[oc] = fmaf(wq[oc], v0,
                      fmaf(wq[64 + oc], v1,
                      fmaf(wq[128 + oc], v2, acc[oc])));
        }
    }

#pragma unroll
    for (int oc = 0; oc < 8; ++oc) {
        const int ocgl = ocg * 8 + oc;
        out[((b * 64 + ocgl) * 2 + od) * 4096 + p] =
            fmaxf(acc[oc] + shb[96 + ocgl], 0.f) * mout;
    }
}

extern "C" void kernel_launch(void* const* d_in, const int* in_sizes, int n_in,
                              void* d_out, int out_size, void* d_ws, size_t ws_size,
                              hipStream_t stream)
{
    const float* vf    = (const float*)d_in[0];
    const int*   coors = (const int*)d_in[1];
    // d_in[2] = batch_size (==2, hardcoded in geometry)
    const float* w1 = (const float*)d_in[3];
    const float* g1 = (const float*)d_in[4];
    const float* b1 = (const float*)d_in[5];
    const float* rm1 = (const float*)d_in[6];
    const float* rv1 = (const float*)d_in[7];
    const float* w2 = (const float*)d_in[8];
    const float* g2 = (const float*)d_in[9];
    const float* b2 = (const float*)d_in[10];
    const float* rm2 = (const float*)d_in[11];
    const float* rv2 = (const float*)d_in[12];
    const float* w3 = (const float*)d_in[13];
    const float* g3 = (const float*)d_in[14];
    const float* b3 = (const float*)d_in[15];
    const float* rm3 = (const float*)d_in[16];
    const float* rv3 = (const float*)d_in[17];
    const float* w4 = (const float*)d_in[18];
    const float* g4 = (const float*)d_in[19];
    const float* b4 = (const float*)d_in[20];
    const float* rm4 = (const float*)d_in[21];
    const float* rv4 = (const float*)d_in[22];

    const int NV = in_sizes[0] / 3;

    float* ws = (float*)d_ws;
    float* y1  = ws;                   // 22,020,096 f-slots: bf16->f16 (2,21,256,256,16)
    float* m1  = y1 + 22020096;        //  2,752,512 f  (2,21,256,256)
    float* h2q = m1 + 2752512;         // 11,534,336 f  (2,8,11,128,128,4) interleaved
    float* m2  = h2q + 11534336;       //    360,448 f  (2,11,128,128)
    float* h3  = m2 + 360448;          //  2,621,440 f  (2,64,5,64,64)
    float* m3  = h3 + 2621440;         //     40,960 f  (2,5,64,64)
    float* wB2 = m3 + 40960;           //      7,168 f-slots (14336 f16 MFMA frags)
    float* wT3 = wB2 + 7168;           //     55,296 f
    float* wT4 = wT3 + 55296;          //     12,288 f
    float* shb = wT4 + 12288;          //        192 f

    // zero the scatter accumulator (bf16) + mask (contiguous)
    (void)hipMemsetAsync(y1, 0, (size_t)(22020096 + 2752512) * sizeof(float), stream);

    repack<<<321, 256, 0, stream>>>(g1, b1, rm1, rv1,
                                    w2, g2, b2, rm2, rv2, w3, g3, b3, rm3, rv3,
                                    w4, g4, b4, rm4, rv4,
                                    (_Float16*)wB2, wT3, wT4, shb);
    scatter_l1<<<(NV * 8 + 255) / 256, 256, 0, stream>>>(vf, coors, NV, w1,
                                                         (unsigned short*)y1, m1);
    h1_pass<<<10752, 256, 0, stream>>>((uint4*)y1, m1, shb);
    build_m2<<<1408, 256, 0, stream>>>(m1, m2);
    conv_l2<<<5632, 256, 0, stream>>>((const unsigned char*)y1, (const uint4*)wB2,
                                      m2, shb, h2q);
    conv_l3<<<dim3(32, 8, 10), 128, 0, stream>>>((const float4*)h2q, m2, wT3, shb,
                                                 h3, m3);
    conv_l4<<<dim3(16, 32), 256, 0, stream>>>(h3, m3, wT4, shb, (float*)d_out);
}

// Round 18
// 274.608 us; speedup vs baseline: 1.4584x; 1.2893x over previous
//
#include <hip/hip_runtime.h>

#define EPS 1e-3f

// Tensor geometry (fixed for this problem):
// y1/h1: channel-last (2, 21,256,256, 16): scatter accumulates bf16;
//   h1_pass converts IN PLACE to f16 relu(bn(y1))*m1. 32 B per cell.
// m1: (2,21,256,256) fp32;  m2: (2,11,128,128) fp32;  m3: (2,5,64,64) fp32
// h2h: f16 channel-last (2, 11,128,128, 32) -- 64 B per cell
// h3: (2,64,5,64,64) fp32;  out: (2,128,64,64) fp32
//
// Lessons encoded:
//  - conv_l2/l3 are effectively dense; VALU formulations plateau (~126us l2,
//    ~115us l3). Implicit-GEMM MFMA (16x16x32 f16) is the pipe that wins:
//    conv_l2 dropped >6x in r17. A[m=lane&15][k=quad*8+j], C/D col=lane&15,
//    row=quad*4+reg -- verified by r17 passing. (r17)
//  - conv_l3 K = 27 taps x 32 cin = 864 = 27 exact K=32 chunks. (r18)
//  - Scatter: bf16 channel-last y1 + packed bf16 atomics. (r13)
//  - Block-uniform weight pointers for VALU convs (conv_l4). (r2)

// f32 -> bf16 (RNE)
static __device__ __forceinline__ unsigned f2bf(float f) {
    unsigned u = __float_as_uint(f);
    return (u + 0x7FFFu + ((u >> 16) & 1u)) >> 16;
}

typedef _Float16 f16x8 __attribute__((ext_vector_type(8)));
typedef float f32x4 __attribute__((ext_vector_type(4)));

// ---------------- Weight repack + BN fold ----------------
// wB2: f16 MFMA B-frags [chunk(14)][tile(2)][lane(64)][8]
//      oc=tile*16+(lane&15); tap=2c+(q>>1); cin=(q&1)*8+j   (q=lane>>4)
// wB3: f16 MFMA B-frags [tap(27)][tile(4)][lane(64)][8]
//      oc=tile*16+(lane&15); cin=q*8+j
// wT4: [(c*3+kz)*64+oc]
// shb: [0..31]=sh2, [32..95]=sh3, [96..159]=sh4, [160..175]=sc1, [176..191]=sh1
__global__ __launch_bounds__(256) void repack(
    const float* __restrict__ g1, const float* __restrict__ b1,
    const float* __restrict__ rm1, const float* __restrict__ rv1,
    const float* __restrict__ w2, const float* __restrict__ g2, const float* __restrict__ b2,
    const float* __restrict__ rm2, const float* __restrict__ rv2,
    const float* __restrict__ w3, const float* __restrict__ g3, const float* __restrict__ b3,
    const float* __restrict__ rm3, const float* __restrict__ rv3,
    const float* __restrict__ w4, const float* __restrict__ g4, const float* __restrict__ b4,
    const float* __restrict__ rm4, const float* __restrict__ rv4,
    _Float16* __restrict__ wB2, _Float16* __restrict__ wB3,
    float* __restrict__ wT4, float* __restrict__ shb)
{
    const int i = blockIdx.x * 256 + threadIdx.x;
    if (i < 14336) {                       // wB2
        const int j = i & 7, lane = (i >> 3) & 63, t = (i >> 9) & 1, c = i >> 10;
        const int q = lane >> 4, n = lane & 15;
        const int oc = t * 16 + n;
        const int tap = 2 * c + (q >> 1);
        const int cin = (q & 1) * 8 + j;
        float val = 0.f;
        if (tap < 27) {
            const float inv = g2[oc] * rsqrtf(rv2[oc] + EPS);
            val = w2[(oc * 16 + cin) * 27 + tap] * inv;
        }
        wB2[i] = (_Float16)val;
    } else if (i < 69632) {                // wB3
        const int j2 = i - 14336;
        const int j = j2 & 7, lane = (j2 >> 3) & 63, t = (j2 >> 9) & 3, tap = j2 >> 11;
        const int q = lane >> 4, n = lane & 15;
        const int oc = t * 16 + n;
        const int cin = q * 8 + j;
        const float inv = g3[oc] * rsqrtf(rv3[oc] + EPS);
        wB3[j2] = (_Float16)(w3[(oc * 32 + cin) * 27 + tap] * inv);
    } else if (i < 81920) {                // wT4[(c*3+kz)*64+oc], 64x3x64
        const int j = i - 69632;
        const int c = j / 192, kz = (j / 64) % 3, oc = j & 63;
        const float inv = g4[oc] * rsqrtf(rv4[oc] + EPS);
        wT4[j] = w4[(oc * 64 + c) * 3 + kz] * inv;
    } else if (i < 82112) {                // shifts + L1 BN scale/shift
        const int j = i - 81920;
        if (j < 32) {
            const float inv = g2[j] * rsqrtf(rv2[j] + EPS);
            shb[j] = b2[j] - rm2[j] * inv;
        } else if (j < 96) {
            const int o = j - 32;
            const float inv = g3[o] * rsqrtf(rv3[o] + EPS);
            shb[j] = b3[o] - rm3[o] * inv;
        } else if (j < 160) {
            const int o = j - 96;
            const float inv = g4[o] * rsqrtf(rv4[o] + EPS);
            shb[j] = b4[o] - rm4[o] * inv;
        } else if (j < 176) {
            const int o = j - 160;
            shb[j] = g1[o] * rsqrtf(rv1[o] + EPS);           // sc1
        } else if (j < 192) {
            const int o = j - 176;
            const float inv = g1[o] * rsqrtf(rv1[o] + EPS);
            shb[j] = b1[o] - rm1[o] * inv;                   // sh1
        }
    }
}

// ---------------- Layer 1: voxel scatter, one thread per (voxel, oc-pair) ----------------
__global__ __launch_bounds__(256) void scatter_l1(
    const float* __restrict__ vf, const int* __restrict__ coors, int NV,
    const float* __restrict__ w1, unsigned short* __restrict__ y1,
    float* __restrict__ m1)
{
    __shared__ float ws[16 * 3 * 27];  // (oc, c, tap)
    for (int e = threadIdx.x; e < 16 * 3 * 27; e += 256) ws[e] = w1[e];
    __syncthreads();

    const int gid = blockIdx.x * 256 + threadIdx.x;
    const int i = gid >> 3;        // voxel
    const int oc2 = gid & 7;       // channel pair
    if (i >= NV) return;
    const int oc = oc2 * 2;

    const int b = coors[4 * i + 0];
    const int z = coors[4 * i + 1];
    const int y = coors[4 * i + 2];
    const int x = coors[4 * i + 3];
    const float f0 = vf[3 * i + 0];
    const float f1 = vf[3 * i + 1];
    const float f2 = vf[3 * i + 2];

    int ozv[2], kzv[2], nz = 0;
    int oyv[2], kyv[2], ny = 0;
    int oxv[2], kxv[2], nx = 0;
#pragma unroll
    for (int k = 0; k < 3; ++k) {
        int t = z + 1 - k;
        if (t >= 0 && !(t & 1)) { int o = t >> 1; if (o < 21) { ozv[nz] = o; kzv[nz] = k; ++nz; } }
    }
#pragma unroll
    for (int k = 0; k < 3; ++k) {
        int t = y + 1 - k;
        if (t >= 0 && !(t & 1)) { int o = t >> 1; if (o < 256) { oyv[ny] = o; kyv[ny] = k; ++ny; } }
    }
#pragma unroll
    for (int k = 0; k < 3; ++k) {
        int t = x + 1 - k;
        if (t >= 0 && !(t & 1)) { int o = t >> 1; if (o < 256) { oxv[nx] = o; kxv[nx] = k; ++nx; } }
    }

    for (int a = 0; a < nz; ++a)
        for (int bb = 0; bb < ny; ++bb)
            for (int c = 0; c < nx; ++c) {
                const int oz = ozv[a], oy = oyv[bb], ox = oxv[c];
                const int tap = (kzv[a] * 3 + kyv[bb]) * 3 + kxv[c];
                const int sp = oz * 65536 + oy * 256 + ox;
                if (oc2 == 0) m1[b * 1376256 + sp] = 1.0f;
                const float s0 = ws[oc * 81 + tap] * f0 + ws[oc * 81 + 27 + tap] * f1 +
                                 ws[oc * 81 + 54 + tap] * f2;
                const float s1 = ws[(oc + 1) * 81 + tap] * f0 +
                                 ws[(oc + 1) * 81 + 27 + tap] * f1 +
                                 ws[(oc + 1) * 81 + 54 + tap] * f2;
                const unsigned pk = f2bf(s0) | (f2bf(s1) << 16);
                unsigned* addr = (unsigned*)(y1 + (size_t)(b * 1376256 + sp) * 16 +
                                             oc2 * 2);
                asm volatile("global_atomic_pk_add_bf16 %0, %1, off"
                             : : "v"(addr), "v"(pk) : "memory");
            }
}

// ---------------- h1 pass: y1(bf16) -> h1(f16) = relu(bn(y1))*m1, IN PLACE ----------------
__global__ __launch_bounds__(256) void h1_pass(
    uint4* __restrict__ y1b, const float* __restrict__ m1,
    const float* __restrict__ shb)
{
    const int idx = blockIdx.x * 256 + threadIdx.x;   // < 2,752,512 cells
    const float mv = m1[idx];
    uint4 u0 = y1b[idx * 2], u1 = y1b[idx * 2 + 1];
    const unsigned d[8] = {u0.x, u0.y, u0.z, u0.w, u1.x, u1.y, u1.z, u1.w};
    unsigned o[8];
#pragma unroll
    for (int j = 0; j < 8; ++j) {
        const int c0 = 2 * j;
        const float vlo = __uint_as_float(d[j] << 16);
        const float vhi = __uint_as_float(d[j] & 0xFFFF0000u);
        const float v0 = fmaxf(vlo * shb[160 + c0] + shb[176 + c0], 0.f) * mv;
        const float v1 = fmaxf(vhi * shb[160 + c0 + 1] + shb[176 + c0 + 1], 0.f) * mv;
        o[j] = __builtin_bit_cast(unsigned, __builtin_amdgcn_cvt_pkrtz(v0, v1));
    }
    uint4 w0, w1;
    w0.x = o[0]; w0.y = o[1]; w0.z = o[2]; w0.w = o[3];
    w1.x = o[4]; w1.y = o[5]; w1.z = o[6]; w1.w = o[7];
    y1b[idx * 2] = w0;
    y1b[idx * 2 + 1] = w1;
}

// ---------------- build m2: per-l2-px "any of 27 taps active" ----------------
__global__ __launch_bounds__(256) void build_m2(
    const float* __restrict__ m1, float* __restrict__ m2)
{
    const int idx = blockIdx.x * 256 + threadIdx.x;       // < 360448
    if (idx >= 360448) return;
    const int b = idx / 180224;
    const int r = idx - b * 180224;
    const int oz = r >> 14, r2 = r & 16383, oy = r2 >> 7, ox = r2 & 127;
    const int iz0 = 2 * oz - 1, iyb = 2 * oy - 1, ixb = 2 * ox - 1;

    float msum = 0.f;
#pragma unroll
    for (int kz = 0; kz < 3; ++kz) {
        const int iz = iz0 + kz;
#pragma unroll
        for (int ky = 0; ky < 3; ++ky) {
            const int iy = iyb + ky;
#pragma unroll
            for (int kx = 0; kx < 3; ++kx) {
                const int ix = ixb + kx;
                if ((unsigned)iz < 21u && (unsigned)iy < 256u && (unsigned)ix < 256u)
                    msum += m1[b * 1376256 + iz * 65536 + iy * 256 + ix];
            }
        }
    }
    m2[idx] = msum > 0.f ? 1.f : 0.f;
}

// ---------------- build m3: per-l3-px "any of 27 m2 taps active" ----------------
__global__ __launch_bounds__(256) void build_m3(
    const float* __restrict__ m2, float* __restrict__ m3)
{
    const int idx = blockIdx.x * 256 + threadIdx.x;       // < 40960
    if (idx >= 40960) return;
    const int b = idx / 20480;
    const int r = idx - b * 20480;
    const int oz = r >> 12, r2 = r & 4095, oy = r2 >> 6, ox = r2 & 63;
    const int iz0 = 2 * oz, iyb = 2 * oy - 1, ixb = 2 * ox - 1;

    float msum = 0.f;
#pragma unroll
    for (int kz = 0; kz < 3; ++kz) {
        const int iz = iz0 + kz;                          // in [0,10]
#pragma unroll
        for (int ky = 0; ky < 3; ++ky) {
            const int iy = iyb + ky;
#pragma unroll
            for (int kx = 0; kx < 3; ++kx) {
                const int ix = ixb + kx;
                if ((unsigned)iy < 128u && (unsigned)ix < 128u)
                    msum += m2[b * 180224 + iz * 16384 + iy * 128 + ix];
            }
        }
    }
    m3[idx] = msum > 0.f ? 1.f : 0.f;
}

// ---------------- Layer 2: implicit-GEMM MFMA conv 16->32 ----------------
// One wave per 16-px x-strip; 2 N-tiles of 16 oc. K = 28 taps x 16 cin (tap 27
// zero-weighted) = 14 chunks of K=32. Writes h2 as f16 channel-last cells.
__global__ __launch_bounds__(256) void conv_l2(
    const unsigned char* __restrict__ h1,   // f16 cells, byte-addressed
    const uint4* __restrict__ wB2,
    const float* __restrict__ m2, const float* __restrict__ shb,
    _Float16* __restrict__ h2h)
{
    const int tid = threadIdx.x;
    const int gw = blockIdx.x * 4 + (tid >> 6);     // 0..22527
    const int lane = tid & 63;
    const int m = lane & 15, q = lane >> 4;

    const int plane = gw >> 10;                     // b*11+oz
    const int rem = gw & 1023;
    const int oy = rem >> 3;
    const int ox0 = (rem & 7) * 16;
    const int b = plane / 11, oz = plane % 11;
    const int iz0 = 2 * oz - 1, iyb = 2 * oy - 1;
    const int ixm = 2 * (ox0 + m) - 1;              // per-lane input x base
    const int bbase = b * 1376256;

    f32x4 acc0 = {0.f, 0.f, 0.f, 0.f}, acc1 = {0.f, 0.f, 0.f, 0.f};
    const int qsel = q >> 1;          // 0: even tap of chunk, 1: odd tap
    const int qoff = (q & 1) * 16;    // byte offset within cell (cin half)

#pragma unroll
    for (int c = 0; c < 14; ++c) {
        const int t0 = 2 * c;
        const int t1 = (2 * c + 1 < 27) ? 2 * c + 1 : 26;   // clamp pad tap addr
        const int kz0 = t0 / 9, ky0 = (t0 / 3) % 3, kx0 = t0 % 3;
        const int kz1 = t1 / 9, ky1 = (t1 / 3) % 3, kx1 = t1 % 3;
        const int izA = iz0 + kz0, iyA = iyb + ky0, ixA = ixm + kx0;
        const int izB = iz0 + kz1, iyB = iyb + ky1, ixB = ixm + kx1;
        const bool vA = (unsigned)izA < 21u && (unsigned)iyA < 256u &&
                        (unsigned)ixA < 256u;
        const bool vB = (unsigned)izB < 21u && (unsigned)iyB < 256u &&
                        (unsigned)ixB < 256u;
        const int cellA = bbase + izA * 65536 + iyA * 256 + ixA;
        const int cellB = bbase + izB * 65536 + iyB * 256 + ixB;
        const bool v = qsel ? vB : vA;
        const int cell = qsel ? cellB : cellA;
        const int addr = v ? (cell * 32 + qoff) : 0;
        uint4 ua = *(const uint4*)(h1 + addr);
        if (!v) { ua.x = 0; ua.y = 0; ua.z = 0; ua.w = 0; }
        const f16x8 af = __builtin_bit_cast(f16x8, ua);
        const f16x8 bf0 = __builtin_bit_cast(f16x8, wB2[(c * 2 + 0) * 64 + lane]);
        const f16x8 bf1 = __builtin_bit_cast(f16x8, wB2[(c * 2 + 1) * 64 + lane]);
        acc0 = __builtin_amdgcn_mfma_f32_16x16x32_f16(af, bf0, acc0, 0, 0, 0);
        acc1 = __builtin_amdgcn_mfma_f32_16x16x32_f16(af, bf1, acc1, 0, 0, 0);
    }

    // epilogue: C/D layout col=lane&15 (oc within tile), row=q*4+r (px)
    const int n = lane & 15;
#pragma unroll
    for (int r = 0; r < 4; ++r) {
        const int px = ox0 + q * 4 + r;
        const int spo = oz * 16384 + oy * 128 + px;
        const float mv = m2[b * 180224 + spo];
        const size_t cbase = (size_t)(b * 180224 + spo) * 32;
        h2h[cbase + n]      = (_Float16)(fmaxf(acc0[r] + shb[n], 0.f) * mv);
        h2h[cbase + 16 + n] = (_Float16)(fmaxf(acc1[r] + shb[16 + n], 0.f) * mv);
    }
}

// ---------------- Layer 3: implicit-GEMM MFMA conv 32->64 ----------------
// One wave per 16-px x-strip; 4 N-tiles of 16 oc. K = 27 taps x 32 cin =
// exactly 27 chunks of K=32 (tap = chunk). A from h2h f16 cells (64 B).
__global__ __launch_bounds__(256) void conv_l3(
    const unsigned char* __restrict__ h2h,  // f16 cells, byte-addressed
    const uint4* __restrict__ wB3,
    const float* __restrict__ m3, const float* __restrict__ shb,
    float* __restrict__ h3)
{
    const int tid = threadIdx.x;
    const int gw = blockIdx.x * 4 + (tid >> 6);     // 0..2559
    const int lane = tid & 63;
    const int m = lane & 15, q = lane >> 4;

    const int plane = gw >> 8;                      // b*5+oz
    const int rem = gw & 255;
    const int oy = rem >> 2;
    const int ox0 = (rem & 3) * 16;
    const int b = plane / 5, oz = plane % 5;
    const int iz0 = 2 * oz, iyb = 2 * oy - 1;       // z pad 0
    const int ixm = 2 * (ox0 + m) - 1;
    const int bbase = b * 180224;
    const int qoff = q * 16;                        // byte offset in 64B cell

    f32x4 acc[4];
#pragma unroll
    for (int t = 0; t < 4; ++t) acc[t] = (f32x4){0.f, 0.f, 0.f, 0.f};

#pragma unroll 1
    for (int tap = 0; tap < 27; ++tap) {
        const int kz = tap / 9, ky = (tap / 3) % 3, kx = tap % 3;
        const int iz = iz0 + kz;                    // always in [0,10]
        const int iy = iyb + ky, ix = ixm + kx;
        const bool v = (unsigned)iy < 128u && (unsigned)ix < 128u;
        const int cell = bbase + iz * 16384 + iy * 128 + ix;
        const int addr = v ? (cell * 64 + qoff) : 0;
        uint4 ua = *(const uint4*)(h2h + addr);
        if (!v) { ua.x = 0; ua.y = 0; ua.z = 0; ua.w = 0; }
        const f16x8 af = __builtin_bit_cast(f16x8, ua);
#pragma unroll
        for (int t = 0; t < 4; ++t) {
            const f16x8 bf = __builtin_bit_cast(f16x8, wB3[(tap * 4 + t) * 64 + lane]);
            acc[t] = __builtin_amdgcn_mfma_f32_16x16x32_f16(af, bf, acc[t], 0, 0, 0);
        }
    }

    const int n = lane & 15;
#pragma unroll
    for (int r = 0; r < 4; ++r) {
        const int px = ox0 + q * 4 + r;
        const int spo = oz * 4096 + oy * 64 + px;
        const float mv = m3[b * 20480 + spo];
#pragma unroll
        for (int t = 0; t < 4; ++t) {
            const int oc = t * 16 + n;
            h3[(b * 64 + oc) * 20480 + spo] =
                fmaxf(acc[t][r] + shb[32 + oc], 0.f) * mv;
        }
    }
}

// ---------------- Layer 4: conv 64->64, k(3,1,1), s(2,1,1), pad 0 ----------------
__global__ __launch_bounds__(256) __attribute__((amdgpu_waves_per_eu(4, 8)))
void conv_l4(
    const float* __restrict__ h3, const float* __restrict__ m3,
    const float* __restrict__ wT4, const float* __restrict__ shb,
    float* __restrict__ out)
{
    const int p = blockIdx.x * 256 + threadIdx.x;  // 0..4095 spatial
    const int bo = blockIdx.y;
    const int b = bo >> 4, od = (bo >> 3) & 1, ocg = bo & 7;

    const float msum = m3[(b * 5 + 2 * od + 0) * 4096 + p] +
                       m3[(b * 5 + 2 * od + 1) * 4096 + p] +
                       m3[(b * 5 + 2 * od + 2) * 4096 + p];
    const float mout = msum > 0.f ? 1.f : 0.f;

    float acc[8];
#pragma unroll
    for (int oc = 0; oc < 8; ++oc) acc[oc] = 0.f;

#pragma unroll 1
    for (int c = 0; c < 64; ++c) {
        const float v0 = h3[((b * 64 + c) * 5 + 2 * od + 0) * 4096 + p];
        const float v1 = h3[((b * 64 + c) * 5 + 2 * od + 1) * 4096 + p];
        const float v2 = h3[((b * 64 + c) * 5 + 2 * od + 2) * 4096 + p];
        const float* __restrict__ wq = wT4 + c * 192 + ocg * 8;  // block-uniform
#pragma unroll
        for (int oc = 0; oc < 8; ++oc) {
            acc[oc] = fmaf(wq[oc], v0,
                      fmaf(wq[64 + oc], v1,
                      fmaf(wq[128 + oc], v2, acc[oc])));
        }
    }

#pragma unroll
    for (int oc = 0; oc < 8; ++oc) {
        const int ocgl = ocg * 8 + oc;
        out[((b * 64 + ocgl) * 2 + od) * 4096 + p] =
            fmaxf(acc[oc] + shb[96 + ocgl], 0.f) * mout;
    }
}

extern "C" void kernel_launch(void* const* d_in, const int* in_sizes, int n_in,
                              void* d_out, int out_size, void* d_ws, size_t ws_size,
                              hipStream_t stream)
{
    const float* vf    = (const float*)d_in[0];
    const int*   coors = (const int*)d_in[1];
    // d_in[2] = batch_size (==2, hardcoded in geometry)
    const float* w1 = (const float*)d_in[3];
    const float* g1 = (const float*)d_in[4];
    const float* b1 = (const float*)d_in[5];
    const float* rm1 = (const float*)d_in[6];
    const float* rv1 = (const float*)d_in[7];
    const float* w2 = (const float*)d_in[8];
    const float* g2 = (const float*)d_in[9];
    const float* b2 = (const float*)d_in[10];
    const float* rm2 = (const float*)d_in[11];
    const float* rv2 = (const float*)d_in[12];
    const float* w3 = (const float*)d_in[13];
    const float* g3 = (const float*)d_in[14];
    const float* b3 = (const float*)d_in[15];
    const float* rm3 = (const float*)d_in[16];
    const float* rv3 = (const float*)d_in[17];
    const float* w4 = (const float*)d_in[18];
    const float* g4 = (const float*)d_in[19];
    const float* b4 = (const float*)d_in[20];
    const float* rm4 = (const float*)d_in[21];
    const float* rv4 = (const float*)d_in[22];

    const int NV = in_sizes[0] / 3;

    float* ws = (float*)d_ws;
    float* y1  = ws;                   // 22,020,096 f-slots: bf16->f16 (2,21,256,256,16)
    float* m1  = y1 + 22020096;        //  2,752,512 f  (2,21,256,256)
    float* h2h = m1 + 2752512;         //  5,767,168 f-slots: f16 (2,11,128,128,32)
    float* m2  = h2h + 5767168;        //    360,448 f  (2,11,128,128)
    float* h3  = m2 + 360448;          //  2,621,440 f  (2,64,5,64,64)
    float* m3  = h3 + 2621440;         //     40,960 f  (2,5,64,64)
    float* wB2 = m3 + 40960;           //      7,168 f-slots (14336 f16)
    float* wB3 = wB2 + 7168;           //     27,648 f-slots (55296 f16)
    float* wT4 = wB3 + 27648;          //     12,288 f
    float* shb = wT4 + 12288;          //        192 f

    // zero the scatter accumulator (bf16) + mask (contiguous)
    (void)hipMemsetAsync(y1, 0, (size_t)(22020096 + 2752512) * sizeof(float), stream);

    repack<<<321, 256, 0, stream>>>(g1, b1, rm1, rv1,
                                    w2, g2, b2, rm2, rv2, w3, g3, b3, rm3, rv3,
                                    w4, g4, b4, rm4, rv4,
                                    (_Float16*)wB2, (_Float16*)wB3, wT4, shb);
    scatter_l1<<<(NV * 8 + 255) / 256, 256, 0, stream>>>(vf, coors, NV, w1,
                                                         (unsigned short*)y1, m1);
    h1_pass<<<10752, 256, 0, stream>>>((uint4*)y1, m1, shb);
    build_m2<<<1408, 256, 0, stream>>>(m1, m2);
    build_m3<<<160, 256, 0, stream>>>(m2, m3);
    conv_l2<<<5632, 256, 0, stream>>>((const unsigned char*)y1, (const uint4*)wB2,
                                      m2, shb, (_Float16*)h2h);
    conv_l3<<<640, 256, 0, stream>>>((const unsigned char*)h2h, (const uint4*)wB3,
                                     m3, shb, h3);
    conv_l4<<<dim3(16, 32), 256, 0, stream>>>(h3, m3, wT4, shb, (float*)d_out);
}

// Round 19
// 254.290 us; speedup vs baseline: 1.5749x; 1.0799x over previous
//
#include <hip/hip_runtime.h>

#define EPS 1e-3f

// Tensor geometry (fixed for this problem):
// y1/h1: channel-last (2, 21,256,256, 16): scatter accumulates bf16;
//   h1_pass converts IN PLACE to f16 relu(bn(y1))*m1. 32 B per cell.
// m1: (2,21,256,256) fp32;  m2: (2,11,128,128) fp32;  m3: (2,5,64,64) fp32
// h2h: f16 channel-last (2, 11,128,128, 32) -- 64 B per cell
// h3h: f16 channel-last (2, 5,64,64, 64) -- 128 B per cell
// out: (2,128,64,64) fp32
//
// Lessons encoded:
//  - All three convs are effectively dense; VALU formulations plateau.
//    Implicit-GEMM MFMA (16x16x32 f16) wins: conv_l2 126->47us (r17),
//    conv_l3 115-><25us (r18). A[m=lane&15][k=quad*8+j], C/D col=lane&15,
//    row=quad*4+reg -- verified by r17/r18 passing.
//  - conv_l4 K = 3 dz x 64 cin = 192 = 6 exact K=32 chunks, no OOB. (r19)
//  - Scatter: bf16 channel-last y1 + packed bf16 atomics. (r13)

// f32 -> bf16 (RNE)
static __device__ __forceinline__ unsigned f2bf(float f) {
    unsigned u = __float_as_uint(f);
    return (u + 0x7FFFu + ((u >> 16) & 1u)) >> 16;
}

typedef _Float16 f16x8 __attribute__((ext_vector_type(8)));
typedef float f32x4 __attribute__((ext_vector_type(4)));

// ---------------- Weight repack + BN fold ----------------
// wB2: f16 B-frags [chunk(14)][tile(2)][lane(64)][8]
//      oc=tile*16+(lane&15); tap=2c+(q>>1); cin=(q&1)*8+j   (q=lane>>4)
// wB3: f16 B-frags [tap(27)][tile(4)][lane(64)][8]  oc=tile*16+n; cin=q*8+j
// wB4: f16 B-frags [chunk(6)][tile(4)][lane(64)][8]
//      k=chunk*32+q*8+j; dz=k>>6; cin=k&63; oc=tile*16+n
// shb: [0..31]=sh2, [32..95]=sh3, [96..159]=sh4, [160..175]=sc1, [176..191]=sh1
__global__ __launch_bounds__(256) void repack(
    const float* __restrict__ g1, const float* __restrict__ b1,
    const float* __restrict__ rm1, const float* __restrict__ rv1,
    const float* __restrict__ w2, const float* __restrict__ g2, const float* __restrict__ b2,
    const float* __restrict__ rm2, const float* __restrict__ rv2,
    const float* __restrict__ w3, const float* __restrict__ g3, const float* __restrict__ b3,
    const float* __restrict__ rm3, const float* __restrict__ rv3,
    const float* __restrict__ w4, const float* __restrict__ g4, const float* __restrict__ b4,
    const float* __restrict__ rm4, const float* __restrict__ rv4,
    _Float16* __restrict__ wB2, _Float16* __restrict__ wB3,
    _Float16* __restrict__ wB4, float* __restrict__ shb)
{
    const int i = blockIdx.x * 256 + threadIdx.x;
    if (i < 14336) {                       // wB2
        const int j = i & 7, lane = (i >> 3) & 63, t = (i >> 9) & 1, c = i >> 10;
        const int q = lane >> 4, n = lane & 15;
        const int oc = t * 16 + n;
        const int tap = 2 * c + (q >> 1);
        const int cin = (q & 1) * 8 + j;
        float val = 0.f;
        if (tap < 27) {
            const float inv = g2[oc] * rsqrtf(rv2[oc] + EPS);
            val = w2[(oc * 16 + cin) * 27 + tap] * inv;
        }
        wB2[i] = (_Float16)val;
    } else if (i < 69632) {                // wB3
        const int j2 = i - 14336;
        const int j = j2 & 7, lane = (j2 >> 3) & 63, t = (j2 >> 9) & 3, tap = j2 >> 11;
        const int q = lane >> 4, n = lane & 15;
        const int oc = t * 16 + n;
        const int cin = q * 8 + j;
        const float inv = g3[oc] * rsqrtf(rv3[oc] + EPS);
        wB3[j2] = (_Float16)(w3[(oc * 32 + cin) * 27 + tap] * inv);
    } else if (i < 81920) {                // wB4
        const int j2 = i - 69632;
        const int j = j2 & 7, lane = (j2 >> 3) & 63, t = (j2 >> 9) & 3, c = j2 >> 11;
        const int q = lane >> 4, n = lane & 15;
        const int oc = t * 16 + n;
        const int k = c * 32 + q * 8 + j;
        const int dz = k >> 6, cin = k & 63;
        const float inv = g4[oc] * rsqrtf(rv4[oc] + EPS);
        wB4[j2] = (_Float16)(w4[(oc * 64 + cin) * 3 + dz] * inv);
    } else if (i < 82112) {                // shifts + L1 BN scale/shift
        const int j = i - 81920;
        if (j < 32) {
            const float inv = g2[j] * rsqrtf(rv2[j] + EPS);
            shb[j] = b2[j] - rm2[j] * inv;
        } else if (j < 96) {
            const int o = j - 32;
            const float inv = g3[o] * rsqrtf(rv3[o] + EPS);
            shb[j] = b3[o] - rm3[o] * inv;
        } else if (j < 160) {
            const int o = j - 96;
            const float inv = g4[o] * rsqrtf(rv4[o] + EPS);
            shb[j] = b4[o] - rm4[o] * inv;
        } else if (j < 176) {
            const int o = j - 160;
            shb[j] = g1[o] * rsqrtf(rv1[o] + EPS);           // sc1
        } else if (j < 192) {
            const int o = j - 176;
            const float inv = g1[o] * rsqrtf(rv1[o] + EPS);
            shb[j] = b1[o] - rm1[o] * inv;                   // sh1
        }
    }
}

// ---------------- Layer 1: voxel scatter, one thread per (voxel, oc-pair) ----------------
__global__ __launch_bounds__(256) void scatter_l1(
    const float* __restrict__ vf, const int* __restrict__ coors, int NV,
    const float* __restrict__ w1, unsigned short* __restrict__ y1,
    float* __restrict__ m1)
{
    __shared__ float ws[16 * 3 * 27];  // (oc, c, tap)
    for (int e = threadIdx.x; e < 16 * 3 * 27; e += 256) ws[e] = w1[e];
    __syncthreads();

    const int gid = blockIdx.x * 256 + threadIdx.x;
    const int i = gid >> 3;        // voxel
    const int oc2 = gid & 7;       // channel pair
    if (i >= NV) return;
    const int oc = oc2 * 2;

    const int b = coors[4 * i + 0];
    const int z = coors[4 * i + 1];
    const int y = coors[4 * i + 2];
    const int x = coors[4 * i + 3];
    const float f0 = vf[3 * i + 0];
    const float f1 = vf[3 * i + 1];
    const float f2 = vf[3 * i + 2];

    int ozv[2], kzv[2], nz = 0;
    int oyv[2], kyv[2], ny = 0;
    int oxv[2], kxv[2], nx = 0;
#pragma unroll
    for (int k = 0; k < 3; ++k) {
        int t = z + 1 - k;
        if (t >= 0 && !(t & 1)) { int o = t >> 1; if (o < 21) { ozv[nz] = o; kzv[nz] = k; ++nz; } }
    }
#pragma unroll
    for (int k = 0; k < 3; ++k) {
        int t = y + 1 - k;
        if (t >= 0 && !(t & 1)) { int o = t >> 1; if (o < 256) { oyv[ny] = o; kyv[ny] = k; ++ny; } }
    }
#pragma unroll
    for (int k = 0; k < 3; ++k) {
        int t = x + 1 - k;
        if (t >= 0 && !(t & 1)) { int o = t >> 1; if (o < 256) { oxv[nx] = o; kxv[nx] = k; ++nx; } }
    }

    for (int a = 0; a < nz; ++a)
        for (int bb = 0; bb < ny; ++bb)
            for (int c = 0; c < nx; ++c) {
                const int oz = ozv[a], oy = oyv[bb], ox = oxv[c];
                const int tap = (kzv[a] * 3 + kyv[bb]) * 3 + kxv[c];
                const int sp = oz * 65536 + oy * 256 + ox;
                if (oc2 == 0) m1[b * 1376256 + sp] = 1.0f;
                const float s0 = ws[oc * 81 + tap] * f0 + ws[oc * 81 + 27 + tap] * f1 +
                                 ws[oc * 81 + 54 + tap] * f2;
                const float s1 = ws[(oc + 1) * 81 + tap] * f0 +
                                 ws[(oc + 1) * 81 + 27 + tap] * f1 +
                                 ws[(oc + 1) * 81 + 54 + tap] * f2;
                const unsigned pk = f2bf(s0) | (f2bf(s1) << 16);
                unsigned* addr = (unsigned*)(y1 + (size_t)(b * 1376256 + sp) * 16 +
                                             oc2 * 2);
                asm volatile("global_atomic_pk_add_bf16 %0, %1, off"
                             : : "v"(addr), "v"(pk) : "memory");
            }
}

// ---------------- h1 pass: y1(bf16) -> h1(f16) = relu(bn(y1))*m1, IN PLACE ----------------
__global__ __launch_bounds__(256) void h1_pass(
    uint4* __restrict__ y1b, const float* __restrict__ m1,
    const float* __restrict__ shb)
{
    const int idx = blockIdx.x * 256 + threadIdx.x;   // < 2,752,512 cells
    const float mv = m1[idx];
    uint4 u0 = y1b[idx * 2], u1 = y1b[idx * 2 + 1];
    const unsigned d[8] = {u0.x, u0.y, u0.z, u0.w, u1.x, u1.y, u1.z, u1.w};
    unsigned o[8];
#pragma unroll
    for (int j = 0; j < 8; ++j) {
        const int c0 = 2 * j;
        const float vlo = __uint_as_float(d[j] << 16);
        const float vhi = __uint_as_float(d[j] & 0xFFFF0000u);
        const float v0 = fmaxf(vlo * shb[160 + c0] + shb[176 + c0], 0.f) * mv;
        const float v1 = fmaxf(vhi * shb[160 + c0 + 1] + shb[176 + c0 + 1], 0.f) * mv;
        o[j] = __builtin_bit_cast(unsigned, __builtin_amdgcn_cvt_pkrtz(v0, v1));
    }
    uint4 w0, w1;
    w0.x = o[0]; w0.y = o[1]; w0.z = o[2]; w0.w = o[3];
    w1.x = o[4]; w1.y = o[5]; w1.z = o[6]; w1.w = o[7];
    y1b[idx * 2] = w0;
    y1b[idx * 2 + 1] = w1;
}

// ---------------- build m2: per-l2-px "any of 27 taps active" ----------------
__global__ __launch_bounds__(256) void build_m2(
    const float* __restrict__ m1, float* __restrict__ m2)
{
    const int idx = blockIdx.x * 256 + threadIdx.x;       // < 360448
    if (idx >= 360448) return;
    const int b = idx / 180224;
    const int r = idx - b * 180224;
    const int oz = r >> 14, r2 = r & 16383, oy = r2 >> 7, ox = r2 & 127;
    const int iz0 = 2 * oz - 1, iyb = 2 * oy - 1, ixb = 2 * ox - 1;

    float msum = 0.f;
#pragma unroll
    for (int kz = 0; kz < 3; ++kz) {
        const int iz = iz0 + kz;
#pragma unroll
        for (int ky = 0; ky < 3; ++ky) {
            const int iy = iyb + ky;
#pragma unroll
            for (int kx = 0; kx < 3; ++kx) {
                const int ix = ixb + kx;
                if ((unsigned)iz < 21u && (unsigned)iy < 256u && (unsigned)ix < 256u)
                    msum += m1[b * 1376256 + iz * 65536 + iy * 256 + ix];
            }
        }
    }
    m2[idx] = msum > 0.f ? 1.f : 0.f;
}

// ---------------- build m3: per-l3-px "any of 27 m2 taps active" ----------------
__global__ __launch_bounds__(256) void build_m3(
    const float* __restrict__ m2, float* __restrict__ m3)
{
    const int idx = blockIdx.x * 256 + threadIdx.x;       // < 40960
    if (idx >= 40960) return;
    const int b = idx / 20480;
    const int r = idx - b * 20480;
    const int oz = r >> 12, r2 = r & 4095, oy = r2 >> 6, ox = r2 & 63;
    const int iz0 = 2 * oz, iyb = 2 * oy - 1, ixb = 2 * ox - 1;

    float msum = 0.f;
#pragma unroll
    for (int kz = 0; kz < 3; ++kz) {
        const int iz = iz0 + kz;                          // in [0,10]
#pragma unroll
        for (int ky = 0; ky < 3; ++ky) {
            const int iy = iyb + ky;
#pragma unroll
            for (int kx = 0; kx < 3; ++kx) {
                const int ix = ixb + kx;
                if ((unsigned)iy < 128u && (unsigned)ix < 128u)
                    msum += m2[b * 180224 + iz * 16384 + iy * 128 + ix];
            }
        }
    }
    m3[idx] = msum > 0.f ? 1.f : 0.f;
}

// ---------------- Layer 2: implicit-GEMM MFMA conv 16->32 ----------------
// One wave per 16-px x-strip; 2 N-tiles of 16 oc. K = 28 taps x 16 cin (tap 27
// zero-weighted) = 14 chunks of K=32. Writes h2 as f16 channel-last cells.
__global__ __launch_bounds__(256) void conv_l2(
    const unsigned char* __restrict__ h1,   // f16 cells, byte-addressed
    const uint4* __restrict__ wB2,
    const float* __restrict__ m2, const float* __restrict__ shb,
    _Float16* __restrict__ h2h)
{
    const int tid = threadIdx.x;
    const int gw = blockIdx.x * 4 + (tid >> 6);     // 0..22527
    const int lane = tid & 63;
    const int m = lane & 15, q = lane >> 4;

    const int plane = gw >> 10;                     // b*11+oz
    const int rem = gw & 1023;
    const int oy = rem >> 3;
    const int ox0 = (rem & 7) * 16;
    const int b = plane / 11, oz = plane % 11;
    const int iz0 = 2 * oz - 1, iyb = 2 * oy - 1;
    const int ixm = 2 * (ox0 + m) - 1;              // per-lane input x base
    const int bbase = b * 1376256;

    f32x4 acc0 = {0.f, 0.f, 0.f, 0.f}, acc1 = {0.f, 0.f, 0.f, 0.f};
    const int qsel = q >> 1;          // 0: even tap of chunk, 1: odd tap
    const int qoff = (q & 1) * 16;    // byte offset within cell (cin half)

#pragma unroll
    for (int c = 0; c < 14; ++c) {
        const int t0 = 2 * c;
        const int t1 = (2 * c + 1 < 27) ? 2 * c + 1 : 26;   // clamp pad tap addr
        const int kz0 = t0 / 9, ky0 = (t0 / 3) % 3, kx0 = t0 % 3;
        const int kz1 = t1 / 9, ky1 = (t1 / 3) % 3, kx1 = t1 % 3;
        const int izA = iz0 + kz0, iyA = iyb + ky0, ixA = ixm + kx0;
        const int izB = iz0 + kz1, iyB = iyb + ky1, ixB = ixm + kx1;
        const bool vA = (unsigned)izA < 21u && (unsigned)iyA < 256u &&
                        (unsigned)ixA < 256u;
        const bool vB = (unsigned)izB < 21u && (unsigned)iyB < 256u &&
                        (unsigned)ixB < 256u;
        const int cellA = bbase + izA * 65536 + iyA * 256 + ixA;
        const int cellB = bbase + izB * 65536 + iyB * 256 + ixB;
        const bool v = qsel ? vB : vA;
        const int cell = qsel ? cellB : cellA;
        const int addr = v ? (cell * 32 + qoff) : 0;
        uint4 ua = *(const uint4*)(h1 + addr);
        if (!v) { ua.x = 0; ua.y = 0; ua.z = 0; ua.w = 0; }
        const f16x8 af = __builtin_bit_cast(f16x8, ua);
        const f16x8 bf0 = __builtin_bit_cast(f16x8, wB2[(c * 2 + 0) * 64 + lane]);
        const f16x8 bf1 = __builtin_bit_cast(f16x8, wB2[(c * 2 + 1) * 64 + lane]);
        acc0 = __builtin_amdgcn_mfma_f32_16x16x32_f16(af, bf0, acc0, 0, 0, 0);
        acc1 = __builtin_amdgcn_mfma_f32_16x16x32_f16(af, bf1, acc1, 0, 0, 0);
    }

    // epilogue: C/D layout col=lane&15 (oc within tile), row=q*4+r (px)
    const int n = lane & 15;
#pragma unroll
    for (int r = 0; r < 4; ++r) {
        const int px = ox0 + q * 4 + r;
        const int spo = oz * 16384 + oy * 128 + px;
        const float mv = m2[b * 180224 + spo];
        const size_t cbase = (size_t)(b * 180224 + spo) * 32;
        h2h[cbase + n]      = (_Float16)(fmaxf(acc0[r] + shb[n], 0.f) * mv);
        h2h[cbase + 16 + n] = (_Float16)(fmaxf(acc1[r] + shb[16 + n], 0.f) * mv);
    }
}

// ---------------- Layer 3: implicit-GEMM MFMA conv 32->64 ----------------
// One wave per 16-px x-strip; 4 N-tiles of 16 oc. K = 27 taps x 32 cin =
// exactly 27 chunks of K=32. Writes h3 as f16 channel-last cells (128 B).
__global__ __launch_bounds__(256) void conv_l3(
    const unsigned char* __restrict__ h2h,  // f16 cells, byte-addressed
    const uint4* __restrict__ wB3,
    const float* __restrict__ m3, const float* __restrict__ shb,
    _Float16* __restrict__ h3h)
{
    const int tid = threadIdx.x;
    const int gw = blockIdx.x * 4 + (tid >> 6);     // 0..2559
    const int lane = tid & 63;
    const int m = lane & 15, q = lane >> 4;

    const int plane = gw >> 8;                      // b*5+oz
    const int rem = gw & 255;
    const int oy = rem >> 2;
    const int ox0 = (rem & 3) * 16;
    const int b = plane / 5, oz = plane % 5;
    const int iz0 = 2 * oz, iyb = 2 * oy - 1;       // z pad 0
    const int ixm = 2 * (ox0 + m) - 1;
    const int bbase = b * 180224;
    const int qoff = q * 16;                        // byte offset in 64B cell

    f32x4 acc[4];
#pragma unroll
    for (int t = 0; t < 4; ++t) acc[t] = (f32x4){0.f, 0.f, 0.f, 0.f};

#pragma unroll 1
    for (int tap = 0; tap < 27; ++tap) {
        const int kz = tap / 9, ky = (tap / 3) % 3, kx = tap % 3;
        const int iz = iz0 + kz;                    // always in [0,10]
        const int iy = iyb + ky, ix = ixm + kx;
        const bool v = (unsigned)iy < 128u && (unsigned)ix < 128u;
        const int cell = bbase + iz * 16384 + iy * 128 + ix;
        const int addr = v ? (cell * 64 + qoff) : 0;
        uint4 ua = *(const uint4*)(h2h + addr);
        if (!v) { ua.x = 0; ua.y = 0; ua.z = 0; ua.w = 0; }
        const f16x8 af = __builtin_bit_cast(f16x8, ua);
#pragma unroll
        for (int t = 0; t < 4; ++t) {
            const f16x8 bf = __builtin_bit_cast(f16x8, wB3[(tap * 4 + t) * 64 + lane]);
            acc[t] = __builtin_amdgcn_mfma_f32_16x16x32_f16(af, bf, acc[t], 0, 0, 0);
        }
    }

    const int n = lane & 15;
#pragma unroll
    for (int r = 0; r < 4; ++r) {
        const int px = ox0 + q * 4 + r;
        const int spo = oz * 4096 + oy * 64 + px;
        const float mv = m3[b * 20480 + spo];
        const size_t cb = (size_t)(b * 20480 + spo) * 64;
#pragma unroll
        for (int t = 0; t < 4; ++t) {
            const int oc = t * 16 + n;
            h3h[cb + oc] = (_Float16)(fmaxf(acc[t][r] + shb[32 + oc], 0.f) * mv);
        }
    }
}

// ---------------- Layer 4: implicit-GEMM MFMA conv 64->64, k(3,1,1) ----------------
// One wave per 16-px x-strip; 4 N-tiles of 16 oc. K = 3 dz x 64 cin = 192 =
// 6 exact K=32 chunks. iz = 2*od + dz in [0,4]: no OOB anywhere.
__global__ __launch_bounds__(256) void conv_l4(
    const unsigned char* __restrict__ h3h,  // f16 cells (128 B), byte-addressed
    const uint4* __restrict__ wB4,
    const float* __restrict__ m3, const float* __restrict__ shb,
    float* __restrict__ out)
{
    const int tid = threadIdx.x;
    const int gw = blockIdx.x * 4 + (tid >> 6);     // 0..1023
    const int lane = tid & 63;
    const int m = lane & 15, q = lane >> 4;

    const int b = gw >> 9, od = (gw >> 8) & 1;
    const int oy = (gw >> 2) & 63, ox0 = (gw & 3) * 16;
    const int cellbase = (b * 5 + 2 * od) * 4096 + oy * 64 + ox0 + m;

    f32x4 acc[4];
#pragma unroll
    for (int t = 0; t < 4; ++t) acc[t] = (f32x4){0.f, 0.f, 0.f, 0.f};

#pragma unroll
    for (int c = 0; c < 6; ++c) {
        const int dz = c >> 1;
        const size_t addr = (size_t)(cellbase + dz * 4096) * 128 +
                            (c & 1) * 64 + q * 16;
        const uint4 ua = *(const uint4*)(h3h + addr);
        const f16x8 af = __builtin_bit_cast(f16x8, ua);
#pragma unroll
        for (int t = 0; t < 4; ++t) {
            const f16x8 bf = __builtin_bit_cast(f16x8, wB4[(c * 4 + t) * 64 + lane]);
            acc[t] = __builtin_amdgcn_mfma_f32_16x16x32_f16(af, bf, acc[t], 0, 0, 0);
        }
    }

    const int n = lane & 15;
#pragma unroll
    for (int r = 0; r < 4; ++r) {
        const int px = ox0 + q * 4 + r;
        const int spo = oy * 64 + px;
        const float msum = m3[(b * 5 + 2 * od + 0) * 4096 + spo] +
                           m3[(b * 5 + 2 * od + 1) * 4096 + spo] +
                           m3[(b * 5 + 2 * od + 2) * 4096 + spo];
        const float mv = msum > 0.f ? 1.f : 0.f;
#pragma unroll
        for (int t = 0; t < 4; ++t) {
            const int oc = t * 16 + n;
            out[((b * 64 + oc) * 2 + od) * 4096 + spo] =
                fmaxf(acc[t][r] + shb[96 + oc], 0.f) * mv;
        }
    }
}

extern "C" void kernel_launch(void* const* d_in, const int* in_sizes, int n_in,
                              void* d_out, int out_size, void* d_ws, size_t ws_size,
                              hipStream_t stream)
{
    const float* vf    = (const float*)d_in[0];
    const int*   coors = (const int*)d_in[1];
    // d_in[2] = batch_size (==2, hardcoded in geometry)
    const float* w1 = (const float*)d_in[3];
    const float* g1 = (const float*)d_in[4];
    const float* b1 = (const float*)d_in[5];
    const float* rm1 = (const float*)d_in[6];
    const float* rv1 = (const float*)d_in[7];
    const float* w2 = (const float*)d_in[8];
    const float* g2 = (const float*)d_in[9];
    const float* b2 = (const float*)d_in[10];
    const float* rm2 = (const float*)d_in[11];
    const float* rv2 = (const float*)d_in[12];
    const float* w3 = (const float*)d_in[13];
    const float* g3 = (const float*)d_in[14];
    const float* b3 = (const float*)d_in[15];
    const float* rm3 = (const float*)d_in[16];
    const float* rv3 = (const float*)d_in[17];
    const float* w4 = (const float*)d_in[18];
    const float* g4 = (const float*)d_in[19];
    const float* b4 = (const float*)d_in[20];
    const float* rm4 = (const float*)d_in[21];
    const float* rv4 = (const float*)d_in[22];

    const int NV = in_sizes[0] / 3;

    float* ws = (float*)d_ws;
    float* y1  = ws;                   // 22,020,096 f-slots: bf16->f16 (2,21,256,256,16)
    float* m1  = y1 + 22020096;        //  2,752,512 f  (2,21,256,256)
    float* h2h = m1 + 2752512;         //  5,767,168 f-slots: f16 (2,11,128,128,32)
    float* m2  = h2h + 5767168;        //    360,448 f  (2,11,128,128)
    float* h3h = m2 + 360448;          //  1,310,720 f-slots: f16 (2,5,64,64,64)
    float* m3  = h3h + 1310720;        //     40,960 f  (2,5,64,64)
    float* wB2 = m3 + 40960;           //      7,168 f-slots (14336 f16)
    float* wB3 = wB2 + 7168;           //     27,648 f-slots (55296 f16)
    float* wB4 = wB3 + 27648;          //      6,144 f-slots (12288 f16)
    float* shb = wB4 + 6144;           //        192 f

    // zero the scatter accumulator (bf16) + mask (contiguous)
    (void)hipMemsetAsync(y1, 0, (size_t)(22020096 + 2752512) * sizeof(float), stream);

    repack<<<321, 256, 0, stream>>>(g1, b1, rm1, rv1,
                                    w2, g2, b2, rm2, rv2, w3, g3, b3, rm3, rv3,
                                    w4, g4, b4, rm4, rv4,
                                    (_Float16*)wB2, (_Float16*)wB3,
                                    (_Float16*)wB4, shb);
    scatter_l1<<<(NV * 8 + 255) / 256, 256, 0, stream>>>(vf, coors, NV, w1,
                                                         (unsigned short*)y1, m1);
    h1_pass<<<10752, 256, 0, stream>>>((uint4*)y1, m1, shb);
    build_m2<<<1408, 256, 0, stream>>>(m1, m2);
    build_m3<<<160, 256, 0, stream>>>(m2, m3);
    conv_l2<<<5632, 256, 0, stream>>>((const unsigned char*)y1, (const uint4*)wB2,
                                      m2, shb, (_Float16*)h2h);
    conv_l3<<<640, 256, 0, stream>>>((const unsigned char*)h2h, (const uint4*)wB3,
                                     m3, shb, (_Float16*)h3h);
    conv_l4<<<256, 256, 0, stream>>>((const unsigned char*)h3h, (const uint4*)wB4,
                                     m3, shb, (float*)d_out);
}

// Round 20
// 251.140 us; speedup vs baseline: 1.5947x; 1.0125x over previous
//
#include <hip/hip_runtime.h>

#define EPS 1e-3f

// Tensor geometry (fixed for this problem):
// y1/h1: channel-last (2, 21,256,256, 16): scatter accumulates bf16;
//   h1_pass converts IN PLACE to f16 relu(bn(y1))*m1. 32 B per cell.
// m1: (2,21,256,256) fp32;  m2: (2,11,128,128) fp32;  m3: (2,5,64,64) fp32
// h2h: f16 channel-last (2, 11,128,128, 32) -- 64 B per cell
// h3h: f16 channel-last (2, 5,64,64, 64) -- 128 B per cell
// out: (2,128,64,64) fp32
//
// Lessons encoded:
//  - Implicit-GEMM MFMA wins all conv layers (r17-r19, each verified).
//    16x16x32: A[m=lane&15][k=quad*8+j], C/D col=lane&15,row=quad*4+reg.
//    32x32x16: A[m=lane&31][k=(lane>>5)*8+j], C/D col=lane&31,
//    row=(reg&3)+8*(reg>>2)+4*(lane>>5)  (guide m74/m101).
//  - conv_l2 @16x16 was load-latency bound (48us, FETCH=79MB=h1 compulsory,
//    HBM floor ~14us): 32x32 shape halves per-px loads + instrs. (r20)
//  - Scatter: bf16 channel-last y1 + packed bf16 atomics. (r13)

// f32 -> bf16 (RNE)
static __device__ __forceinline__ unsigned f2bf(float f) {
    unsigned u = __float_as_uint(f);
    return (u + 0x7FFFu + ((u >> 16) & 1u)) >> 16;
}

typedef _Float16 f16x8 __attribute__((ext_vector_type(8)));
typedef float f32x4 __attribute__((ext_vector_type(4)));
typedef float f32x16 __attribute__((ext_vector_type(16)));

// ---------------- Weight repack + BN fold ----------------
// wB2: f16 B-frags 32x32x16 [tap(27)][lane(64)][8]: oc=lane&31; cin=(lane>>5)*8+j
// wB3: f16 B-frags 16x16x32 [tap(27)][tile(4)][lane(64)][8]: oc=tile*16+(lane&15);
//      cin=(lane>>4)*8+j
// wB4: f16 B-frags 16x16x32 [chunk(6)][tile(4)][lane(64)][8]:
//      k=chunk*32+(lane>>4)*8+j; dz=k>>6; cin=k&63; oc=tile*16+(lane&15)
// shb: [0..31]=sh2, [32..95]=sh3, [96..159]=sh4, [160..175]=sc1, [176..191]=sh1
__global__ __launch_bounds__(256) void repack(
    const float* __restrict__ g1, const float* __restrict__ b1,
    const float* __restrict__ rm1, const float* __restrict__ rv1,
    const float* __restrict__ w2, const float* __restrict__ g2, const float* __restrict__ b2,
    const float* __restrict__ rm2, const float* __restrict__ rv2,
    const float* __restrict__ w3, const float* __restrict__ g3, const float* __restrict__ b3,
    const float* __restrict__ rm3, const float* __restrict__ rv3,
    const float* __restrict__ w4, const float* __restrict__ g4, const float* __restrict__ b4,
    const float* __restrict__ rm4, const float* __restrict__ rv4,
    _Float16* __restrict__ wB2, _Float16* __restrict__ wB3,
    _Float16* __restrict__ wB4, float* __restrict__ shb)
{
    const int i = blockIdx.x * 256 + threadIdx.x;
    if (i < 13824) {                       // wB2[tap*512 + lane*8 + j]
        const int j = i & 7, lane = (i >> 3) & 63, tap = i >> 9;
        const int oc = lane & 31;
        const int cin = (lane >> 5) * 8 + j;
        const float inv = g2[oc] * rsqrtf(rv2[oc] + EPS);
        wB2[i] = (_Float16)(w2[(oc * 16 + cin) * 27 + tap] * inv);
    } else if (i >= 14336 && i < 69632) {  // wB3
        const int j2 = i - 14336;
        const int j = j2 & 7, lane = (j2 >> 3) & 63, t = (j2 >> 9) & 3, tap = j2 >> 11;
        const int q = lane >> 4, n = lane & 15;
        const int oc = t * 16 + n;
        const int cin = q * 8 + j;
        const float inv = g3[oc] * rsqrtf(rv3[oc] + EPS);
        wB3[j2] = (_Float16)(w3[(oc * 32 + cin) * 27 + tap] * inv);
    } else if (i >= 69632 && i < 81920) {  // wB4
        const int j2 = i - 69632;
        const int j = j2 & 7, lane = (j2 >> 3) & 63, t = (j2 >> 9) & 3, c = j2 >> 11;
        const int q = lane >> 4, n = lane & 15;
        const int oc = t * 16 + n;
        const int k = c * 32 + q * 8 + j;
        const int dz = k >> 6, cin = k & 63;
        const float inv = g4[oc] * rsqrtf(rv4[oc] + EPS);
        wB4[j2] = (_Float16)(w4[(oc * 64 + cin) * 3 + dz] * inv);
    } else if (i >= 81920 && i < 82112) {  // shifts + L1 BN scale/shift
        const int j = i - 81920;
        if (j < 32) {
            const float inv = g2[j] * rsqrtf(rv2[j] + EPS);
            shb[j] = b2[j] - rm2[j] * inv;
        } else if (j < 96) {
            const int o = j - 32;
            const float inv = g3[o] * rsqrtf(rv3[o] + EPS);
            shb[j] = b3[o] - rm3[o] * inv;
        } else if (j < 160) {
            const int o = j - 96;
            const float inv = g4[o] * rsqrtf(rv4[o] + EPS);
            shb[j] = b4[o] - rm4[o] * inv;
        } else if (j < 176) {
            const int o = j - 160;
            shb[j] = g1[o] * rsqrtf(rv1[o] + EPS);           // sc1
        } else if (j < 192) {
            const int o = j - 176;
            const float inv = g1[o] * rsqrtf(rv1[o] + EPS);
            shb[j] = b1[o] - rm1[o] * inv;                   // sh1
        }
    }
}

// ---------------- Layer 1: voxel scatter, one thread per (voxel, oc-pair) ----------------
__global__ __launch_bounds__(256) void scatter_l1(
    const float* __restrict__ vf, const int* __restrict__ coors, int NV,
    const float* __restrict__ w1, unsigned short* __restrict__ y1,
    float* __restrict__ m1)
{
    __shared__ float ws[16 * 3 * 27];  // (oc, c, tap)
    for (int e = threadIdx.x; e < 16 * 3 * 27; e += 256) ws[e] = w1[e];
    __syncthreads();

    const int gid = blockIdx.x * 256 + threadIdx.x;
    const int i = gid >> 3;        // voxel
    const int oc2 = gid & 7;       // channel pair
    if (i >= NV) return;
    const int oc = oc2 * 2;

    const int b = coors[4 * i + 0];
    const int z = coors[4 * i + 1];
    const int y = coors[4 * i + 2];
    const int x = coors[4 * i + 3];
    const float f0 = vf[3 * i + 0];
    const float f1 = vf[3 * i + 1];
    const float f2 = vf[3 * i + 2];

    int ozv[2], kzv[2], nz = 0;
    int oyv[2], kyv[2], ny = 0;
    int oxv[2], kxv[2], nx = 0;
#pragma unroll
    for (int k = 0; k < 3; ++k) {
        int t = z + 1 - k;
        if (t >= 0 && !(t & 1)) { int o = t >> 1; if (o < 21) { ozv[nz] = o; kzv[nz] = k; ++nz; } }
    }
#pragma unroll
    for (int k = 0; k < 3; ++k) {
        int t = y + 1 - k;
        if (t >= 0 && !(t & 1)) { int o = t >> 1; if (o < 256) { oyv[ny] = o; kyv[ny] = k; ++ny; } }
    }
#pragma unroll
    for (int k = 0; k < 3; ++k) {
        int t = x + 1 - k;
        if (t >= 0 && !(t & 1)) { int o = t >> 1; if (o < 256) { oxv[nx] = o; kxv[nx] = k; ++nx; } }
    }

    for (int a = 0; a < nz; ++a)
        for (int bb = 0; bb < ny; ++bb)
            for (int c = 0; c < nx; ++c) {
                const int oz = ozv[a], oy = oyv[bb], ox = oxv[c];
                const int tap = (kzv[a] * 3 + kyv[bb]) * 3 + kxv[c];
                const int sp = oz * 65536 + oy * 256 + ox;
                if (oc2 == 0) m1[b * 1376256 + sp] = 1.0f;
                const float s0 = ws[oc * 81 + tap] * f0 + ws[oc * 81 + 27 + tap] * f1 +
                                 ws[oc * 81 + 54 + tap] * f2;
                const float s1 = ws[(oc + 1) * 81 + tap] * f0 +
                                 ws[(oc + 1) * 81 + 27 + tap] * f1 +
                                 ws[(oc + 1) * 81 + 54 + tap] * f2;
                const unsigned pk = f2bf(s0) | (f2bf(s1) << 16);
                unsigned* addr = (unsigned*)(y1 + (size_t)(b * 1376256 + sp) * 16 +
                                             oc2 * 2);
                asm volatile("global_atomic_pk_add_bf16 %0, %1, off"
                             : : "v"(addr), "v"(pk) : "memory");
            }
}

// ---------------- h1 pass: y1(bf16) -> h1(f16) = relu(bn(y1))*m1, IN PLACE ----------------
__global__ __launch_bounds__(256) void h1_pass(
    uint4* __restrict__ y1b, const float* __restrict__ m1,
    const float* __restrict__ shb)
{
    const int idx = blockIdx.x * 256 + threadIdx.x;   // < 2,752,512 cells
    const float mv = m1[idx];
    uint4 u0 = y1b[idx * 2], u1 = y1b[idx * 2 + 1];
    const unsigned d[8] = {u0.x, u0.y, u0.z, u0.w, u1.x, u1.y, u1.z, u1.w};
    unsigned o[8];
#pragma unroll
    for (int j = 0; j < 8; ++j) {
        const int c0 = 2 * j;
        const float vlo = __uint_as_float(d[j] << 16);
        const float vhi = __uint_as_float(d[j] & 0xFFFF0000u);
        const float v0 = fmaxf(vlo * shb[160 + c0] + shb[176 + c0], 0.f) * mv;
        const float v1 = fmaxf(vhi * shb[160 + c0 + 1] + shb[176 + c0 + 1], 0.f) * mv;
        o[j] = __builtin_bit_cast(unsigned, __builtin_amdgcn_cvt_pkrtz(v0, v1));
    }
    uint4 w0, w1;
    w0.x = o[0]; w0.y = o[1]; w0.z = o[2]; w0.w = o[3];
    w1.x = o[4]; w1.y = o[5]; w1.z = o[6]; w1.w = o[7];
    y1b[idx * 2] = w0;
    y1b[idx * 2 + 1] = w1;
}

// ---------------- build m2: per-l2-px "any of 27 taps active" ----------------
__global__ __launch_bounds__(256) void build_m2(
    const float* __restrict__ m1, float* __restrict__ m2)
{
    const int idx = blockIdx.x * 256 + threadIdx.x;       // < 360448
    if (idx >= 360448) return;
    const int b = idx / 180224;
    const int r = idx - b * 180224;
    const int oz = r >> 14, r2 = r & 16383, oy = r2 >> 7, ox = r2 & 127;
    const int iz0 = 2 * oz - 1, iyb = 2 * oy - 1, ixb = 2 * ox - 1;

    float msum = 0.f;
#pragma unroll
    for (int kz = 0; kz < 3; ++kz) {
        const int iz = iz0 + kz;
#pragma unroll
        for (int ky = 0; ky < 3; ++ky) {
            const int iy = iyb + ky;
#pragma unroll
            for (int kx = 0; kx < 3; ++kx) {
                const int ix = ixb + kx;
                if ((unsigned)iz < 21u && (unsigned)iy < 256u && (unsigned)ix < 256u)
                    msum += m1[b * 1376256 + iz * 65536 + iy * 256 + ix];
            }
        }
    }
    m2[idx] = msum > 0.f ? 1.f : 0.f;
}

// ---------------- build m3: per-l3-px "any of 27 m2 taps active" ----------------
__global__ __launch_bounds__(256) void build_m3(
    const float* __restrict__ m2, float* __restrict__ m3)
{
    const int idx = blockIdx.x * 256 + threadIdx.x;       // < 40960
    if (idx >= 40960) return;
    const int b = idx / 20480;
    const int r = idx - b * 20480;
    const int oz = r >> 12, r2 = r & 4095, oy = r2 >> 6, ox = r2 & 63;
    const int iz0 = 2 * oz, iyb = 2 * oy - 1, ixb = 2 * ox - 1;

    float msum = 0.f;
#pragma unroll
    for (int kz = 0; kz < 3; ++kz) {
        const int iz = iz0 + kz;                          // in [0,10]
#pragma unroll
        for (int ky = 0; ky < 3; ++ky) {
            const int iy = iyb + ky;
#pragma unroll
            for (int kx = 0; kx < 3; ++kx) {
                const int ix = ixb + kx;
                if ((unsigned)iy < 128u && (unsigned)ix < 128u)
                    msum += m2[b * 180224 + iz * 16384 + iy * 128 + ix];
            }
        }
    }
    m3[idx] = msum > 0.f ? 1.f : 0.f;
}

// ---------------- Layer 2: implicit-GEMM MFMA 32x32x16 conv 16->32 ----------------
// One wave per 32-px x-strip, all 32 oc. K = 16 cin = one tap per MFMA:
// 27 A-loads + 27 MFMA per wave (half the per-px loads/instrs of 16x16).
__global__ __launch_bounds__(256) void conv_l2(
    const unsigned char* __restrict__ h1,   // f16 cells, byte-addressed
    const uint4* __restrict__ wB2,
    const float* __restrict__ m2, const float* __restrict__ shb,
    _Float16* __restrict__ h2h)
{
    const int tid = threadIdx.x;
    const int gw = blockIdx.x * 4 + (tid >> 6);     // 0..11263
    const int lane = tid & 63;
    const int m = lane & 31, h = lane >> 5;         // px-in-strip, cin-half

    const int plane = gw >> 9;                      // b*11+oz
    const int rem = gw & 511;
    const int oy = rem >> 2;
    const int ox0 = (rem & 3) * 32;
    const int b = plane / 11, oz = plane % 11;
    const int iz0 = 2 * oz - 1, iyb = 2 * oy - 1;
    const int ixm = 2 * (ox0 + m) - 1;              // per-lane input x base
    const int bbase = b * 1376256;
    const int qoff = h * 16;                        // byte offset within 32B cell

    f32x16 acc;
#pragma unroll
    for (int r = 0; r < 16; ++r) acc[r] = 0.f;

#pragma unroll
    for (int tap = 0; tap < 27; ++tap) {
        const int kz = tap / 9, ky = (tap / 3) % 3, kx = tap % 3;
        const int iz = iz0 + kz, iy = iyb + ky, ix = ixm + kx;
        const bool v = (unsigned)iz < 21u && (unsigned)iy < 256u &&
                       (unsigned)ix < 256u;
        const int cell = bbase + iz * 65536 + iy * 256 + ix;
        const int addr = v ? (cell * 32 + qoff) : 0;
        uint4 ua = *(const uint4*)(h1 + addr);
        if (!v) { ua.x = 0; ua.y = 0; ua.z = 0; ua.w = 0; }
        const f16x8 af = __builtin_bit_cast(f16x8, ua);
        const f16x8 bf = __builtin_bit_cast(f16x8, wB2[tap * 64 + lane]);
        acc = __builtin_amdgcn_mfma_f32_32x32x16_f16(af, bf, acc, 0, 0, 0);
    }

    // epilogue: col=lane&31 (oc), row=(r&3)+8*(r>>2)+4*(lane>>5) (px)
    const int oc = lane & 31;
#pragma unroll
    for (int r = 0; r < 16; ++r) {
        const int row = (r & 3) + 8 * (r >> 2) + 4 * h;
        const int px = ox0 + row;
        const int spo = oz * 16384 + oy * 128 + px;
        const float mv = m2[b * 180224 + spo];
        const size_t cbase = (size_t)(b * 180224 + spo) * 32;
        h2h[cbase + oc] = (_Float16)(fmaxf(acc[r] + shb[oc], 0.f) * mv);
    }
}

// ---------------- Layer 3: implicit-GEMM MFMA conv 32->64 ----------------
// One wave per 16-px x-strip; 4 N-tiles of 16 oc. K = 27 taps x 32 cin =
// exactly 27 chunks of K=32. Writes h3 as f16 channel-last cells (128 B).
__global__ __launch_bounds__(256) void conv_l3(
    const unsigned char* __restrict__ h2h,  // f16 cells, byte-addressed
    const uint4* __restrict__ wB3,
    const float* __restrict__ m3, const float* __restrict__ shb,
    _Float16* __restrict__ h3h)
{
    const int tid = threadIdx.x;
    const int gw = blockIdx.x * 4 + (tid >> 6);     // 0..2559
    const int lane = tid & 63;
    const int m = lane & 15, q = lane >> 4;

    const int plane = gw >> 8;                      // b*5+oz
    const int rem = gw & 255;
    const int oy = rem >> 2;
    const int ox0 = (rem & 3) * 16;
    const int b = plane / 5, oz = plane % 5;
    const int iz0 = 2 * oz, iyb = 2 * oy - 1;       // z pad 0
    const int ixm = 2 * (ox0 + m) - 1;
    const int bbase = b * 180224;
    const int qoff = q * 16;                        // byte offset in 64B cell

    f32x4 acc[4];
#pragma unroll
    for (int t = 0; t < 4; ++t) acc[t] = (f32x4){0.f, 0.f, 0.f, 0.f};

#pragma unroll 1
    for (int tap = 0; tap < 27; ++tap) {
        const int kz = tap / 9, ky = (tap / 3) % 3, kx = tap % 3;
        const int iz = iz0 + kz;                    // always in [0,10]
        const int iy = iyb + ky, ix = ixm + kx;
        const bool v = (unsigned)iy < 128u && (unsigned)ix < 128u;
        const int cell = bbase + iz * 16384 + iy * 128 + ix;
        const int addr = v ? (cell * 64 + qoff) : 0;
        uint4 ua = *(const uint4*)(h2h + addr);
        if (!v) { ua.x = 0; ua.y = 0; ua.z = 0; ua.w = 0; }
        const f16x8 af = __builtin_bit_cast(f16x8, ua);
#pragma unroll
        for (int t = 0; t < 4; ++t) {
            const f16x8 bf = __builtin_bit_cast(f16x8, wB3[(tap * 4 + t) * 64 + lane]);
            acc[t] = __builtin_amdgcn_mfma_f32_16x16x32_f16(af, bf, acc[t], 0, 0, 0);
        }
    }

    const int n = lane & 15;
#pragma unroll
    for (int r = 0; r < 4; ++r) {
        const int px = ox0 + q * 4 + r;
        const int spo = oz * 4096 + oy * 64 + px;
        const float mv = m3[b * 20480 + spo];
        const size_t cb = (size_t)(b * 20480 + spo) * 64;
#pragma unroll
        for (int t = 0; t < 4; ++t) {
            const int oc = t * 16 + n;
            h3h[cb + oc] = (_Float16)(fmaxf(acc[t][r] + shb[32 + oc], 0.f) * mv);
        }
    }
}

// ---------------- Layer 4: implicit-GEMM MFMA conv 64->64, k(3,1,1) ----------------
__global__ __launch_bounds__(256) void conv_l4(
    const unsigned char* __restrict__ h3h,  // f16 cells (128 B), byte-addressed
    const uint4* __restrict__ wB4,
    const float* __restrict__ m3, const float* __restrict__ shb,
    float* __restrict__ out)
{
    const int tid = threadIdx.x;
    const int gw = blockIdx.x * 4 + (tid >> 6);     // 0..1023
    const int lane = tid & 63;
    const int m = lane & 15, q = lane >> 4;

    const int b = gw >> 9, od = (gw >> 8) & 1;
    const int oy = (gw >> 2) & 63, ox0 = (gw & 3) * 16;
    const int cellbase = (b * 5 + 2 * od) * 4096 + oy * 64 + ox0 + m;

    f32x4 acc[4];
#pragma unroll
    for (int t = 0; t < 4; ++t) acc[t] = (f32x4){0.f, 0.f, 0.f, 0.f};

#pragma unroll
    for (int c = 0; c < 6; ++c) {
        const int dz = c >> 1;
        const size_t addr = (size_t)(cellbase + dz * 4096) * 128 +
                            (c & 1) * 64 + q * 16;
        const uint4 ua = *(const uint4*)(h3h + addr);
        const f16x8 af = __builtin_bit_cast(f16x8, ua);
#pragma unroll
        for (int t = 0; t < 4; ++t) {
            const f16x8 bf = __builtin_bit_cast(f16x8, wB4[(c * 4 + t) * 64 + lane]);
            acc[t] = __builtin_amdgcn_mfma_f32_16x16x32_f16(af, bf, acc[t], 0, 0, 0);
        }
    }

    const int n = lane & 15;
#pragma unroll
    for (int r = 0; r < 4; ++r) {
        const int px = ox0 + q * 4 + r;
        const int spo = oy * 64 + px;
        const float msum = m3[(b * 5 + 2 * od + 0) * 4096 + spo] +
                           m3[(b * 5 + 2 * od + 1) * 4096 + spo] +
                           m3[(b * 5 + 2 * od + 2) * 4096 + spo];
        const float mv = msum > 0.f ? 1.f : 0.f;
#pragma unroll
        for (int t = 0; t < 4; ++t) {
            const int oc = t * 16 + n;
            out[((b * 64 + oc) * 2 + od) * 4096 + spo] =
                fmaxf(acc[t][r] + shb[96 + oc], 0.f) * mv;
        }
    }
}

extern "C" void kernel_launch(void* const* d_in, const int* in_sizes, int n_in,
                              void* d_out, int out_size, void* d_ws, size_t ws_size,
                              hipStream_t stream)
{
    const float* vf    = (const float*)d_in[0];
    const int*   coors = (const int*)d_in[1];
    // d_in[2] = batch_size (==2, hardcoded in geometry)
    const float* w1 = (const float*)d_in[3];
    const float* g1 = (const float*)d_in[4];
    const float* b1 = (const float*)d_in[5];
    const float* rm1 = (const float*)d_in[6];
    const float* rv1 = (const float*)d_in[7];
    const float* w2 = (const float*)d_in[8];
    const float* g2 = (const float*)d_in[9];
    const float* b2 = (const float*)d_in[10];
    const float* rm2 = (const float*)d_in[11];
    const float* rv2 = (const float*)d_in[12];
    const float* w3 = (const float*)d_in[13];
    const float* g3 = (const float*)d_in[14];
    const float* b3 = (const float*)d_in[15];
    const float* rm3 = (const float*)d_in[16];
    const float* rv3 = (const float*)d_in[17];
    const float* w4 = (const float*)d_in[18];
    const float* g4 = (const float*)d_in[19];
    const float* b4 = (const float*)d_in[20];
    const float* rm4 = (const float*)d_in[21];
    const float* rv4 = (const float*)d_in[22];

    const int NV = in_sizes[0] / 3;

    float* ws = (float*)d_ws;
    float* y1  = ws;                   // 22,020,096 f-slots: bf16->f16 (2,21,256,256,16)
    float* m1  = y1 + 22020096;        //  2,752,512 f  (2,21,256,256)
    float* h2h = m1 + 2752512;         //  5,767,168 f-slots: f16 (2,11,128,128,32)
    float* m2  = h2h + 5767168;        //    360,448 f  (2,11,128,128)
    float* h3h = m2 + 360448;          //  1,310,720 f-slots: f16 (2,5,64,64,64)
    float* m3  = h3h + 1310720;        //     40,960 f  (2,5,64,64)
    float* wB2 = m3 + 40960;           //      7,168 f-slots (13824 f16 used)
    float* wB3 = wB2 + 7168;           //     27,648 f-slots (55296 f16)
    float* wB4 = wB3 + 27648;          //      6,144 f-slots (12288 f16)
    float* shb = wB4 + 6144;           //        192 f

    // zero the scatter accumulator (bf16) + mask (contiguous)
    (void)hipMemsetAsync(y1, 0, (size_t)(22020096 + 2752512) * sizeof(float), stream);

    repack<<<321, 256, 0, stream>>>(g1, b1, rm1, rv1,
                                    w2, g2, b2, rm2, rv2, w3, g3, b3, rm3, rv3,
                                    w4, g4, b4, rm4, rv4,
                                    (_Float16*)wB2, (_Float16*)wB3,
                                    (_Float16*)wB4, shb);
    scatter_l1<<<(NV * 8 + 255) / 256, 256, 0, stream>>>(vf, coors, NV, w1,
                                                         (unsigned short*)y1, m1);
    h1_pass<<<10752, 256, 0, stream>>>((uint4*)y1, m1, shb);
    build_m2<<<1408, 256, 0, stream>>>(m1, m2);
    build_m3<<<160, 256, 0, stream>>>(m2, m3);
    conv_l2<<<2816, 256, 0, stream>>>((const unsigned char*)y1, (const uint4*)wB2,
                                      m2, shb, (_Float16*)h2h);
    conv_l3<<<640, 256, 0, stream>>>((const unsigned char*)h2h, (const uint4*)wB3,
                                     m3, shb, (_Float16*)h3h);
    conv_l4<<<256, 256, 0, stream>>>((const unsigned char*)h3h, (const uint4*)wB4,
                                     m3, shb, (float*)d_out);
}

// Round 21
// 251.138 us; speedup vs baseline: 1.5947x; 1.0000x over previous
//
#include <hip/hip_runtime.h>

#define EPS 1e-3f

// Tensor geometry (fixed for this problem):
// y1/h1: channel-last (2, 21,256,256, 16): scatter accumulates bf16;
//   h1_pass converts IN PLACE to f16 relu(bn(y1))*m1. 32 B per cell.
// m1: (2,21,256,256) fp32;  m2: (2,11,128,128) fp32;  m3: (2,5,64,64) fp32
// h2h: f16 channel-last (2, 11,128,128, 32) -- 64 B per cell
// h3h: f16 channel-last (2, 5,64,64, 64) -- 128 B per cell
// out: (2,128,64,64) fp32
//
// Lessons encoded:
//  - Implicit-GEMM MFMA wins all conv layers (r17-r20, each verified).
//    16x16x32: A[m=lane&15][k=quad*8+j], C/D col=lane&15,row=quad*4+reg.
//    32x32x16: A[m=lane&31][k=(lane>>5)*8+j], C/D col=lane&31,
//    row=(reg&3)+8*(reg>>2)+4*(lane>>5)  (guide m74/m101).
//  - r20: conv_l2 at VGPR=32 had only ~3 of its 27 independent A-loads in
//    flight (2.6 TB/s, latency-bound). waves_per_eu(4,8) lifts the VGPR cap
//    to 128 so the unrolled tap loop keeps ~13 loads outstanding. (r21)
//  - Scatter: bf16 channel-last y1 + packed bf16 atomics. (r13)

// f32 -> bf16 (RNE)
static __device__ __forceinline__ unsigned f2bf(float f) {
    unsigned u = __float_as_uint(f);
    return (u + 0x7FFFu + ((u >> 16) & 1u)) >> 16;
}

typedef _Float16 f16x8 __attribute__((ext_vector_type(8)));
typedef float f32x4 __attribute__((ext_vector_type(4)));
typedef float f32x16 __attribute__((ext_vector_type(16)));

// ---------------- Weight repack + BN fold ----------------
// wB2: f16 B-frags 32x32x16 [tap(27)][lane(64)][8]: oc=lane&31; cin=(lane>>5)*8+j
// wB3: f16 B-frags 16x16x32 [tap(27)][tile(4)][lane(64)][8]: oc=tile*16+(lane&15);
//      cin=(lane>>4)*8+j
// wB4: f16 B-frags 16x16x32 [chunk(6)][tile(4)][lane(64)][8]:
//      k=chunk*32+(lane>>4)*8+j; dz=k>>6; cin=k&63; oc=tile*16+(lane&15)
// shb: [0..31]=sh2, [32..95]=sh3, [96..159]=sh4, [160..175]=sc1, [176..191]=sh1
__global__ __launch_bounds__(256) void repack(
    const float* __restrict__ g1, const float* __restrict__ b1,
    const float* __restrict__ rm1, const float* __restrict__ rv1,
    const float* __restrict__ w2, const float* __restrict__ g2, const float* __restrict__ b2,
    const float* __restrict__ rm2, const float* __restrict__ rv2,
    const float* __restrict__ w3, const float* __restrict__ g3, const float* __restrict__ b3,
    const float* __restrict__ rm3, const float* __restrict__ rv3,
    const float* __restrict__ w4, const float* __restrict__ g4, const float* __restrict__ b4,
    const float* __restrict__ rm4, const float* __restrict__ rv4,
    _Float16* __restrict__ wB2, _Float16* __restrict__ wB3,
    _Float16* __restrict__ wB4, float* __restrict__ shb)
{
    const int i = blockIdx.x * 256 + threadIdx.x;
    if (i < 13824) {                       // wB2[tap*512 + lane*8 + j]
        const int j = i & 7, lane = (i >> 3) & 63, tap = i >> 9;
        const int oc = lane & 31;
        const int cin = (lane >> 5) * 8 + j;
        const float inv = g2[oc] * rsqrtf(rv2[oc] + EPS);
        wB2[i] = (_Float16)(w2[(oc * 16 + cin) * 27 + tap] * inv);
    } else if (i >= 14336 && i < 69632) {  // wB3
        const int j2 = i - 14336;
        const int j = j2 & 7, lane = (j2 >> 3) & 63, t = (j2 >> 9) & 3, tap = j2 >> 11;
        const int q = lane >> 4, n = lane & 15;
        const int oc = t * 16 + n;
        const int cin = q * 8 + j;
        const float inv = g3[oc] * rsqrtf(rv3[oc] + EPS);
        wB3[j2] = (_Float16)(w3[(oc * 32 + cin) * 27 + tap] * inv);
    } else if (i >= 69632 && i < 81920) {  // wB4
        const int j2 = i - 69632;
        const int j = j2 & 7, lane = (j2 >> 3) & 63, t = (j2 >> 9) & 3, c = j2 >> 11;
        const int q = lane >> 4, n = lane & 15;
        const int oc = t * 16 + n;
        const int k = c * 32 + q * 8 + j;
        const int dz = k >> 6, cin = k & 63;
        const float inv = g4[oc] * rsqrtf(rv4[oc] + EPS);
        wB4[j2] = (_Float16)(w4[(oc * 64 + cin) * 3 + dz] * inv);
    } else if (i >= 81920 && i < 82112) {  // shifts + L1 BN scale/shift
        const int j = i - 81920;
        if (j < 32) {
            const float inv = g2[j] * rsqrtf(rv2[j] + EPS);
            shb[j] = b2[j] - rm2[j] * inv;
        } else if (j < 96) {
            const int o = j - 32;
            const float inv = g3[o] * rsqrtf(rv3[o] + EPS);
            shb[j] = b3[o] - rm3[o] * inv;
        } else if (j < 160) {
            const int o = j - 96;
            const float inv = g4[o] * rsqrtf(rv4[o] + EPS);
            shb[j] = b4[o] - rm4[o] * inv;
        } else if (j < 176) {
            const int o = j - 160;
            shb[j] = g1[o] * rsqrtf(rv1[o] + EPS);           // sc1
        } else if (j < 192) {
            const int o = j - 176;
            const float inv = g1[o] * rsqrtf(rv1[o] + EPS);
            shb[j] = b1[o] - rm1[o] * inv;                   // sh1
        }
    }
}

// ---------------- Layer 1: voxel scatter, one thread per (voxel, oc-pair) ----------------
__global__ __launch_bounds__(256) void scatter_l1(
    const float* __restrict__ vf, const int* __restrict__ coors, int NV,
    const float* __restrict__ w1, unsigned short* __restrict__ y1,
    float* __restrict__ m1)
{
    __shared__ float ws[16 * 3 * 27];  // (oc, c, tap)
    for (int e = threadIdx.x; e < 16 * 3 * 27; e += 256) ws[e] = w1[e];
    __syncthreads();

    const int gid = blockIdx.x * 256 + threadIdx.x;
    const int i = gid >> 3;        // voxel
    const int oc2 = gid & 7;       // channel pair
    if (i >= NV) return;
    const int oc = oc2 * 2;

    const int b = coors[4 * i + 0];
    const int z = coors[4 * i + 1];
    const int y = coors[4 * i + 2];
    const int x = coors[4 * i + 3];
    const float f0 = vf[3 * i + 0];
    const float f1 = vf[3 * i + 1];
    const float f2 = vf[3 * i + 2];

    int ozv[2], kzv[2], nz = 0;
    int oyv[2], kyv[2], ny = 0;
    int oxv[2], kxv[2], nx = 0;
#pragma unroll
    for (int k = 0; k < 3; ++k) {
        int t = z + 1 - k;
        if (t >= 0 && !(t & 1)) { int o = t >> 1; if (o < 21) { ozv[nz] = o; kzv[nz] = k; ++nz; } }
    }
#pragma unroll
    for (int k = 0; k < 3; ++k) {
        int t = y + 1 - k;
        if (t >= 0 && !(t & 1)) { int o = t >> 1; if (o < 256) { oyv[ny] = o; kyv[ny] = k; ++ny; } }
    }
#pragma unroll
    for (int k = 0; k < 3; ++k) {
        int t = x + 1 - k;
        if (t >= 0 && !(t & 1)) { int o = t >> 1; if (o < 256) { oxv[nx] = o; kxv[nx] = k; ++nx; } }
    }

    for (int a = 0; a < nz; ++a)
        for (int bb = 0; bb < ny; ++bb)
            for (int c = 0; c < nx; ++c) {
                const int oz = ozv[a], oy = oyv[bb], ox = oxv[c];
                const int tap = (kzv[a] * 3 + kyv[bb]) * 3 + kxv[c];
                const int sp = oz * 65536 + oy * 256 + ox;
                if (oc2 == 0) m1[b * 1376256 + sp] = 1.0f;
                const float s0 = ws[oc * 81 + tap] * f0 + ws[oc * 81 + 27 + tap] * f1 +
                                 ws[oc * 81 + 54 + tap] * f2;
                const float s1 = ws[(oc + 1) * 81 + tap] * f0 +
                                 ws[(oc + 1) * 81 + 27 + tap] * f1 +
                                 ws[(oc + 1) * 81 + 54 + tap] * f2;
                const unsigned pk = f2bf(s0) | (f2bf(s1) << 16);
                unsigned* addr = (unsigned*)(y1 + (size_t)(b * 1376256 + sp) * 16 +
                                             oc2 * 2);
                asm volatile("global_atomic_pk_add_bf16 %0, %1, off"
                             : : "v"(addr), "v"(pk) : "memory");
            }
}

// ---------------- h1 pass: y1(bf16) -> h1(f16) = relu(bn(y1))*m1, IN PLACE ----------------
__global__ __launch_bounds__(256) void h1_pass(
    uint4* __restrict__ y1b, const float* __restrict__ m1,
    const float* __restrict__ shb)
{
    const int idx = blockIdx.x * 256 + threadIdx.x;   // < 2,752,512 cells
    const float mv = m1[idx];
    uint4 u0 = y1b[idx * 2], u1 = y1b[idx * 2 + 1];
    const unsigned d[8] = {u0.x, u0.y, u0.z, u0.w, u1.x, u1.y, u1.z, u1.w};
    unsigned o[8];
#pragma unroll
    for (int j = 0; j < 8; ++j) {
        const int c0 = 2 * j;
        const float vlo = __uint_as_float(d[j] << 16);
        const float vhi = __uint_as_float(d[j] & 0xFFFF0000u);
        const float v0 = fmaxf(vlo * shb[160 + c0] + shb[176 + c0], 0.f) * mv;
        const float v1 = fmaxf(vhi * shb[160 + c0 + 1] + shb[176 + c0 + 1], 0.f) * mv;
        o[j] = __builtin_bit_cast(unsigned, __builtin_amdgcn_cvt_pkrtz(v0, v1));
    }
    uint4 w0, w1;
    w0.x = o[0]; w0.y = o[1]; w0.z = o[2]; w0.w = o[3];
    w1.x = o[4]; w1.y = o[5]; w1.z = o[6]; w1.w = o[7];
    y1b[idx * 2] = w0;
    y1b[idx * 2 + 1] = w1;
}

// ---------------- build m2: per-l2-px "any of 27 taps active" ----------------
__global__ __launch_bounds__(256) void build_m2(
    const float* __restrict__ m1, float* __restrict__ m2)
{
    const int idx = blockIdx.x * 256 + threadIdx.x;       // < 360448
    if (idx >= 360448) return;
    const int b = idx / 180224;
    const int r = idx - b * 180224;
    const int oz = r >> 14, r2 = r & 16383, oy = r2 >> 7, ox = r2 & 127;
    const int iz0 = 2 * oz - 1, iyb = 2 * oy - 1, ixb = 2 * ox - 1;

    float msum = 0.f;
#pragma unroll
    for (int kz = 0; kz < 3; ++kz) {
        const int iz = iz0 + kz;
#pragma unroll
        for (int ky = 0; ky < 3; ++ky) {
            const int iy = iyb + ky;
#pragma unroll
            for (int kx = 0; kx < 3; ++kx) {
                const int ix = ixb + kx;
                if ((unsigned)iz < 21u && (unsigned)iy < 256u && (unsigned)ix < 256u)
                    msum += m1[b * 1376256 + iz * 65536 + iy * 256 + ix];
            }
        }
    }
    m2[idx] = msum > 0.f ? 1.f : 0.f;
}

// ---------------- build m3: per-l3-px "any of 27 m2 taps active" ----------------
__global__ __launch_bounds__(256) void build_m3(
    const float* __restrict__ m2, float* __restrict__ m3)
{
    const int idx = blockIdx.x * 256 + threadIdx.x;       // < 40960
    if (idx >= 40960) return;
    const int b = idx / 20480;
    const int r = idx - b * 20480;
    const int oz = r >> 12, r2 = r & 4095, oy = r2 >> 6, ox = r2 & 63;
    const int iz0 = 2 * oz, iyb = 2 * oy - 1, ixb = 2 * ox - 1;

    float msum = 0.f;
#pragma unroll
    for (int kz = 0; kz < 3; ++kz) {
        const int iz = iz0 + kz;                          // in [0,10]
#pragma unroll
        for (int ky = 0; ky < 3; ++ky) {
            const int iy = iyb + ky;
#pragma unroll
            for (int kx = 0; kx < 3; ++kx) {
                const int ix = ixb + kx;
                if ((unsigned)iy < 128u && (unsigned)ix < 128u)
                    msum += m2[b * 180224 + iz * 16384 + iy * 128 + ix];
            }
        }
    }
    m3[idx] = msum > 0.f ? 1.f : 0.f;
}

// ---------------- Layer 2: implicit-GEMM MFMA 32x32x16 conv 16->32 ----------------
// One wave per 32-px x-strip, all 32 oc. 27 independent A-loads + 27 MFMA;
// waves_per_eu(4,8) lifts VGPR cap so ~13 loads stay in flight (r21).
__global__ __launch_bounds__(256) __attribute__((amdgpu_waves_per_eu(4, 8)))
void conv_l2(
    const unsigned char* __restrict__ h1,   // f16 cells, byte-addressed
    const uint4* __restrict__ wB2,
    const float* __restrict__ m2, const float* __restrict__ shb,
    _Float16* __restrict__ h2h)
{
    const int tid = threadIdx.x;
    const int gw = blockIdx.x * 4 + (tid >> 6);     // 0..11263
    const int lane = tid & 63;
    const int m = lane & 31, h = lane >> 5;         // px-in-strip, cin-half

    const int plane = gw >> 9;                      // b*11+oz
    const int rem = gw & 511;
    const int oy = rem >> 2;
    const int ox0 = (rem & 3) * 32;
    const int b = plane / 11, oz = plane % 11;
    const int iz0 = 2 * oz - 1, iyb = 2 * oy - 1;
    const int ixm = 2 * (ox0 + m) - 1;              // per-lane input x base
    const int bbase = b * 1376256;
    const int qoff = h * 16;                        // byte offset within 32B cell

    f32x16 acc;
#pragma unroll
    for (int r = 0; r < 16; ++r) acc[r] = 0.f;

#pragma unroll
    for (int tap = 0; tap < 27; ++tap) {
        const int kz = tap / 9, ky = (tap / 3) % 3, kx = tap % 3;
        const int iz = iz0 + kz, iy = iyb + ky, ix = ixm + kx;
        const bool v = (unsigned)iz < 21u && (unsigned)iy < 256u &&
                       (unsigned)ix < 256u;
        const int cell = bbase + iz * 65536 + iy * 256 + ix;
        const int addr = v ? (cell * 32 + qoff) : 0;
        uint4 ua = *(const uint4*)(h1 + addr);
        if (!v) { ua.x = 0; ua.y = 0; ua.z = 0; ua.w = 0; }
        const f16x8 af = __builtin_bit_cast(f16x8, ua);
        const f16x8 bf = __builtin_bit_cast(f16x8, wB2[tap * 64 + lane]);
        acc = __builtin_amdgcn_mfma_f32_32x32x16_f16(af, bf, acc, 0, 0, 0);
    }

    // epilogue: col=lane&31 (oc), row=(r&3)+8*(r>>2)+4*(lane>>5) (px)
    const int oc = lane & 31;
#pragma unroll
    for (int r = 0; r < 16; ++r) {
        const int row = (r & 3) + 8 * (r >> 2) + 4 * h;
        const int px = ox0 + row;
        const int spo = oz * 16384 + oy * 128 + px;
        const float mv = m2[b * 180224 + spo];
        const size_t cbase = (size_t)(b * 180224 + spo) * 32;
        h2h[cbase + oc] = (_Float16)(fmaxf(acc[r] + shb[oc], 0.f) * mv);
    }
}

// ---------------- Layer 3: implicit-GEMM MFMA conv 32->64 ----------------
// One wave per 16-px x-strip; 4 N-tiles of 16 oc. K = 27 taps x 32 cin =
// exactly 27 chunks of K=32. Writes h3 as f16 channel-last cells (128 B).
__global__ __launch_bounds__(256) __attribute__((amdgpu_waves_per_eu(4, 8)))
void conv_l3(
    const unsigned char* __restrict__ h2h,  // f16 cells, byte-addressed
    const uint4* __restrict__ wB3,
    const float* __restrict__ m3, const float* __restrict__ shb,
    _Float16* __restrict__ h3h)
{
    const int tid = threadIdx.x;
    const int gw = blockIdx.x * 4 + (tid >> 6);     // 0..2559
    const int lane = tid & 63;
    const int m = lane & 15, q = lane >> 4;

    const int plane = gw >> 8;                      // b*5+oz
    const int rem = gw & 255;
    const int oy = rem >> 2;
    const int ox0 = (rem & 3) * 16;
    const int b = plane / 5, oz = plane % 5;
    const int iz0 = 2 * oz, iyb = 2 * oy - 1;       // z pad 0
    const int ixm = 2 * (ox0 + m) - 1;
    const int bbase = b * 180224;
    const int qoff = q * 16;                        // byte offset in 64B cell

    f32x4 acc[4];
#pragma unroll
    for (int t = 0; t < 4; ++t) acc[t] = (f32x4){0.f, 0.f, 0.f, 0.f};

#pragma unroll
    for (int tap = 0; tap < 27; ++tap) {
        const int kz = tap / 9, ky = (tap / 3) % 3, kx = tap % 3;
        const int iz = iz0 + kz;                    // always in [0,10]
        const int iy = iyb + ky, ix = ixm + kx;
        const bool v = (unsigned)iy < 128u && (unsigned)ix < 128u;
        const int cell = bbase + iz * 16384 + iy * 128 + ix;
        const int addr = v ? (cell * 64 + qoff) : 0;
        uint4 ua = *(const uint4*)(h2h + addr);
        if (!v) { ua.x = 0; ua.y = 0; ua.z = 0; ua.w = 0; }
        const f16x8 af = __builtin_bit_cast(f16x8, ua);
#pragma unroll
        for (int t = 0; t < 4; ++t) {
            const f16x8 bf = __builtin_bit_cast(f16x8, wB3[(tap * 4 + t) * 64 + lane]);
            acc[t] = __builtin_amdgcn_mfma_f32_16x16x32_f16(af, bf, acc[t], 0, 0, 0);
        }
    }

    const int n = lane & 15;
#pragma unroll
    for (int r = 0; r < 4; ++r) {
        const int px = ox0 + q * 4 + r;
        const int spo = oz * 4096 + oy * 64 + px;
        const float mv = m3[b * 20480 + spo];
        const size_t cb = (size_t)(b * 20480 + spo) * 64;
#pragma unroll
        for (int t = 0; t < 4; ++t) {
            const int oc = t * 16 + n;
            h3h[cb + oc] = (_Float16)(fmaxf(acc[t][r] + shb[32 + oc], 0.f) * mv);
        }
    }
}

// ---------------- Layer 4: implicit-GEMM MFMA conv 64->64, k(3,1,1) ----------------
__global__ __launch_bounds__(256) __attribute__((amdgpu_waves_per_eu(4, 8)))
void conv_l4(
    const unsigned char* __restrict__ h3h,  // f16 cells (128 B), byte-addressed
    const uint4* __restrict__ wB4,
    const float* __restrict__ m3, const float* __restrict__ shb,
    float* __restrict__ out)
{
    const int tid = threadIdx.x;
    const int gw = blockIdx.x * 4 + (tid >> 6);     // 0..1023
    const int lane = tid & 63;
    const int m = lane & 15, q = lane >> 4;

    const int b = gw >> 9, od = (gw >> 8) & 1;
    const int oy = (gw >> 2) & 63, ox0 = (gw & 3) * 16;
    const int cellbase = (b * 5 + 2 * od) * 4096 + oy * 64 + ox0 + m;

    f32x4 acc[4];
#pragma unroll
    for (int t = 0; t < 4; ++t) acc[t] = (f32x4){0.f, 0.f, 0.f, 0.f};

#pragma unroll
    for (int c = 0; c < 6; ++c) {
        const int dz = c >> 1;
        const size_t addr = (size_t)(cellbase + dz * 4096) * 128 +
                            (c & 1) * 64 + q * 16;
        const uint4 ua = *(const uint4*)(h3h + addr);
        const f16x8 af = __builtin_bit_cast(f16x8, ua);
#pragma unroll
        for (int t = 0; t < 4; ++t) {
            const f16x8 bf = __builtin_bit_cast(f16x8, wB4[(c * 4 + t) * 64 + lane]);
            acc[t] = __builtin_amdgcn_mfma_f32_16x16x32_f16(af, bf, acc[t], 0, 0, 0);
        }
    }

    const int n = lane & 15;
#pragma unroll
    for (int r = 0; r < 4; ++r) {
        const int px = ox0 + q * 4 + r;
        const int spo = oy * 64 + px;
        const float msum = m3[(b * 5 + 2 * od + 0) * 4096 + spo] +
                           m3[(b * 5 + 2 * od + 1) * 4096 + spo] +
                           m3[(b * 5 + 2 * od + 2) * 4096 + spo];
        const float mv = msum > 0.f ? 1.f : 0.f;
#pragma unroll
        for (int t = 0; t < 4; ++t) {
            const int oc = t * 16 + n;
            out[((b * 64 + oc) * 2 + od) * 4096 + spo] =
                fmaxf(acc[t][r] + shb[96 + oc], 0.f) * mv;
        }
    }
}

extern "C" void kernel_launch(void* const* d_in, const int* in_sizes, int n_in,
                              void* d_out, int out_size, void* d_ws, size_t ws_size,
                              hipStream_t stream)
{
    const float* vf    = (const float*)d_in[0];
    const int*   coors = (const int*)d_in[1];
    // d_in[2] = batch_size (==2, hardcoded in geometry)
    const float* w1 = (const float*)d_in[3];
    const float* g1 = (const float*)d_in[4];
    const float* b1 = (const float*)d_in[5];
    const float* rm1 = (const float*)d_in[6];
    const float* rv1 = (const float*)d_in[7];
    const float* w2 = (const float*)d_in[8];
    const float* g2 = (const float*)d_in[9];
    const float* b2 = (const float*)d_in[10];
    const float* rm2 = (const float*)d_in[11];
    const float* rv2 = (const float*)d_in[12];
    const float* w3 = (const float*)d_in[13];
    const float* g3 = (const float*)d_in[14];
    const float* b3 = (const float*)d_in[15];
    const float* rm3 = (const float*)d_in[16];
    const float* rv3 = (const float*)d_in[17];
    const float* w4 = (const float*)d_in[18];
    const float* g4 = (const float*)d_in[19];
    const float* b4 = (const float*)d_in[20];
    const float* rm4 = (const float*)d_in[21];
    const float* rv4 = (const float*)d_in[22];

    const int NV = in_sizes[0] / 3;

    float* ws = (float*)d_ws;
    float* y1  = ws;                   // 22,020,096 f-slots: bf16->f16 (2,21,256,256,16)
    float* m1  = y1 + 22020096;        //  2,752,512 f  (2,21,256,256)
    float* h2h = m1 + 2752512;         //  5,767,168 f-slots: f16 (2,11,128,128,32)
    float* m2  = h2h + 5767168;        //    360,448 f  (2,11,128,128)
    float* h3h = m2 + 360448;          //  1,310,720 f-slots: f16 (2,5,64,64,64)
    float* m3  = h3h + 1310720;        //     40,960 f  (2,5,64,64)
    float* wB2 = m3 + 40960;           //      7,168 f-slots (13824 f16 used)
    float* wB3 = wB2 + 7168;           //     27,648 f-slots (55296 f16)
    float* wB4 = wB3 + 27648;          //      6,144 f-slots (12288 f16)
    float* shb = wB4 + 6144;           //        192 f

    // zero the scatter accumulator (bf16) + mask (contiguous)
    (void)hipMemsetAsync(y1, 0, (size_t)(22020096 + 2752512) * sizeof(float), stream);

    repack<<<321, 256, 0, stream>>>(g1, b1, rm1, rv1,
                                    w2, g2, b2, rm2, rv2, w3, g3, b3, rm3, rv3,
                                    w4, g4, b4, rm4, rv4,
                                    (_Float16*)wB2, (_Float16*)wB3,
                                    (_Float16*)wB4, shb);
    scatter_l1<<<(NV * 8 + 255) / 256, 256, 0, stream>>>(vf, coors, NV, w1,
                                                         (unsigned short*)y1, m1);
    h1_pass<<<10752, 256, 0, stream>>>((uint4*)y1, m1, shb);
    build_m2<<<1408, 256, 0, stream>>>(m1, m2);
    build_m3<<<160, 256, 0, stream>>>(m2, m3);
    conv_l2<<<2816, 256, 0, stream>>>((const unsigned char*)y1, (const uint4*)wB2,
                                      m2, shb, (_Float16*)h2h);
    conv_l3<<<640, 256, 0, stream>>>((const unsigned char*)h2h, (const uint4*)wB3,
                                     m3, shb, (_Float16*)h3h);
    conv_l4<<<256, 256, 0, stream>>>((const unsigned char*)h3h, (const uint4*)wB4,
                                     m3, shb, (float*)d_out);
}

// Round 22
// 244.376 us; speedup vs baseline: 1.6388x; 1.0277x over previous
//
#include <hip/hip_runtime.h>

#define EPS 1e-3f

// Tensor geometry (fixed for this problem):
// y1/h1: channel-last (2, 21,256,256, 16): scatter accumulates bf16;
//   h1_pass converts IN PLACE to f16 relu(bn(y1))*m1. 32 B per cell.
// m1: (2,21,256,256) fp32;  m2: (2,11,128,128) fp32;  m3: (2,5,64,64) fp32
// h2h: f16 channel-last (2, 11,128,128, 32) -- 64 B per cell
// h3h: f16 channel-last (2, 5,64,64, 64) -- 128 B per cell
// out: (2,128,64,64) fp32
//
// Lessons encoded:
//  - Implicit-GEMM MFMA wins all conv layers (r17-r20, each verified).
//    16x16x32: A[m=lane&15][k=quad*8+j], C/D col=lane&15,row=quad*4+reg.
//    32x32x16: A[m=lane&31][k=(lane>>5)*8+j], C/D col=lane&31,
//    row=(reg&3)+8*(reg>>2)+4*(lane>>5)  (guide m74/m101).
//  - r21: waves_per_eu alone is a no-op -- the compiler still scheduled loads
//    adjacent to MFMAs (VGPR stayed 32, ~3 loads in flight). MLP must be
//    forced STRUCTURALLY: explicit depth-9 circular load buffer. (r22)
//  - Scatter: bf16 channel-last y1 + packed bf16 atomics. (r13)

// f32 -> bf16 (RNE)
static __device__ __forceinline__ unsigned f2bf(float f) {
    unsigned u = __float_as_uint(f);
    return (u + 0x7FFFu + ((u >> 16) & 1u)) >> 16;
}

typedef _Float16 f16x8 __attribute__((ext_vector_type(8)));
typedef float f32x4 __attribute__((ext_vector_type(4)));
typedef float f32x16 __attribute__((ext_vector_type(16)));

// ---------------- Weight repack + BN fold ----------------
// wB2: f16 B-frags 32x32x16 [tap(27)][lane(64)][8]: oc=lane&31; cin=(lane>>5)*8+j
// wB3: f16 B-frags 16x16x32 [tap(27)][tile(4)][lane(64)][8]: oc=tile*16+(lane&15);
//      cin=(lane>>4)*8+j
// wB4: f16 B-frags 16x16x32 [chunk(6)][tile(4)][lane(64)][8]:
//      k=chunk*32+(lane>>4)*8+j; dz=k>>6; cin=k&63; oc=tile*16+(lane&15)
// shb: [0..31]=sh2, [32..95]=sh3, [96..159]=sh4, [160..175]=sc1, [176..191]=sh1
__global__ __launch_bounds__(256) void repack(
    const float* __restrict__ g1, const float* __restrict__ b1,
    const float* __restrict__ rm1, const float* __restrict__ rv1,
    const float* __restrict__ w2, const float* __restrict__ g2, const float* __restrict__ b2,
    const float* __restrict__ rm2, const float* __restrict__ rv2,
    const float* __restrict__ w3, const float* __restrict__ g3, const float* __restrict__ b3,
    const float* __restrict__ rm3, const float* __restrict__ rv3,
    const float* __restrict__ w4, const float* __restrict__ g4, const float* __restrict__ b4,
    const float* __restrict__ rm4, const float* __restrict__ rv4,
    _Float16* __restrict__ wB2, _Float16* __restrict__ wB3,
    _Float16* __restrict__ wB4, float* __restrict__ shb)
{
    const int i = blockIdx.x * 256 + threadIdx.x;
    if (i < 13824) {                       // wB2[tap*512 + lane*8 + j]
        const int j = i & 7, lane = (i >> 3) & 63, tap = i >> 9;
        const int oc = lane & 31;
        const int cin = (lane >> 5) * 8 + j;
        const float inv = g2[oc] * rsqrtf(rv2[oc] + EPS);
        wB2[i] = (_Float16)(w2[(oc * 16 + cin) * 27 + tap] * inv);
    } else if (i >= 14336 && i < 69632) {  // wB3
        const int j2 = i - 14336;
        const int j = j2 & 7, lane = (j2 >> 3) & 63, t = (j2 >> 9) & 3, tap = j2 >> 11;
        const int q = lane >> 4, n = lane & 15;
        const int oc = t * 16 + n;
        const int cin = q * 8 + j;
        const float inv = g3[oc] * rsqrtf(rv3[oc] + EPS);
        wB3[j2] = (_Float16)(w3[(oc * 32 + cin) * 27 + tap] * inv);
    } else if (i >= 69632 && i < 81920) {  // wB4
        const int j2 = i - 69632;
        const int j = j2 & 7, lane = (j2 >> 3) & 63, t = (j2 >> 9) & 3, c = j2 >> 11;
        const int q = lane >> 4, n = lane & 15;
        const int oc = t * 16 + n;
        const int k = c * 32 + q * 8 + j;
        const int dz = k >> 6, cin = k & 63;
        const float inv = g4[oc] * rsqrtf(rv4[oc] + EPS);
        wB4[j2] = (_Float16)(w4[(oc * 64 + cin) * 3 + dz] * inv);
    } else if (i >= 81920 && i < 82112) {  // shifts + L1 BN scale/shift
        const int j = i - 81920;
        if (j < 32) {
            const float inv = g2[j] * rsqrtf(rv2[j] + EPS);
            shb[j] = b2[j] - rm2[j] * inv;
        } else if (j < 96) {
            const int o = j - 32;
            const float inv = g3[o] * rsqrtf(rv3[o] + EPS);
            shb[j] = b3[o] - rm3[o] * inv;
        } else if (j < 160) {
            const int o = j - 96;
            const float inv = g4[o] * rsqrtf(rv4[o] + EPS);
            shb[j] = b4[o] - rm4[o] * inv;
        } else if (j < 176) {
            const int o = j - 160;
            shb[j] = g1[o] * rsqrtf(rv1[o] + EPS);           // sc1
        } else if (j < 192) {
            const int o = j - 176;
            const float inv = g1[o] * rsqrtf(rv1[o] + EPS);
            shb[j] = b1[o] - rm1[o] * inv;                   // sh1
        }
    }
}

// ---------------- Layer 1: voxel scatter, one thread per (voxel, oc-pair) ----------------
__global__ __launch_bounds__(256) void scatter_l1(
    const float* __restrict__ vf, const int* __restrict__ coors, int NV,
    const float* __restrict__ w1, unsigned short* __restrict__ y1,
    float* __restrict__ m1)
{
    __shared__ float ws[16 * 3 * 27];  // (oc, c, tap)
    for (int e = threadIdx.x; e < 16 * 3 * 27; e += 256) ws[e] = w1[e];
    __syncthreads();

    const int gid = blockIdx.x * 256 + threadIdx.x;
    const int i = gid >> 3;        // voxel
    const int oc2 = gid & 7;       // channel pair
    if (i >= NV) return;
    const int oc = oc2 * 2;

    const int b = coors[4 * i + 0];
    const int z = coors[4 * i + 1];
    const int y = coors[4 * i + 2];
    const int x = coors[4 * i + 3];
    const float f0 = vf[3 * i + 0];
    const float f1 = vf[3 * i + 1];
    const float f2 = vf[3 * i + 2];

    int ozv[2], kzv[2], nz = 0;
    int oyv[2], kyv[2], ny = 0;
    int oxv[2], kxv[2], nx = 0;
#pragma unroll
    for (int k = 0; k < 3; ++k) {
        int t = z + 1 - k;
        if (t >= 0 && !(t & 1)) { int o = t >> 1; if (o < 21) { ozv[nz] = o; kzv[nz] = k; ++nz; } }
    }
#pragma unroll
    for (int k = 0; k < 3; ++k) {
        int t = y + 1 - k;
        if (t >= 0 && !(t & 1)) { int o = t >> 1; if (o < 256) { oyv[ny] = o; kyv[ny] = k; ++ny; } }
    }
#pragma unroll
    for (int k = 0; k < 3; ++k) {
        int t = x + 1 - k;
        if (t >= 0 && !(t & 1)) { int o = t >> 1; if (o < 256) { oxv[nx] = o; kxv[nx] = k; ++nx; } }
    }

    for (int a = 0; a < nz; ++a)
        for (int bb = 0; bb < ny; ++bb)
            for (int c = 0; c < nx; ++c) {
                const int oz = ozv[a], oy = oyv[bb], ox = oxv[c];
                const int tap = (kzv[a] * 3 + kyv[bb]) * 3 + kxv[c];
                const int sp = oz * 65536 + oy * 256 + ox;
                if (oc2 == 0) m1[b * 1376256 + sp] = 1.0f;
                const float s0 = ws[oc * 81 + tap] * f0 + ws[oc * 81 + 27 + tap] * f1 +
                                 ws[oc * 81 + 54 + tap] * f2;
                const float s1 = ws[(oc + 1) * 81 + tap] * f0 +
                                 ws[(oc + 1) * 81 + 27 + tap] * f1 +
                                 ws[(oc + 1) * 81 + 54 + tap] * f2;
                const unsigned pk = f2bf(s0) | (f2bf(s1) << 16);
                unsigned* addr = (unsigned*)(y1 + (size_t)(b * 1376256 + sp) * 16 +
                                             oc2 * 2);
                asm volatile("global_atomic_pk_add_bf16 %0, %1, off"
                             : : "v"(addr), "v"(pk) : "memory");
            }
}

// ---------------- h1 pass: y1(bf16) -> h1(f16) = relu(bn(y1))*m1, IN PLACE ----------------
__global__ __launch_bounds__(256) void h1_pass(
    uint4* __restrict__ y1b, const float* __restrict__ m1,
    const float* __restrict__ shb)
{
    const int idx = blockIdx.x * 256 + threadIdx.x;   // < 2,752,512 cells
    const float mv = m1[idx];
    uint4 u0 = y1b[idx * 2], u1 = y1b[idx * 2 + 1];
    const unsigned d[8] = {u0.x, u0.y, u0.z, u0.w, u1.x, u1.y, u1.z, u1.w};
    unsigned o[8];
#pragma unroll
    for (int j = 0; j < 8; ++j) {
        const int c0 = 2 * j;
        const float vlo = __uint_as_float(d[j] << 16);
        const float vhi = __uint_as_float(d[j] & 0xFFFF0000u);
        const float v0 = fmaxf(vlo * shb[160 + c0] + shb[176 + c0], 0.f) * mv;
        const float v1 = fmaxf(vhi * shb[160 + c0 + 1] + shb[176 + c0 + 1], 0.f) * mv;
        o[j] = __builtin_bit_cast(unsigned, __builtin_amdgcn_cvt_pkrtz(v0, v1));
    }
    uint4 w0, w1;
    w0.x = o[0]; w0.y = o[1]; w0.z = o[2]; w0.w = o[3];
    w1.x = o[4]; w1.y = o[5]; w1.z = o[6]; w1.w = o[7];
    y1b[idx * 2] = w0;
    y1b[idx * 2 + 1] = w1;
}

// ---------------- build m2: per-l2-px "any of 27 taps active" ----------------
__global__ __launch_bounds__(256) void build_m2(
    const float* __restrict__ m1, float* __restrict__ m2)
{
    const int idx = blockIdx.x * 256 + threadIdx.x;       // < 360448
    if (idx >= 360448) return;
    const int b = idx / 180224;
    const int r = idx - b * 180224;
    const int oz = r >> 14, r2 = r & 16383, oy = r2 >> 7, ox = r2 & 127;
    const int iz0 = 2 * oz - 1, iyb = 2 * oy - 1, ixb = 2 * ox - 1;

    float msum = 0.f;
#pragma unroll
    for (int kz = 0; kz < 3; ++kz) {
        const int iz = iz0 + kz;
#pragma unroll
        for (int ky = 0; ky < 3; ++ky) {
            const int iy = iyb + ky;
#pragma unroll
            for (int kx = 0; kx < 3; ++kx) {
                const int ix = ixb + kx;
                if ((unsigned)iz < 21u && (unsigned)iy < 256u && (unsigned)ix < 256u)
                    msum += m1[b * 1376256 + iz * 65536 + iy * 256 + ix];
            }
        }
    }
    m2[idx] = msum > 0.f ? 1.f : 0.f;
}

// ---------------- build m3: per-l3-px "any of 27 m2 taps active" ----------------
__global__ __launch_bounds__(256) void build_m3(
    const float* __restrict__ m2, float* __restrict__ m3)
{
    const int idx = blockIdx.x * 256 + threadIdx.x;       // < 40960
    if (idx >= 40960) return;
    const int b = idx / 20480;
    const int r = idx - b * 20480;
    const int oz = r >> 12, r2 = r & 4095, oy = r2 >> 6, ox = r2 & 63;
    const int iz0 = 2 * oz, iyb = 2 * oy - 1, ixb = 2 * ox - 1;

    float msum = 0.f;
#pragma unroll
    for (int kz = 0; kz < 3; ++kz) {
        const int iz = iz0 + kz;                          // in [0,10]
#pragma unroll
        for (int ky = 0; ky < 3; ++ky) {
            const int iy = iyb + ky;
#pragma unroll
            for (int kx = 0; kx < 3; ++kx) {
                const int ix = ixb + kx;
                if ((unsigned)iy < 128u && (unsigned)ix < 128u)
                    msum += m2[b * 180224 + iz * 16384 + iy * 128 + ix];
            }
        }
    }
    m3[idx] = msum > 0.f ? 1.f : 0.f;
}

// ---------------- Layer 2: implicit-GEMM MFMA 32x32x16 conv 16->32 ----------------
// One wave per 32-px x-strip, all 32 oc. Explicit depth-9 circular load buffer
// forces ~9 A-loads in flight (r22; compiler alone kept only ~3, r21).
__global__ __launch_bounds__(256) __attribute__((amdgpu_waves_per_eu(4, 8)))
void conv_l2(
    const unsigned char* __restrict__ h1,   // f16 cells, byte-addressed
    const uint4* __restrict__ wB2,
    const float* __restrict__ m2, const float* __restrict__ shb,
    _Float16* __restrict__ h2h)
{
    const int tid = threadIdx.x;
    const int gw = blockIdx.x * 4 + (tid >> 6);     // 0..11263
    const int lane = tid & 63;
    const int m = lane & 31, h = lane >> 5;         // px-in-strip, cin-half

    const int plane = gw >> 9;                      // b*11+oz
    const int rem = gw & 511;
    const int oy = rem >> 2;
    const int ox0 = (rem & 3) * 32;
    const int b = plane / 11, oz = plane % 11;
    const int iz0 = 2 * oz - 1, iyb = 2 * oy - 1;
    const int ixm = 2 * (ox0 + m) - 1;              // per-lane input x base
    const int bbase = b * 1376256;
    const int qoff = h * 16;                        // byte offset within 32B cell

    f32x16 acc;
#pragma unroll
    for (int r = 0; r < 16; ++r) acc[r] = 0.f;

    // explicit depth-9 pipeline
    uint4 buf[9];
    bool  val[9];
#pragma unroll
    for (int t = 0; t < 9; ++t) {
        const int kz = t / 9, ky = (t / 3) % 3, kx = t % 3;
        const int iz = iz0 + kz, iy = iyb + ky, ix = ixm + kx;
        const bool v = (unsigned)iz < 21u && (unsigned)iy < 256u &&
                       (unsigned)ix < 256u;
        const int cell = bbase + iz * 65536 + iy * 256 + ix;
        buf[t] = *(const uint4*)(h1 + (v ? (cell * 32 + qoff) : 0));
        val[t] = v;
    }

#pragma unroll
    for (int tap = 0; tap < 27; ++tap) {
        const int s = tap % 9;
        uint4 ua = buf[s];
        if (!val[s]) { ua.x = 0; ua.y = 0; ua.z = 0; ua.w = 0; }
        // refill slot with tap+9's load; latency hides under following MFMAs
        if (tap + 9 < 27) {
            const int t2 = tap + 9;
            const int kz = t2 / 9, ky = (t2 / 3) % 3, kx = t2 % 3;
            const int iz = iz0 + kz, iy = iyb + ky, ix = ixm + kx;
            const bool v = (unsigned)iz < 21u && (unsigned)iy < 256u &&
                           (unsigned)ix < 256u;
            const int cell = bbase + iz * 65536 + iy * 256 + ix;
            buf[s] = *(const uint4*)(h1 + (v ? (cell * 32 + qoff) : 0));
            val[s] = v;
        }
        const f16x8 af = __builtin_bit_cast(f16x8, ua);
        const f16x8 bf = __builtin_bit_cast(f16x8, wB2[tap * 64 + lane]);
        acc = __builtin_amdgcn_mfma_f32_32x32x16_f16(af, bf, acc, 0, 0, 0);
    }

    // epilogue: col=lane&31 (oc), row=(r&3)+8*(r>>2)+4*(lane>>5) (px)
    const int oc = lane & 31;
#pragma unroll
    for (int r = 0; r < 16; ++r) {
        const int row = (r & 3) + 8 * (r >> 2) + 4 * h;
        const int px = ox0 + row;
        const int spo = oz * 16384 + oy * 128 + px;
        const float mv = m2[b * 180224 + spo];
        const size_t cbase = (size_t)(b * 180224 + spo) * 32;
        h2h[cbase + oc] = (_Float16)(fmaxf(acc[r] + shb[oc], 0.f) * mv);
    }
}

// ---------------- Layer 3: implicit-GEMM MFMA conv 32->64 ----------------
__global__ __launch_bounds__(256) __attribute__((amdgpu_waves_per_eu(4, 8)))
void conv_l3(
    const unsigned char* __restrict__ h2h,  // f16 cells, byte-addressed
    const uint4* __restrict__ wB3,
    const float* __restrict__ m3, const float* __restrict__ shb,
    _Float16* __restrict__ h3h)
{
    const int tid = threadIdx.x;
    const int gw = blockIdx.x * 4 + (tid >> 6);     // 0..2559
    const int lane = tid & 63;
    const int m = lane & 15, q = lane >> 4;

    const int plane = gw >> 8;                      // b*5+oz
    const int rem = gw & 255;
    const int oy = rem >> 2;
    const int ox0 = (rem & 3) * 16;
    const int b = plane / 5, oz = plane % 5;
    const int iz0 = 2 * oz, iyb = 2 * oy - 1;       // z pad 0
    const int ixm = 2 * (ox0 + m) - 1;
    const int bbase = b * 180224;
    const int qoff = q * 16;                        // byte offset in 64B cell

    f32x4 acc[4];
#pragma unroll
    for (int t = 0; t < 4; ++t) acc[t] = (f32x4){0.f, 0.f, 0.f, 0.f};

    uint4 buf[9];
    bool  val[9];
#pragma unroll
    for (int t = 0; t < 9; ++t) {
        const int ky = (t / 3) % 3, kx = t % 3;
        const int iz = iz0 + t / 9, iy = iyb + ky, ix = ixm + kx;
        const bool v = (unsigned)iy < 128u && (unsigned)ix < 128u;
        const int cell = bbase + iz * 16384 + iy * 128 + ix;
        buf[t] = *(const uint4*)(h2h + (v ? (cell * 64 + qoff) : 0));
        val[t] = v;
    }

#pragma unroll
    for (int tap = 0; tap < 27; ++tap) {
        const int s = tap % 9;
        uint4 ua = buf[s];
        if (!val[s]) { ua.x = 0; ua.y = 0; ua.z = 0; ua.w = 0; }
        if (tap + 9 < 27) {
            const int t2 = tap + 9;
            const int kz = t2 / 9, ky = (t2 / 3) % 3, kx = t2 % 3;
            const int iz = iz0 + kz, iy = iyb + ky, ix = ixm + kx;
            const bool v = (unsigned)iy < 128u && (unsigned)ix < 128u;
            const int cell = bbase + iz * 16384 + iy * 128 + ix;
            buf[s] = *(const uint4*)(h2h + (v ? (cell * 64 + qoff) : 0));
            val[s] = v;
        }
        const f16x8 af = __builtin_bit_cast(f16x8, ua);
#pragma unroll
        for (int t = 0; t < 4; ++t) {
            const f16x8 bf = __builtin_bit_cast(f16x8, wB3[(tap * 4 + t) * 64 + lane]);
            acc[t] = __builtin_amdgcn_mfma_f32_16x16x32_f16(af, bf, acc[t], 0, 0, 0);
        }
    }

    const int n = lane & 15;
#pragma unroll
    for (int r = 0; r < 4; ++r) {
        const int px = ox0 + q * 4 + r;
        const int spo = oz * 4096 + oy * 64 + px;
        const float mv = m3[b * 20480 + spo];
        const size_t cb = (size_t)(b * 20480 + spo) * 64;
#pragma unroll
        for (int t = 0; t < 4; ++t) {
            const int oc = t * 16 + n;
            h3h[cb + oc] = (_Float16)(fmaxf(acc[t][r] + shb[32 + oc], 0.f) * mv);
        }
    }
}

// ---------------- Layer 4: implicit-GEMM MFMA conv 64->64, k(3,1,1) ----------------
__global__ __launch_bounds__(256) __attribute__((amdgpu_waves_per_eu(4, 8)))
void conv_l4(
    const unsigned char* __restrict__ h3h,  // f16 cells (128 B), byte-addressed
    const uint4* __restrict__ wB4,
    const float* __restrict__ m3, const float* __restrict__ shb,
    float* __restrict__ out)
{
    const int tid = threadIdx.x;
    const int gw = blockIdx.x * 4 + (tid >> 6);     // 0..1023
    const int lane = tid & 63;
    const int m = lane & 15, q = lane >> 4;

    const int b = gw >> 9, od = (gw >> 8) & 1;
    const int oy = (gw >> 2) & 63, ox0 = (gw & 3) * 16;
    const int cellbase = (b * 5 + 2 * od) * 4096 + oy * 64 + ox0 + m;

    f32x4 acc[4];
#pragma unroll
    for (int t = 0; t < 4; ++t) acc[t] = (f32x4){0.f, 0.f, 0.f, 0.f};

#pragma unroll
    for (int c = 0; c < 6; ++c) {
        const int dz = c >> 1;
        const size_t addr = (size_t)(cellbase + dz * 4096) * 128 +
                            (c & 1) * 64 + q * 16;
        const uint4 ua = *(const uint4*)(h3h + addr);
        const f16x8 af = __builtin_bit_cast(f16x8, ua);
#pragma unroll
        for (int t = 0; t < 4; ++t) {
            const f16x8 bf = __builtin_bit_cast(f16x8, wB4[(c * 4 + t) * 64 + lane]);
            acc[t] = __builtin_amdgcn_mfma_f32_16x16x32_f16(af, bf, acc[t], 0, 0, 0);
        }
    }

    const int n = lane & 15;
#pragma unroll
    for (int r = 0; r < 4; ++r) {
        const int px = ox0 + q * 4 + r;
        const int spo = oy * 64 + px;
        const float msum = m3[(b * 5 + 2 * od + 0) * 4096 + spo] +
                           m3[(b * 5 + 2 * od + 1) * 4096 + spo] +
                           m3[(b * 5 + 2 * od + 2) * 4096 + spo];
        const float mv = msum > 0.f ? 1.f : 0.f;
#pragma unroll
        for (int t = 0; t < 4; ++t) {
            const int oc = t * 16 + n;
            out[((b * 64 + oc) * 2 + od) * 4096 + spo] =
                fmaxf(acc[t][r] + shb[96 + oc], 0.f) * mv;
        }
    }
}

extern "C" void kernel_launch(void* const* d_in, const int* in_sizes, int n_in,
                              void* d_out, int out_size, void* d_ws, size_t ws_size,
                              hipStream_t stream)
{
    const float* vf    = (const float*)d_in[0];
    const int*   coors = (const int*)d_in[1];
    // d_in[2] = batch_size (==2, hardcoded in geometry)
    const float* w1 = (const float*)d_in[3];
    const float* g1 = (const float*)d_in[4];
    const float* b1 = (const float*)d_in[5];
    const float* rm1 = (const float*)d_in[6];
    const float* rv1 = (const float*)d_in[7];
    const float* w2 = (const float*)d_in[8];
    const float* g2 = (const float*)d_in[9];
    const float* b2 = (const float*)d_in[10];
    const float* rm2 = (const float*)d_in[11];
    const float* rv2 = (const float*)d_in[12];
    const float* w3 = (const float*)d_in[13];
    const float* g3 = (const float*)d_in[14];
    const float* b3 = (const float*)d_in[15];
    const float* rm3 = (const float*)d_in[16];
    const float* rv3 = (const float*)d_in[17];
    const float* w4 = (const float*)d_in[18];
    const float* g4 = (const float*)d_in[19];
    const float* b4 = (const float*)d_in[20];
    const float* rm4 = (const float*)d_in[21];
    const float* rv4 = (const float*)d_in[22];

    const int NV = in_sizes[0] / 3;

    float* ws = (float*)d_ws;
    float* y1  = ws;                   // 22,020,096 f-slots: bf16->f16 (2,21,256,256,16)
    float* m1  = y1 + 22020096;        //  2,752,512 f  (2,21,256,256)
    float* h2h = m1 + 2752512;         //  5,767,168 f-slots: f16 (2,11,128,128,32)
    float* m2  = h2h + 5767168;        //    360,448 f  (2,11,128,128)
    float* h3h = m2 + 360448;          //  1,310,720 f-slots: f16 (2,5,64,64,64)
    float* m3  = h3h + 1310720;        //     40,960 f  (2,5,64,64)
    float* wB2 = m3 + 40960;           //      7,168 f-slots (13824 f16 used)
    float* wB3 = wB2 + 7168;           //     27,648 f-slots (55296 f16)
    float* wB4 = wB3 + 27648;          //      6,144 f-slots (12288 f16)
    float* shb = wB4 + 6144;           //        192 f

    // zero the scatter accumulator (bf16) + mask (contiguous)
    (void)hipMemsetAsync(y1, 0, (size_t)(22020096 + 2752512) * sizeof(float), stream);

    repack<<<321, 256, 0, stream>>>(g1, b1, rm1, rv1,
                                    w2, g2, b2, rm2, rv2, w3, g3, b3, rm3, rv3,
                                    w4, g4, b4, rm4, rv4,
                                    (_Float16*)wB2, (_Float16*)wB3,
                                    (_Float16*)wB4, shb);
    scatter_l1<<<(NV * 8 + 255) / 256, 256, 0, stream>>>(vf, coors, NV, w1,
                                                         (unsigned short*)y1, m1);
    h1_pass<<<10752, 256, 0, stream>>>((uint4*)y1, m1, shb);
    build_m2<<<1408, 256, 0, stream>>>(m1, m2);
    build_m3<<<160, 256, 0, stream>>>(m2, m3);
    conv_l2<<<2816, 256, 0, stream>>>((const unsigned char*)y1, (const uint4*)wB2,
                                      m2, shb, (_Float16*)h2h);
    conv_l3<<<640, 256, 0, stream>>>((const unsigned char*)h2h, (const uint4*)wB3,
                                     m3, shb, (_Float16*)h3h);
    conv_l4<<<256, 256, 0, stream>>>((const unsigned char*)h3h, (const uint4*)wB4,
                                     m3, shb, (float*)d_out);
}

// Round 23
// 236.570 us; speedup vs baseline: 1.6929x; 1.0330x over previous
//
#include <hip/hip_runtime.h>

#define EPS 1e-3f

// Tensor geometry (fixed for this problem):
// y1/h1: channel-last (2, 21,256,256, 16): scatter accumulates bf16;
//   h1_pass converts IN PLACE to f16 relu(bn(y1))*m1 AND builds m2. 32 B/cell.
// m1: (2,21,256,256) fp32;  m2: (2,11,128,128) fp32;  m3: (2,5,64,64) fp32
// h2h: f16 channel-last (2, 11,128,128, 32) -- 64 B per cell
// h3h: f16 channel-last (2, 5,64,64, 64) -- 128 B per cell
// out: (2,128,64,64) fp32
//
// Lessons encoded:
//  - Implicit-GEMM MFMA wins all conv layers (r17-r20, each verified).
//    16x16x32: A[m=lane&15][k=quad*8+j], C/D col=lane&15,row=quad*4+reg.
//    32x32x16: A[m=lane&31][k=(lane>>5)*8+j], C/D col=lane&31,
//    row=(reg&3)+8*(reg>>2)+4*(lane>>5)  (guide m74/m101).
//  - MLP must be forced STRUCTURALLY (explicit circular load buffer);
//    waves_per_eu alone is a no-op (r21/r22: depth-9 buffer -7us).
//  - Scatter: bf16 channel-last y1 + packed bf16 atomics. (r13)
//  - r23: fuse build_m2 into h1_pass (one fewer launch); conv_l2 pipeline
//    depth 9->13 (VGPR headroom to 128 cap).

// f32 -> bf16 (RNE)
static __device__ __forceinline__ unsigned f2bf(float f) {
    unsigned u = __float_as_uint(f);
    return (u + 0x7FFFu + ((u >> 16) & 1u)) >> 16;
}

typedef _Float16 f16x8 __attribute__((ext_vector_type(8)));
typedef float f32x4 __attribute__((ext_vector_type(4)));
typedef float f32x16 __attribute__((ext_vector_type(16)));

// ---------------- Weight repack + BN fold ----------------
// wB2: f16 B-frags 32x32x16 [tap(27)][lane(64)][8]: oc=lane&31; cin=(lane>>5)*8+j
// wB3: f16 B-frags 16x16x32 [tap(27)][tile(4)][lane(64)][8]: oc=tile*16+(lane&15);
//      cin=(lane>>4)*8+j
// wB4: f16 B-frags 16x16x32 [chunk(6)][tile(4)][lane(64)][8]:
//      k=chunk*32+(lane>>4)*8+j; dz=k>>6; cin=k&63; oc=tile*16+(lane&15)
// shb: [0..31]=sh2, [32..95]=sh3, [96..159]=sh4, [160..175]=sc1, [176..191]=sh1
__global__ __launch_bounds__(256) void repack(
    const float* __restrict__ g1, const float* __restrict__ b1,
    const float* __restrict__ rm1, const float* __restrict__ rv1,
    const float* __restrict__ w2, const float* __restrict__ g2, const float* __restrict__ b2,
    const float* __restrict__ rm2, const float* __restrict__ rv2,
    const float* __restrict__ w3, const float* __restrict__ g3, const float* __restrict__ b3,
    const float* __restrict__ rm3, const float* __restrict__ rv3,
    const float* __restrict__ w4, const float* __restrict__ g4, const float* __restrict__ b4,
    const float* __restrict__ rm4, const float* __restrict__ rv4,
    _Float16* __restrict__ wB2, _Float16* __restrict__ wB3,
    _Float16* __restrict__ wB4, float* __restrict__ shb)
{
    const int i = blockIdx.x * 256 + threadIdx.x;
    if (i < 13824) {                       // wB2[tap*512 + lane*8 + j]
        const int j = i & 7, lane = (i >> 3) & 63, tap = i >> 9;
        const int oc = lane & 31;
        const int cin = (lane >> 5) * 8 + j;
        const float inv = g2[oc] * rsqrtf(rv2[oc] + EPS);
        wB2[i] = (_Float16)(w2[(oc * 16 + cin) * 27 + tap] * inv);
    } else if (i >= 14336 && i < 69632) {  // wB3
        const int j2 = i - 14336;
        const int j = j2 & 7, lane = (j2 >> 3) & 63, t = (j2 >> 9) & 3, tap = j2 >> 11;
        const int q = lane >> 4, n = lane & 15;
        const int oc = t * 16 + n;
        const int cin = q * 8 + j;
        const float inv = g3[oc] * rsqrtf(rv3[oc] + EPS);
        wB3[j2] = (_Float16)(w3[(oc * 32 + cin) * 27 + tap] * inv);
    } else if (i >= 69632 && i < 81920) {  // wB4
        const int j2 = i - 69632;
        const int j = j2 & 7, lane = (j2 >> 3) & 63, t = (j2 >> 9) & 3, c = j2 >> 11;
        const int q = lane >> 4, n = lane & 15;
        const int oc = t * 16 + n;
        const int k = c * 32 + q * 8 + j;
        const int dz = k >> 6, cin = k & 63;
        const float inv = g4[oc] * rsqrtf(rv4[oc] + EPS);
        wB4[j2] = (_Float16)(w4[(oc * 64 + cin) * 3 + dz] * inv);
    } else if (i >= 81920 && i < 82112) {  // shifts + L1 BN scale/shift
        const int j = i - 81920;
        if (j < 32) {
            const float inv = g2[j] * rsqrtf(rv2[j] + EPS);
            shb[j] = b2[j] - rm2[j] * inv;
        } else if (j < 96) {
            const int o = j - 32;
            const float inv = g3[o] * rsqrtf(rv3[o] + EPS);
            shb[j] = b3[o] - rm3[o] * inv;
        } else if (j < 160) {
            const int o = j - 96;
            const float inv = g4[o] * rsqrtf(rv4[o] + EPS);
            shb[j] = b4[o] - rm4[o] * inv;
        } else if (j < 176) {
            const int o = j - 160;
            shb[j] = g1[o] * rsqrtf(rv1[o] + EPS);           // sc1
        } else if (j < 192) {
            const int o = j - 176;
            const float inv = g1[o] * rsqrtf(rv1[o] + EPS);
            shb[j] = b1[o] - rm1[o] * inv;                   // sh1
        }
    }
}

// ---------------- Layer 1: voxel scatter, one thread per (voxel, oc-pair) ----------------
__global__ __launch_bounds__(256) void scatter_l1(
    const float* __restrict__ vf, const int* __restrict__ coors, int NV,
    const float* __restrict__ w1, unsigned short* __restrict__ y1,
    float* __restrict__ m1)
{
    __shared__ float ws[16 * 3 * 27];  // (oc, c, tap)
    for (int e = threadIdx.x; e < 16 * 3 * 27; e += 256) ws[e] = w1[e];
    __syncthreads();

    const int gid = blockIdx.x * 256 + threadIdx.x;
    const int i = gid >> 3;        // voxel
    const int oc2 = gid & 7;       // channel pair
    if (i >= NV) return;
    const int oc = oc2 * 2;

    const int b = coors[4 * i + 0];
    const int z = coors[4 * i + 1];
    const int y = coors[4 * i + 2];
    const int x = coors[4 * i + 3];
    const float f0 = vf[3 * i + 0];
    const float f1 = vf[3 * i + 1];
    const float f2 = vf[3 * i + 2];

    int ozv[2], kzv[2], nz = 0;
    int oyv[2], kyv[2], ny = 0;
    int oxv[2], kxv[2], nx = 0;
#pragma unroll
    for (int k = 0; k < 3; ++k) {
        int t = z + 1 - k;
        if (t >= 0 && !(t & 1)) { int o = t >> 1; if (o < 21) { ozv[nz] = o; kzv[nz] = k; ++nz; } }
    }
#pragma unroll
    for (int k = 0; k < 3; ++k) {
        int t = y + 1 - k;
        if (t >= 0 && !(t & 1)) { int o = t >> 1; if (o < 256) { oyv[ny] = o; kyv[ny] = k; ++ny; } }
    }
#pragma unroll
    for (int k = 0; k < 3; ++k) {
        int t = x + 1 - k;
        if (t >= 0 && !(t & 1)) { int o = t >> 1; if (o < 256) { oxv[nx] = o; kxv[nx] = k; ++nx; } }
    }

    for (int a = 0; a < nz; ++a)
        for (int bb = 0; bb < ny; ++bb)
            for (int c = 0; c < nx; ++c) {
                const int oz = ozv[a], oy = oyv[bb], ox = oxv[c];
                const int tap = (kzv[a] * 3 + kyv[bb]) * 3 + kxv[c];
                const int sp = oz * 65536 + oy * 256 + ox;
                if (oc2 == 0) m1[b * 1376256 + sp] = 1.0f;
                const float s0 = ws[oc * 81 + tap] * f0 + ws[oc * 81 + 27 + tap] * f1 +
                                 ws[oc * 81 + 54 + tap] * f2;
                const float s1 = ws[(oc + 1) * 81 + tap] * f0 +
                                 ws[(oc + 1) * 81 + 27 + tap] * f1 +
                                 ws[(oc + 1) * 81 + 54 + tap] * f2;
                const unsigned pk = f2bf(s0) | (f2bf(s1) << 16);
                unsigned* addr = (unsigned*)(y1 + (size_t)(b * 1376256 + sp) * 16 +
                                             oc2 * 2);
                asm volatile("global_atomic_pk_add_bf16 %0, %1, off"
                             : : "v"(addr), "v"(pk) : "memory");
            }
}

// ---------------- h1 pass (+fused build_m2) ----------------
// Per cell: y1(bf16) -> h1(f16) = relu(bn(y1))*m1, IN PLACE.
// Threads with idx < 360448 additionally build one m2 px (reads only m1).
__global__ __launch_bounds__(256) void h1_pass(
    uint4* __restrict__ y1b, const float* __restrict__ m1,
    const float* __restrict__ shb, float* __restrict__ m2)
{
    const int idx = blockIdx.x * 256 + threadIdx.x;   // < 2,752,512 cells
    const float mv = m1[idx];
    uint4 u0 = y1b[idx * 2], u1 = y1b[idx * 2 + 1];
    const unsigned d[8] = {u0.x, u0.y, u0.z, u0.w, u1.x, u1.y, u1.z, u1.w};
    unsigned o[8];
#pragma unroll
    for (int j = 0; j < 8; ++j) {
        const int c0 = 2 * j;
        const float vlo = __uint_as_float(d[j] << 16);
        const float vhi = __uint_as_float(d[j] & 0xFFFF0000u);
        const float v0 = fmaxf(vlo * shb[160 + c0] + shb[176 + c0], 0.f) * mv;
        const float v1 = fmaxf(vhi * shb[160 + c0 + 1] + shb[176 + c0 + 1], 0.f) * mv;
        o[j] = __builtin_bit_cast(unsigned, __builtin_amdgcn_cvt_pkrtz(v0, v1));
    }
    uint4 w0, w1;
    w0.x = o[0]; w0.y = o[1]; w0.z = o[2]; w0.w = o[3];
    w1.x = o[4]; w1.y = o[5]; w1.z = o[6]; w1.w = o[7];
    y1b[idx * 2] = w0;
    y1b[idx * 2 + 1] = w1;

    // fused build_m2 (reads only m1; m1 is not written here)
    if (idx < 360448) {
        const int b = idx / 180224;
        const int r = idx - b * 180224;
        const int oz = r >> 14, r2 = r & 16383, oy = r2 >> 7, ox = r2 & 127;
        const int iz0 = 2 * oz - 1, iyb = 2 * oy - 1, ixb = 2 * ox - 1;
        float msum = 0.f;
#pragma unroll
        for (int kz = 0; kz < 3; ++kz) {
            const int iz = iz0 + kz;
#pragma unroll
            for (int ky = 0; ky < 3; ++ky) {
                const int iy = iyb + ky;
#pragma unroll
                for (int kx = 0; kx < 3; ++kx) {
                    const int ix = ixb + kx;
                    if ((unsigned)iz < 21u && (unsigned)iy < 256u &&
                        (unsigned)ix < 256u)
                        msum += m1[b * 1376256 + iz * 65536 + iy * 256 + ix];
                }
            }
        }
        m2[idx] = msum > 0.f ? 1.f : 0.f;
    }
}

// ---------------- build m3: per-l3-px "any of 27 m2 taps active" ----------------
__global__ __launch_bounds__(256) void build_m3(
    const float* __restrict__ m2, float* __restrict__ m3)
{
    const int idx = blockIdx.x * 256 + threadIdx.x;       // < 40960
    if (idx >= 40960) return;
    const int b = idx / 20480;
    const int r = idx - b * 20480;
    const int oz = r >> 12, r2 = r & 4095, oy = r2 >> 6, ox = r2 & 63;
    const int iz0 = 2 * oz, iyb = 2 * oy - 1, ixb = 2 * ox - 1;

    float msum = 0.f;
#pragma unroll
    for (int kz = 0; kz < 3; ++kz) {
        const int iz = iz0 + kz;                          // in [0,10]
#pragma unroll
        for (int ky = 0; ky < 3; ++ky) {
            const int iy = iyb + ky;
#pragma unroll
            for (int kx = 0; kx < 3; ++kx) {
                const int ix = ixb + kx;
                if ((unsigned)iy < 128u && (unsigned)ix < 128u)
                    msum += m2[b * 180224 + iz * 16384 + iy * 128 + ix];
            }
        }
    }
    m3[idx] = msum > 0.f ? 1.f : 0.f;
}

// ---------------- Layer 2: implicit-GEMM MFMA 32x32x16 conv 16->32 ----------------
// One wave per 32-px x-strip, all 32 oc. Explicit depth-13 circular load
// buffer keeps ~13 A-loads in flight (r22 depth-9 proved the technique).
__global__ __launch_bounds__(256) __attribute__((amdgpu_waves_per_eu(4, 8)))
void conv_l2(
    const unsigned char* __restrict__ h1,   // f16 cells, byte-addressed
    const uint4* __restrict__ wB2,
    const float* __restrict__ m2, const float* __restrict__ shb,
    _Float16* __restrict__ h2h)
{
    const int tid = threadIdx.x;
    const int gw = blockIdx.x * 4 + (tid >> 6);     // 0..11263
    const int lane = tid & 63;
    const int m = lane & 31, h = lane >> 5;         // px-in-strip, cin-half

    const int plane = gw >> 9;                      // b*11+oz
    const int rem = gw & 511;
    const int oy = rem >> 2;
    const int ox0 = (rem & 3) * 32;
    const int b = plane / 11, oz = plane % 11;
    const int iz0 = 2 * oz - 1, iyb = 2 * oy - 1;
    const int ixm = 2 * (ox0 + m) - 1;              // per-lane input x base
    const int bbase = b * 1376256;
    const int qoff = h * 16;                        // byte offset within 32B cell

    f32x16 acc;
#pragma unroll
    for (int r = 0; r < 16; ++r) acc[r] = 0.f;

    // explicit depth-13 pipeline
    uint4 buf[13];
    bool  val[13];
#pragma unroll
    for (int t = 0; t < 13; ++t) {
        const int kz = t / 9, ky = (t / 3) % 3, kx = t % 3;
        const int iz = iz0 + kz, iy = iyb + ky, ix = ixm + kx;
        const bool v = (unsigned)iz < 21u && (unsigned)iy < 256u &&
                       (unsigned)ix < 256u;
        const int cell = bbase + iz * 65536 + iy * 256 + ix;
        buf[t] = *(const uint4*)(h1 + (v ? (cell * 32 + qoff) : 0));
        val[t] = v;
    }

#pragma unroll
    for (int tap = 0; tap < 27; ++tap) {
        const int s = tap % 13;
        uint4 ua = buf[s];
        if (!val[s]) { ua.x = 0; ua.y = 0; ua.z = 0; ua.w = 0; }
        // refill slot with tap+13's load; latency hides under following MFMAs
        if (tap + 13 < 27) {
            const int t2 = tap + 13;
            const int kz = t2 / 9, ky = (t2 / 3) % 3, kx = t2 % 3;
            const int iz = iz0 + kz, iy = iyb + ky, ix = ixm + kx;
            const bool v = (unsigned)iz < 21u && (unsigned)iy < 256u &&
                           (unsigned)ix < 256u;
            const int cell = bbase + iz * 65536 + iy * 256 + ix;
            buf[s] = *(const uint4*)(h1 + (v ? (cell * 32 + qoff) : 0));
            val[s] = v;
        }
        const f16x8 af = __builtin_bit_cast(f16x8, ua);
        const f16x8 bf = __builtin_bit_cast(f16x8, wB2[tap * 64 + lane]);
        acc = __builtin_amdgcn_mfma_f32_32x32x16_f16(af, bf, acc, 0, 0, 0);
    }

    // epilogue: col=lane&31 (oc), row=(r&3)+8*(r>>2)+4*(lane>>5) (px)
    const int oc = lane & 31;
#pragma unroll
    for (int r = 0; r < 16; ++r) {
        const int row = (r & 3) + 8 * (r >> 2) + 4 * h;
        const int px = ox0 + row;
        const int spo = oz * 16384 + oy * 128 + px;
        const float mv = m2[b * 180224 + spo];
        const size_t cbase = (size_t)(b * 180224 + spo) * 32;
        h2h[cbase + oc] = (_Float16)(fmaxf(acc[r] + shb[oc], 0.f) * mv);
    }
}

// ---------------- Layer 3: implicit-GEMM MFMA conv 32->64 ----------------
__global__ __launch_bounds__(256) __attribute__((amdgpu_waves_per_eu(4, 8)))
void conv_l3(
    const unsigned char* __restrict__ h2h,  // f16 cells, byte-addressed
    const uint4* __restrict__ wB3,
    const float* __restrict__ m3, const float* __restrict__ shb,
    _Float16* __restrict__ h3h)
{
    const int tid = threadIdx.x;
    const int gw = blockIdx.x * 4 + (tid >> 6);     // 0..2559
    const int lane = tid & 63;
    const int m = lane & 15, q = lane >> 4;

    const int plane = gw >> 8;                      // b*5+oz
    const int rem = gw & 255;
    const int oy = rem >> 2;
    const int ox0 = (rem & 3) * 16;
    const int b = plane / 5, oz = plane % 5;
    const int iz0 = 2 * oz, iyb = 2 * oy - 1;       // z pad 0
    const int ixm = 2 * (ox0 + m) - 1;
    const int bbase = b * 180224;
    const int qoff = q * 16;                        // byte offset in 64B cell

    f32x4 acc[4];
#pragma unroll
    for (int t = 0; t < 4; ++t) acc[t] = (f32x4){0.f, 0.f, 0.f, 0.f};

    uint4 buf[9];
    bool  val[9];
#pragma unroll
    for (int t = 0; t < 9; ++t) {
        const int ky = (t / 3) % 3, kx = t % 3;
        const int iz = iz0 + t / 9, iy = iyb + ky, ix = ixm + kx;
        const bool v = (unsigned)iy < 128u && (unsigned)ix < 128u;
        const int cell = bbase + iz * 16384 + iy * 128 + ix;
        buf[t] = *(const uint4*)(h2h + (v ? (cell * 64 + qoff) : 0));
        val[t] = v;
    }

#pragma unroll
    for (int tap = 0; tap < 27; ++tap) {
        const int s = tap % 9;
        uint4 ua = buf[s];
        if (!val[s]) { ua.x = 0; ua.y = 0; ua.z = 0; ua.w = 0; }
        if (tap + 9 < 27) {
            const int t2 = tap + 9;
            const int kz = t2 / 9, ky = (t2 / 3) % 3, kx = t2 % 3;
            const int iz = iz0 + kz, iy = iyb + ky, ix = ixm + kx;
            const bool v = (unsigned)iy < 128u && (unsigned)ix < 128u;
            const int cell = bbase + iz * 16384 + iy * 128 + ix;
            buf[s] = *(const uint4*)(h2h + (v ? (cell * 64 + qoff) : 0));
            val[s] = v;
        }
        const f16x8 af = __builtin_bit_cast(f16x8, ua);
#pragma unroll
        for (int t = 0; t < 4; ++t) {
            const f16x8 bf = __builtin_bit_cast(f16x8, wB3[(tap * 4 + t) * 64 + lane]);
            acc[t] = __builtin_amdgcn_mfma_f32_16x16x32_f16(af, bf, acc[t], 0, 0, 0);
        }
    }

    const int n = lane & 15;
#pragma unroll
    for (int r = 0; r < 4; ++r) {
        const int px = ox0 + q * 4 + r;
        const int spo = oz * 4096 + oy * 64 + px;
        const float mv = m3[b * 20480 + spo];
        const size_t cb = (size_t)(b * 20480 + spo) * 64;
#pragma unroll
        for (int t = 0; t < 4; ++t) {
            const int oc = t * 16 + n;
            h3h[cb + oc] = (_Float16)(fmaxf(acc[t][r] + shb[32 + oc], 0.f) * mv);
        }
    }
}

// ---------------- Layer 4: implicit-GEMM MFMA conv 64->64, k(3,1,1) ----------------
__global__ __launch_bounds__(256) __attribute__((amdgpu_waves_per_eu(4, 8)))
void conv_l4(
    const unsigned char* __restrict__ h3h,  // f16 cells (128 B), byte-addressed
    const uint4* __restrict__ wB4,
    const float* __restrict__ m3, const float* __restrict__ shb,
    float* __restrict__ out)
{
    const int tid = threadIdx.x;
    const int gw = blockIdx.x * 4 + (tid >> 6);     // 0..1023
    const int lane = tid & 63;
    const int m = lane & 15, q = lane >> 4;

    const int b = gw >> 9, od = (gw >> 8) & 1;
    const int oy = (gw >> 2) & 63, ox0 = (gw & 3) * 16;
    const int cellbase = (b * 5 + 2 * od) * 4096 + oy * 64 + ox0 + m;

    f32x4 acc[4];
#pragma unroll
    for (int t = 0; t < 4; ++t) acc[t] = (f32x4){0.f, 0.f, 0.f, 0.f};

#pragma unroll
    for (int c = 0; c < 6; ++c) {
        const int dz = c >> 1;
        const size_t addr = (size_t)(cellbase + dz * 4096) * 128 +
                            (c & 1) * 64 + q * 16;
        const uint4 ua = *(const uint4*)(h3h + addr);
        const f16x8 af = __builtin_bit_cast(f16x8, ua);
#pragma unroll
        for (int t = 0; t < 4; ++t) {
            const f16x8 bf = __builtin_bit_cast(f16x8, wB4[(c * 4 + t) * 64 + lane]);
            acc[t] = __builtin_amdgcn_mfma_f32_16x16x32_f16(af, bf, acc[t], 0, 0, 0);
        }
    }

    const int n = lane & 15;
#pragma unroll
    for (int r = 0; r < 4; ++r) {
        const int px = ox0 + q * 4 + r;
        const int spo = oy * 64 + px;
        const float msum = m3[(b * 5 + 2 * od + 0) * 4096 + spo] +
                           m3[(b * 5 + 2 * od + 1) * 4096 + spo] +
                           m3[(b * 5 + 2 * od + 2) * 4096 + spo];
        const float mv = msum > 0.f ? 1.f : 0.f;
#pragma unroll
        for (int t = 0; t < 4; ++t) {
            const int oc = t * 16 + n;
            out[((b * 64 + oc) * 2 + od) * 4096 + spo] =
                fmaxf(acc[t][r] + shb[96 + oc], 0.f) * mv;
        }
    }
}

extern "C" void kernel_launch(void* const* d_in, const int* in_sizes, int n_in,
                              void* d_out, int out_size, void* d_ws, size_t ws_size,
                              hipStream_t stream)
{
    const float* vf    = (const float*)d_in[0];
    const int*   coors = (const int*)d_in[1];
    // d_in[2] = batch_size (==2, hardcoded in geometry)
    const float* w1 = (const float*)d_in[3];
    const float* g1 = (const float*)d_in[4];
    const float* b1 = (const float*)d_in[5];
    const float* rm1 = (const float*)d_in[6];
    const float* rv1 = (const float*)d_in[7];
    const float* w2 = (const float*)d_in[8];
    const float* g2 = (const float*)d_in[9];
    const float* b2 = (const float*)d_in[10];
    const float* rm2 = (const float*)d_in[11];
    const float* rv2 = (const float*)d_in[12];
    const float* w3 = (const float*)d_in[13];
    const float* g3 = (const float*)d_in[14];
    const float* b3 = (const float*)d_in[15];
    const float* rm3 = (const float*)d_in[16];
    const float* rv3 = (const float*)d_in[17];
    const float* w4 = (const float*)d_in[18];
    const float* g4 = (const float*)d_in[19];
    const float* b4 = (const float*)d_in[20];
    const float* rm4 = (const float*)d_in[21];
    const float* rv4 = (const float*)d_in[22];

    const int NV = in_sizes[0] / 3;

    float* ws = (float*)d_ws;
    float* y1  = ws;                   // 22,020,096 f-slots: bf16->f16 (2,21,256,256,16)
    float* m1  = y1 + 22020096;        //  2,752,512 f  (2,21,256,256)
    float* h2h = m1 + 2752512;         //  5,767,168 f-slots: f16 (2,11,128,128,32)
    float* m2  = h2h + 5767168;        //    360,448 f  (2,11,128,128)
    float* h3h = m2 + 360448;          //  1,310,720 f-slots: f16 (2,5,64,64,64)
    float* m3  = h3h + 1310720;        //     40,960 f  (2,5,64,64)
    float* wB2 = m3 + 40960;           //      7,168 f-slots (13824 f16 used)
    float* wB3 = wB2 + 7168;           //     27,648 f-slots (55296 f16)
    float* wB4 = wB3 + 27648;          //      6,144 f-slots (12288 f16)
    float* shb = wB4 + 6144;           //        192 f

    // zero the scatter accumulator (bf16) + mask (contiguous)
    (void)hipMemsetAsync(y1, 0, (size_t)(22020096 + 2752512) * sizeof(float), stream);

    repack<<<321, 256, 0, stream>>>(g1, b1, rm1, rv1,
                                    w2, g2, b2, rm2, rv2, w3, g3, b3, rm3, rv3,
                                    w4, g4, b4, rm4, rv4,
                                    (_Float16*)wB2, (_Float16*)wB3,
                                    (_Float16*)wB4, shb);
    scatter_l1<<<(NV * 8 + 255) / 256, 256, 0, stream>>>(vf, coors, NV, w1,
                                                         (unsigned short*)y1, m1);
    h1_pass<<<10752, 256, 0, stream>>>((uint4*)y1, m1, shb, m2);
    build_m3<<<160, 256, 0, stream>>>(m2, m3);
    conv_l2<<<2816, 256, 0, stream>>>((const unsigned char*)y1, (const uint4*)wB2,
                                      m2, shb, (_Float16*)h2h);
    conv_l3<<<640, 256, 0, stream>>>((const unsigned char*)h2h, (const uint4*)wB3,
                                     m3, shb, (_Float16*)h3h);
    conv_l4<<<256, 256, 0, stream>>>((const unsigned char*)h3h, (const uint4*)wB4,
                                     m3, shb, (float*)d_out);
}